// Round 1
// baseline (2185.670 us; speedup 1.0000x reference)
//
#include <hip/hip_runtime.h>

#define NN 20000   // nodes
#define DD 64      // emb dim
#define HH 512     // hidden
#define EE 320000  // edges per graph
#define NT 8       // nodes per wave in GEMM kernels (20000 % 8 == 0)

// ---------------- degree ----------------
__global__ __launch_bounds__(256) void degree_kernel(const int* __restrict__ dst,
                                                     float* __restrict__ deg) {
    int e = blockIdx.x * blockDim.x + threadIdx.x;
    if (e < EE) unsafeAtomicAdd(&deg[dst[e]], 1.0f);
}

__global__ __launch_bounds__(256) void inv_kernel(float* __restrict__ deg, int n) {
    int i = blockIdx.x * blockDim.x + threadIdx.x;
    if (i < n) deg[i] = 1.0f / fmaxf(deg[i], 1.0f);
}

// ---------------- scatter-add (push aggregation) ----------------
// wave per edge, lane = feature dim. src/dst/ew loads are wave-uniform -> scalar.
__global__ __launch_bounds__(256) void scatter_kernel(const float* __restrict__ x,
                                                      const int* __restrict__ src,
                                                      const int* __restrict__ dst,
                                                      const float* __restrict__ ew,
                                                      float* __restrict__ agg) {
    int t = blockIdx.x * blockDim.x + threadIdx.x;
    int e = t >> 6, lane = t & 63;
    if (e >= EE) return;
    int s = src[e], d = dst[e];
    float v = x[s * DD + lane];
    if (ew) v *= ew[e];
    unsafeAtomicAdd(&agg[d * DD + lane], v);
}

// ---------------- layer0: h1 = relu(x@Ws + (agg*inv_deg)@Wn + b) ----------------
// wave = 8 nodes x 64 cols. x/agg loads wave-uniform (scalar), W loads coalesced.
template <int K, int NC>
__global__ __launch_bounds__(256) void sage_layer0(const float* __restrict__ x,    // [N,K]
                                                   const float* __restrict__ agg,  // [N,K]
                                                   const float* __restrict__ invd, // [N]
                                                   const float* __restrict__ Ws,   // [K,NC]
                                                   const float* __restrict__ Wn,   // [K,NC]
                                                   const float* __restrict__ bias, // [NC]
                                                   float* __restrict__ out) {      // [N,NC]
    int wid = (blockIdx.x * blockDim.x + threadIdx.x) >> 6;
    int lane = threadIdx.x & 63;
    constexpr int CT = NC / 64;
    int ntile = wid / CT;
    int ctile = wid % CT;
    int n0 = ntile * NT;
    if (n0 >= NN) return;
    int col = ctile * 64 + lane;
    float accx[NT] = {};
    float accn[NT] = {};
    for (int k = 0; k < K; ++k) {
        float ws = Ws[k * NC + col];
        float wn = Wn[k * NC + col];
#pragma unroll
        for (int i = 0; i < NT; ++i) {
            accx[i] = fmaf(x[(n0 + i) * K + k], ws, accx[i]);
            accn[i] = fmaf(agg[(n0 + i) * K + k], wn, accn[i]);
        }
    }
    float b = bias[col];
#pragma unroll
    for (int i = 0; i < NT; ++i) {
        float v = accx[i] + accn[i] * invd[n0 + i] + b;
        out[(n0 + i) * NC + col] = fmaxf(v, 0.0f);
    }
}

// ---------------- layer1 GEMM pair: s_part = h@Ws1, xn = h@Wn1 ----------------
template <int K>
__global__ __launch_bounds__(256) void sage_layer1(const float* __restrict__ h,   // [N,K]
                                                   const float* __restrict__ Ws,  // [K,64]
                                                   const float* __restrict__ Wn,  // [K,64]
                                                   float* __restrict__ s_part,    // [N,64]
                                                   float* __restrict__ xn) {      // [N,64]
    int wid = (blockIdx.x * blockDim.x + threadIdx.x) >> 6;
    int lane = threadIdx.x & 63;
    int n0 = wid * NT;
    if (n0 >= NN) return;
    float acc1[NT] = {};
    float acc2[NT] = {};
    for (int k = 0; k < K; ++k) {
        float w1 = Ws[k * 64 + lane];
        float w2 = Wn[k * 64 + lane];
#pragma unroll
        for (int i = 0; i < NT; ++i) {
            float hv = h[(n0 + i) * K + k];
            acc1[i] = fmaf(hv, w1, acc1[i]);
            acc2[i] = fmaf(hv, w2, acc2[i]);
        }
    }
#pragma unroll
    for (int i = 0; i < NT; ++i) {
        s_part[(n0 + i) * 64 + lane] = acc1[i];
        xn[(n0 + i) * 64 + lane] = acc2[i];
    }
}

// ---------------- combine: out = s_part + agg1*inv_deg + b ----------------
__global__ __launch_bounds__(256) void combine_kernel(const float* __restrict__ s_part,
                                                      const float* __restrict__ agg1,
                                                      const float* __restrict__ invd,
                                                      const float* __restrict__ bias,
                                                      float* __restrict__ out) {
    int t = blockIdx.x * blockDim.x + threadIdx.x;
    if (t >= NN * DD) return;
    int n = t >> 6, d = t & 63;
    out[t] = s_part[t] + agg1[t] * invd[n] + bias[d];
}

// ---------------- attention reduction: w_s = sum_n sum_d ap[n,d]*tanh(z_s[n]@attW + attb)[d]
__global__ __launch_bounds__(256) void att_reduce(const float* __restrict__ pr,
                                                  const float* __restrict__ cc,
                                                  const float* __restrict__ ap,
                                                  const float* __restrict__ attW,
                                                  const float* __restrict__ attb,
                                                  float* __restrict__ w_acc) {
    int wid = (blockIdx.x * blockDim.x + threadIdx.x) >> 6;
    int lane = threadIdx.x & 63;
    if (wid >= NN) return;
    int n = wid;
    float p0 = 0.f, p1 = 0.f;
    for (int k = 0; k < DD; ++k) {
        float w = attW[k * DD + lane];
        p0 = fmaf(pr[n * DD + k], w, p0);
        p1 = fmaf(cc[n * DD + k], w, p1);
    }
    float b = attb[lane];
    float a = ap[n * DD + lane];
    float c0 = a * tanhf(p0 + b);
    float c1 = a * tanhf(p1 + b);
#pragma unroll
    for (int off = 32; off; off >>= 1) {
        c0 += __shfl_xor(c0, off);
        c1 += __shfl_xor(c1, off);
    }
    if (lane == 0) {
        unsafeAtomicAdd(&w_acc[0], c0);
        unsafeAtomicAdd(&w_acc[1], c1);
    }
}

// ---------------- final: beta = softmax(w/N); out = b0*pr + b1*cc ----------------
__global__ __launch_bounds__(256) void final_kernel(const float* __restrict__ pr,
                                                    const float* __restrict__ cc,
                                                    const float* __restrict__ w_acc,
                                                    float* __restrict__ out) {
    int t = blockIdx.x * blockDim.x + threadIdx.x;
    if (t >= NN * DD) return;
    float w0 = w_acc[0] * (1.0f / NN);
    float w1 = w_acc[1] * (1.0f / NN);
    float m = fmaxf(w0, w1);
    float e0 = __expf(w0 - m), e1 = __expf(w1 - m);
    float inv = 1.0f / (e0 + e1);
    out[t] = (e0 * pr[t] + e1 * cc[t]) * inv;
}

extern "C" void kernel_launch(void* const* d_in, const int* in_sizes, int n_in,
                              void* d_out, int out_size, void* d_ws, size_t ws_size,
                              hipStream_t stream) {
    const float* k_emb  = (const float*)d_in[0];
    const int*   pr_src = (const int*)d_in[1];
    const int*   pr_dst = (const int*)d_in[2];
    const float* pr_ew  = (const float*)d_in[3];
    const int*   cc_src = (const int*)d_in[4];
    const int*   cc_dst = (const int*)d_in[5];
    const float* cc_ew  = (const float*)d_in[6];
    const int*   sps_src = (const int*)d_in[7];
    const int*   sps_dst = (const int*)d_in[8];
    const float* pr_Ws0 = (const float*)d_in[9];
    const float* pr_Wn0 = (const float*)d_in[10];
    const float* pr_b0  = (const float*)d_in[11];
    const float* pr_Ws1 = (const float*)d_in[12];
    const float* pr_Wn1 = (const float*)d_in[13];
    const float* pr_b1  = (const float*)d_in[14];
    const float* cc_Ws0 = (const float*)d_in[15];
    const float* cc_Wn0 = (const float*)d_in[16];
    const float* cc_b0  = (const float*)d_in[17];
    const float* cc_Ws1 = (const float*)d_in[18];
    const float* cc_Wn1 = (const float*)d_in[19];
    const float* cc_b1  = (const float*)d_in[20];
    const float* ap_Ws0 = (const float*)d_in[21];
    const float* ap_Wn0 = (const float*)d_in[22];
    const float* ap_b0  = (const float*)d_in[23];
    const float* ap_Ws1 = (const float*)d_in[24];
    const float* ap_Wn1 = (const float*)d_in[25];
    const float* ap_b1  = (const float*)d_in[26];
    const float* att_W  = (const float*)d_in[27];
    const float* att_b  = (const float*)d_in[28];
    float* out = (float*)d_out;

    // workspace layout (floats)
    float* ws = (float*)d_ws;
    float* deg_pr = ws;                    // N
    float* deg_cc = deg_pr + NN;           // N
    float* deg_ap = deg_cc + NN;           // N
    float* w_acc  = deg_ap + NN;           // 2 (+pad to 16)
    float* agg0   = w_acc + 16;            // N*64
    float* agg1   = agg0 + NN * DD;        // N*64
    float* xn     = agg1 + NN * DD;        // N*64
    float* s_part = xn + NN * DD;          // N*64
    float* out_pr = s_part + NN * DD;      // N*64
    float* out_cc = out_pr + NN * DD;      // N*64
    float* out_ap = out_cc + NN * DD;      // N*64
    float* h1     = out_ap + NN * DD;      // N*512 (ap uses first N*64)
    // total = 3N + 16 + 7*N*64 + N*512 floats ~= 77 MB

    const int TB = 256;
    const int blocks_E   = EE / TB;                 // 1250
    const int blocks_EL  = (EE * 64) / TB;          // 80000
    const int blocks_ND  = (NN * DD) / TB;          // 5000
    const int blocks_g0b = (NN / NT) * (HH / 64) * 64 / TB;  // 5000
    const int blocks_g64 = (NN / NT) * 64 / TB;     // 625
    const int blocks_att = NN * 64 / TB;            // 5000

    // ---- degrees ----
    hipMemsetAsync(deg_pr, 0, 3 * NN * sizeof(float), stream);
    hipMemsetAsync(w_acc, 0, 16 * sizeof(float), stream);
    degree_kernel<<<blocks_E, TB, 0, stream>>>(pr_dst, deg_pr);
    degree_kernel<<<blocks_E, TB, 0, stream>>>(cc_dst, deg_cc);
    degree_kernel<<<blocks_E, TB, 0, stream>>>(sps_dst, deg_ap);
    inv_kernel<<<(3 * NN + TB - 1) / TB, TB, 0, stream>>>(deg_pr, 3 * NN);  // contiguous

    // ---- pr branch ----
    hipMemsetAsync(agg0, 0, NN * DD * sizeof(float), stream);
    scatter_kernel<<<blocks_EL, TB, 0, stream>>>(k_emb, pr_src, pr_dst, pr_ew, agg0);
    sage_layer0<DD, HH><<<blocks_g0b, TB, 0, stream>>>(k_emb, agg0, deg_pr, pr_Ws0, pr_Wn0, pr_b0, h1);
    sage_layer1<HH><<<blocks_g64, TB, 0, stream>>>(h1, pr_Ws1, pr_Wn1, s_part, xn);
    hipMemsetAsync(agg1, 0, NN * DD * sizeof(float), stream);
    scatter_kernel<<<blocks_EL, TB, 0, stream>>>(xn, pr_src, pr_dst, pr_ew, agg1);
    combine_kernel<<<blocks_ND, TB, 0, stream>>>(s_part, agg1, deg_pr, pr_b1, out_pr);

    // ---- cc branch ----
    hipMemsetAsync(agg0, 0, NN * DD * sizeof(float), stream);
    scatter_kernel<<<blocks_EL, TB, 0, stream>>>(k_emb, cc_src, cc_dst, cc_ew, agg0);
    sage_layer0<DD, HH><<<blocks_g0b, TB, 0, stream>>>(k_emb, agg0, deg_cc, cc_Ws0, cc_Wn0, cc_b0, h1);
    sage_layer1<HH><<<blocks_g64, TB, 0, stream>>>(h1, cc_Ws1, cc_Wn1, s_part, xn);
    hipMemsetAsync(agg1, 0, NN * DD * sizeof(float), stream);
    scatter_kernel<<<blocks_EL, TB, 0, stream>>>(xn, cc_src, cc_dst, cc_ew, agg1);
    combine_kernel<<<blocks_ND, TB, 0, stream>>>(s_part, agg1, deg_cc, cc_b1, out_cc);

    // ---- ap branch (64->64->64, no edge weights) ----
    hipMemsetAsync(agg0, 0, NN * DD * sizeof(float), stream);
    scatter_kernel<<<blocks_EL, TB, 0, stream>>>(k_emb, sps_src, sps_dst, nullptr, agg0);
    sage_layer0<DD, DD><<<blocks_g64, TB, 0, stream>>>(k_emb, agg0, deg_ap, ap_Ws0, ap_Wn0, ap_b0, h1);
    sage_layer1<DD><<<blocks_g64, TB, 0, stream>>>(h1, ap_Ws1, ap_Wn1, s_part, xn);
    hipMemsetAsync(agg1, 0, NN * DD * sizeof(float), stream);
    scatter_kernel<<<blocks_EL, TB, 0, stream>>>(xn, sps_src, sps_dst, nullptr, agg1);
    combine_kernel<<<blocks_ND, TB, 0, stream>>>(s_part, agg1, deg_ap, ap_b1, out_ap);

    // ---- attention fusion ----
    att_reduce<<<blocks_att, TB, 0, stream>>>(out_pr, out_cc, out_ap, att_W, att_b, w_acc);
    final_kernel<<<blocks_ND, TB, 0, stream>>>(out_pr, out_cc, w_acc, out);
}

// Round 2
// 1796.197 us; speedup vs baseline: 1.2168x; 1.2168x over previous
//
#include <hip/hip_runtime.h>

#define NN 20000   // nodes
#define DD 64      // emb dim
#define HH 512     // hidden
#define EE 320000  // edges per graph
#define NT 8       // nodes per wave in GEMM kernels (20000 % 8 == 0)
#define ATT_BLOCKS 625  // stage-1 blocks for attention reduce (20000/(625*4)=8 nodes/wave)

// ---------------- degree ----------------
__global__ __launch_bounds__(256) void degree_kernel(const int* __restrict__ dst,
                                                     float* __restrict__ deg) {
    int e = blockIdx.x * blockDim.x + threadIdx.x;
    if (e < EE) unsafeAtomicAdd(&deg[dst[e]], 1.0f);
}

__global__ __launch_bounds__(256) void inv_kernel(float* __restrict__ deg, int n) {
    int i = blockIdx.x * blockDim.x + threadIdx.x;
    if (i < n) deg[i] = 1.0f / fmaxf(deg[i], 1.0f);
}

// ---------------- scatter-add (push aggregation) ----------------
// wave per edge, lane = feature dim. src/dst/ew loads are wave-uniform -> scalar.
__global__ __launch_bounds__(256) void scatter_kernel(const float* __restrict__ x,
                                                      const int* __restrict__ src,
                                                      const int* __restrict__ dst,
                                                      const float* __restrict__ ew,
                                                      float* __restrict__ agg) {
    int t = blockIdx.x * blockDim.x + threadIdx.x;
    int e = t >> 6, lane = t & 63;
    if (e >= EE) return;
    int s = src[e], d = dst[e];
    float v = x[s * DD + lane];
    if (ew) v *= ew[e];
    unsafeAtomicAdd(&agg[d * DD + lane], v);
}

// ---------------- layer0: h1 = relu(x@Ws + (agg*inv_deg)@Wn + b) ----------------
template <int K, int NC>
__global__ __launch_bounds__(256) void sage_layer0(const float* __restrict__ x,    // [N,K]
                                                   const float* __restrict__ agg,  // [N,K]
                                                   const float* __restrict__ invd, // [N]
                                                   const float* __restrict__ Ws,   // [K,NC]
                                                   const float* __restrict__ Wn,   // [K,NC]
                                                   const float* __restrict__ bias, // [NC]
                                                   float* __restrict__ out) {      // [N,NC]
    int wid = (blockIdx.x * blockDim.x + threadIdx.x) >> 6;
    int lane = threadIdx.x & 63;
    constexpr int CT = NC / 64;
    int ntile = wid / CT;
    int ctile = wid % CT;
    int n0 = ntile * NT;
    if (n0 >= NN) return;
    int col = ctile * 64 + lane;
    float accx[NT] = {};
    float accn[NT] = {};
    for (int k = 0; k < K; ++k) {
        float ws = Ws[k * NC + col];
        float wn = Wn[k * NC + col];
#pragma unroll
        for (int i = 0; i < NT; ++i) {
            accx[i] = fmaf(x[(n0 + i) * K + k], ws, accx[i]);
            accn[i] = fmaf(agg[(n0 + i) * K + k], wn, accn[i]);
        }
    }
    float b = bias[col];
#pragma unroll
    for (int i = 0; i < NT; ++i) {
        float v = accx[i] + accn[i] * invd[n0 + i] + b;
        out[(n0 + i) * NC + col] = fmaxf(v, 0.0f);
    }
}

// ---------------- layer1 GEMM pair: s_part = h@Ws1, xn = h@Wn1 ----------------
template <int K>
__global__ __launch_bounds__(256) void sage_layer1(const float* __restrict__ h,   // [N,K]
                                                   const float* __restrict__ Ws,  // [K,64]
                                                   const float* __restrict__ Wn,  // [K,64]
                                                   float* __restrict__ s_part,    // [N,64]
                                                   float* __restrict__ xn) {      // [N,64]
    int wid = (blockIdx.x * blockDim.x + threadIdx.x) >> 6;
    int lane = threadIdx.x & 63;
    int n0 = wid * NT;
    if (n0 >= NN) return;
    float acc1[NT] = {};
    float acc2[NT] = {};
    for (int k = 0; k < K; ++k) {
        float w1 = Ws[k * 64 + lane];
        float w2 = Wn[k * 64 + lane];
#pragma unroll
        for (int i = 0; i < NT; ++i) {
            float hv = h[(n0 + i) * K + k];
            acc1[i] = fmaf(hv, w1, acc1[i]);
            acc2[i] = fmaf(hv, w2, acc2[i]);
        }
    }
#pragma unroll
    for (int i = 0; i < NT; ++i) {
        s_part[(n0 + i) * 64 + lane] = acc1[i];
        xn[(n0 + i) * 64 + lane] = acc2[i];
    }
}

// ---------------- combine: out = s_part + agg1*inv_deg + b ----------------
__global__ __launch_bounds__(256) void combine_kernel(const float* __restrict__ s_part,
                                                      const float* __restrict__ agg1,
                                                      const float* __restrict__ invd,
                                                      const float* __restrict__ bias,
                                                      float* __restrict__ out) {
    int t = blockIdx.x * blockDim.x + threadIdx.x;
    if (t >= NN * DD) return;
    int n = t >> 6, d = t & 63;
    out[t] = s_part[t] + agg1[t] * invd[n] + bias[d];
}

// ---------------- attention reduction, stage 1: per-block partial sums ----------------
// grid = ATT_BLOCKS x 256. Each wave handles NN/(ATT_BLOCKS*4) nodes; registers ->
// wave shuffle-reduce -> LDS across 4 waves -> one float2 partial per block. NO atomics.
__global__ __launch_bounds__(256) void att_stage1(const float* __restrict__ pr,
                                                  const float* __restrict__ cc,
                                                  const float* __restrict__ ap,
                                                  const float* __restrict__ attW,
                                                  const float* __restrict__ attb,
                                                  float2* __restrict__ partial) {
    __shared__ float red[8];
    int lane = threadIdx.x & 63;
    int wv = threadIdx.x >> 6;               // 0..3
    int gw = blockIdx.x * 4 + wv;            // global wave id, 0..ATT_BLOCKS*4-1
    const int nwaves = ATT_BLOCKS * 4;
    float b = attb[lane];
    float c0 = 0.f, c1 = 0.f;
    for (int n = gw; n < NN; n += nwaves) {
        float p0 = 0.f, p1 = 0.f;
        for (int k = 0; k < DD; ++k) {
            float w = attW[k * DD + lane];
            p0 = fmaf(pr[n * DD + k], w, p0);
            p1 = fmaf(cc[n * DD + k], w, p1);
        }
        float a = ap[n * DD + lane];
        c0 += a * tanhf(p0 + b);
        c1 += a * tanhf(p1 + b);
    }
#pragma unroll
    for (int off = 32; off; off >>= 1) {
        c0 += __shfl_xor(c0, off);
        c1 += __shfl_xor(c1, off);
    }
    if (lane == 0) { red[wv * 2] = c0; red[wv * 2 + 1] = c1; }
    __syncthreads();
    if (threadIdx.x == 0) {
        float s0 = red[0] + red[2] + red[4] + red[6];
        float s1 = red[1] + red[3] + red[5] + red[7];
        partial[blockIdx.x] = make_float2(s0, s1);
    }
}

// ---------------- attention reduction, stage 2: reduce partials -> w_acc[2] ----------------
__global__ __launch_bounds__(64) void att_stage2(const float2* __restrict__ partial,
                                                 float* __restrict__ w_acc) {
    int lane = threadIdx.x;
    float s0 = 0.f, s1 = 0.f;
    for (int i = lane; i < ATT_BLOCKS; i += 64) {
        float2 p = partial[i];
        s0 += p.x; s1 += p.y;
    }
#pragma unroll
    for (int off = 32; off; off >>= 1) {
        s0 += __shfl_xor(s0, off);
        s1 += __shfl_xor(s1, off);
    }
    if (lane == 0) { w_acc[0] = s0; w_acc[1] = s1; }
}

// ---------------- final: beta = softmax(w/N); out = b0*pr + b1*cc ----------------
__global__ __launch_bounds__(256) void final_kernel(const float* __restrict__ pr,
                                                    const float* __restrict__ cc,
                                                    const float* __restrict__ w_acc,
                                                    float* __restrict__ out) {
    int t = blockIdx.x * blockDim.x + threadIdx.x;
    if (t >= NN * DD) return;
    float w0 = w_acc[0] * (1.0f / NN);
    float w1 = w_acc[1] * (1.0f / NN);
    float m = fmaxf(w0, w1);
    float e0 = __expf(w0 - m), e1 = __expf(w1 - m);
    float inv = 1.0f / (e0 + e1);
    out[t] = (e0 * pr[t] + e1 * cc[t]) * inv;
}

extern "C" void kernel_launch(void* const* d_in, const int* in_sizes, int n_in,
                              void* d_out, int out_size, void* d_ws, size_t ws_size,
                              hipStream_t stream) {
    const float* k_emb  = (const float*)d_in[0];
    const int*   pr_src = (const int*)d_in[1];
    const int*   pr_dst = (const int*)d_in[2];
    const float* pr_ew  = (const float*)d_in[3];
    const int*   cc_src = (const int*)d_in[4];
    const int*   cc_dst = (const int*)d_in[5];
    const float* cc_ew  = (const float*)d_in[6];
    const int*   sps_src = (const int*)d_in[7];
    const int*   sps_dst = (const int*)d_in[8];
    const float* pr_Ws0 = (const float*)d_in[9];
    const float* pr_Wn0 = (const float*)d_in[10];
    const float* pr_b0  = (const float*)d_in[11];
    const float* pr_Ws1 = (const float*)d_in[12];
    const float* pr_Wn1 = (const float*)d_in[13];
    const float* pr_b1  = (const float*)d_in[14];
    const float* cc_Ws0 = (const float*)d_in[15];
    const float* cc_Wn0 = (const float*)d_in[16];
    const float* cc_b0  = (const float*)d_in[17];
    const float* cc_Ws1 = (const float*)d_in[18];
    const float* cc_Wn1 = (const float*)d_in[19];
    const float* cc_b1  = (const float*)d_in[20];
    const float* ap_Ws0 = (const float*)d_in[21];
    const float* ap_Wn0 = (const float*)d_in[22];
    const float* ap_b0  = (const float*)d_in[23];
    const float* ap_Ws1 = (const float*)d_in[24];
    const float* ap_Wn1 = (const float*)d_in[25];
    const float* ap_b1  = (const float*)d_in[26];
    const float* att_W  = (const float*)d_in[27];
    const float* att_b  = (const float*)d_in[28];
    float* out = (float*)d_out;

    // workspace layout (floats)
    float* ws = (float*)d_ws;
    float* deg_pr = ws;                    // N
    float* deg_cc = deg_pr + NN;           // N
    float* deg_ap = deg_cc + NN;           // N
    float* w_acc  = deg_ap + NN;           // 2 (+pad)
    float2* att_partial = (float2*)(w_acc + 16);  // ATT_BLOCKS float2
    float* agg0   = (float*)(att_partial + ATT_BLOCKS + 1);   // N*64
    float* agg1   = agg0 + NN * DD;        // N*64
    float* xn     = agg1 + NN * DD;        // N*64
    float* s_part = xn + NN * DD;          // N*64
    float* out_pr = s_part + NN * DD;      // N*64
    float* out_cc = out_pr + NN * DD;      // N*64
    float* out_ap = out_cc + NN * DD;      // N*64
    float* h1     = out_ap + NN * DD;      // N*512

    const int TB = 256;
    const int blocks_E   = EE / TB;                 // 1250
    const int blocks_EL  = (EE * 64) / TB;          // 80000
    const int blocks_ND  = (NN * DD) / TB;          // 5000
    const int blocks_g0b = (NN / NT) * (HH / 64) * 64 / TB;  // 5000
    const int blocks_g64 = (NN / NT) * 64 / TB;     // 625

    // ---- degrees ----
    hipMemsetAsync(deg_pr, 0, 3 * NN * sizeof(float), stream);
    degree_kernel<<<blocks_E, TB, 0, stream>>>(pr_dst, deg_pr);
    degree_kernel<<<blocks_E, TB, 0, stream>>>(cc_dst, deg_cc);
    degree_kernel<<<blocks_E, TB, 0, stream>>>(sps_dst, deg_ap);
    inv_kernel<<<(3 * NN + TB - 1) / TB, TB, 0, stream>>>(deg_pr, 3 * NN);

    // ---- pr branch ----
    hipMemsetAsync(agg0, 0, NN * DD * sizeof(float), stream);
    scatter_kernel<<<blocks_EL, TB, 0, stream>>>(k_emb, pr_src, pr_dst, pr_ew, agg0);
    sage_layer0<DD, HH><<<blocks_g0b, TB, 0, stream>>>(k_emb, agg0, deg_pr, pr_Ws0, pr_Wn0, pr_b0, h1);
    sage_layer1<HH><<<blocks_g64, TB, 0, stream>>>(h1, pr_Ws1, pr_Wn1, s_part, xn);
    hipMemsetAsync(agg1, 0, NN * DD * sizeof(float), stream);
    scatter_kernel<<<blocks_EL, TB, 0, stream>>>(xn, pr_src, pr_dst, pr_ew, agg1);
    combine_kernel<<<blocks_ND, TB, 0, stream>>>(s_part, agg1, deg_pr, pr_b1, out_pr);

    // ---- cc branch ----
    hipMemsetAsync(agg0, 0, NN * DD * sizeof(float), stream);
    scatter_kernel<<<blocks_EL, TB, 0, stream>>>(k_emb, cc_src, cc_dst, cc_ew, agg0);
    sage_layer0<DD, HH><<<blocks_g0b, TB, 0, stream>>>(k_emb, agg0, deg_cc, cc_Ws0, cc_Wn0, cc_b0, h1);
    sage_layer1<HH><<<blocks_g64, TB, 0, stream>>>(h1, cc_Ws1, cc_Wn1, s_part, xn);
    hipMemsetAsync(agg1, 0, NN * DD * sizeof(float), stream);
    scatter_kernel<<<blocks_EL, TB, 0, stream>>>(xn, cc_src, cc_dst, cc_ew, agg1);
    combine_kernel<<<blocks_ND, TB, 0, stream>>>(s_part, agg1, deg_cc, cc_b1, out_cc);

    // ---- ap branch (64->64->64, no edge weights) ----
    hipMemsetAsync(agg0, 0, NN * DD * sizeof(float), stream);
    scatter_kernel<<<blocks_EL, TB, 0, stream>>>(k_emb, sps_src, sps_dst, nullptr, agg0);
    sage_layer0<DD, DD><<<blocks_g64, TB, 0, stream>>>(k_emb, agg0, deg_ap, ap_Ws0, ap_Wn0, ap_b0, h1);
    sage_layer1<DD><<<blocks_g64, TB, 0, stream>>>(h1, ap_Ws1, ap_Wn1, s_part, xn);
    hipMemsetAsync(agg1, 0, NN * DD * sizeof(float), stream);
    scatter_kernel<<<blocks_EL, TB, 0, stream>>>(xn, sps_src, sps_dst, nullptr, agg1);
    combine_kernel<<<blocks_ND, TB, 0, stream>>>(s_part, agg1, deg_ap, ap_b1, out_ap);

    // ---- attention fusion (two-stage reduction, no same-address atomics) ----
    att_stage1<<<ATT_BLOCKS, TB, 0, stream>>>(out_pr, out_cc, out_ap, att_W, att_b, att_partial);
    att_stage2<<<1, 64, 0, stream>>>(att_partial, w_acc);
    final_kernel<<<blocks_ND, TB, 0, stream>>>(out_pr, out_cc, w_acc, out);
}

// Round 5
// 853.065 us; speedup vs baseline: 2.5621x; 2.1056x over previous
//
#include <hip/hip_runtime.h>

#define NN 20000   // nodes
#define DD 64      // emb dim
#define HH 512     // hidden
#define EE 320000  // edges per graph
#define ATT_BLOCKS 625

typedef __attribute__((ext_vector_type(8))) short short8;   // 8 bf16 = 4 VGPR
typedef __attribute__((ext_vector_type(4))) float f32x4;

__device__ __forceinline__ ushort f2bf(float f) {
    union { float f; unsigned u; } v; v.f = f;
    unsigned r = v.u + 0x7FFF + ((v.u >> 16) & 1);   // RNE
    return (ushort)(r >> 16);
}
__device__ __forceinline__ float bf2f(ushort h) {
    union { unsigned u; float f; } v; v.u = ((unsigned)h) << 16;
    return v.f;
}
// split fp32 into hi+lo bf16 (f - hi is exactly representable; hi+lo ~ 17-bit mantissa)
__device__ __forceinline__ void split_bf(float f, ushort& hi, ushort& lo) {
    hi = f2bf(f);
    lo = f2bf(f - bf2f(hi));
}

// ---------------- degree ----------------
__global__ __launch_bounds__(256) void degree_kernel(const int* __restrict__ dst,
                                                     float* __restrict__ deg) {
    int e = blockIdx.x * blockDim.x + threadIdx.x;
    if (e < EE) unsafeAtomicAdd(&deg[dst[e]], 1.0f);
}

__global__ __launch_bounds__(256) void inv_kernel(float* __restrict__ deg, int n) {
    int i = blockIdx.x * blockDim.x + threadIdx.x;
    if (i < n) deg[i] = 1.0f / fmaxf(deg[i], 1.0f);
}

// ---------------- scatter-add (push aggregation), fp32 ----------------
__global__ __launch_bounds__(256) void scatter_kernel(const float* __restrict__ x,
                                                      const int* __restrict__ src,
                                                      const int* __restrict__ dst,
                                                      const float* __restrict__ ew,
                                                      float* __restrict__ agg) {
    int t = blockIdx.x * blockDim.x + threadIdx.x;
    int e = t >> 6, lane = t & 63;
    if (e >= EE) return;
    int s = src[e], d = dst[e];
    float v = x[s * DD + lane];
    if (ew) v *= ew[e];
    unsafeAtomicAdd(&agg[d * DD + lane], v);
}

// ---------------- bf16 hi/lo packing ----------------
__global__ __launch_bounds__(256) void cast_x_kernel(const float* __restrict__ x,
                                                     ushort* __restrict__ xh,
                                                     ushort* __restrict__ xl) {
    int t = blockIdx.x * blockDim.x + threadIdx.x;
    if (t >= NN * DD) return;
    int n = t >> 6, d = t & 63;
    ushort hi, lo; split_bf(x[t], hi, lo);
    xh[n * 128 + d] = hi;
    xl[n * 128 + d] = lo;
}

__global__ __launch_bounds__(256) void cast_agg_kernel(const float* __restrict__ agg,
                                                       const float* __restrict__ invd,
                                                       ushort* __restrict__ xh,
                                                       ushort* __restrict__ xl) {
    int t = blockIdx.x * blockDim.x + threadIdx.x;
    if (t >= NN * DD) return;
    int n = t >> 6, d = t & 63;
    ushort hi, lo; split_bf(agg[t] * invd[n], hi, lo);
    xh[n * 128 + 64 + d] = hi;
    xl[n * 128 + 64 + d] = lo;
}

// Wt[c][k]: k<KT/2 -> Ws[k][c], else Wn[k-KT/2][c]   (stacked, transposed)
template <int KT, int NC>
__global__ __launch_bounds__(256) void pack_w0(const float* __restrict__ Ws,
                                               const float* __restrict__ Wn,
                                               ushort* __restrict__ Wh,
                                               ushort* __restrict__ Wl) {
    int t = blockIdx.x * blockDim.x + threadIdx.x;
    if (t >= NC * KT) return;
    int c = t / KT, k = t % KT;
    float v = (k < KT / 2) ? Ws[k * NC + c] : Wn[(k - KT / 2) * NC + c];
    ushort hi, lo; split_bf(v, hi, lo);
    Wh[t] = hi; Wl[t] = lo;
}

// Wt[c][k] (c<128): c<64 -> Ws[k][c], else Wn[k][c-64]   (side-by-side, transposed)
template <int KT>
__global__ __launch_bounds__(256) void pack_w1(const float* __restrict__ Ws,
                                               const float* __restrict__ Wn,
                                               ushort* __restrict__ Wh,
                                               ushort* __restrict__ Wl) {
    int t = blockIdx.x * blockDim.x + threadIdx.x;
    if (t >= 128 * KT) return;
    int c = t / KT, k = t % KT;
    float v = (c < 64) ? Ws[k * 64 + c] : Wn[k * 64 + (c - 64)];
    ushort hi, lo; split_bf(v, hi, lo);
    Wh[t] = hi; Wl[t] = lo;
}

// ---------------- MFMA GEMM with hi/lo fp32 emulation ----------------
// C = (Ah+Al) @ (Bh+Bl)^T ~= Ah*Bh + Al*Bh + Ah*Bl  (fp32 accum)
// wave = 16 rows x 64 cols. EPI 0: bias+relu -> hi/lo bf16 out.
// EPI 1: fp32, col-group 0 -> out0[N,64], col-group 1 -> out1[N,64].
template <int K, int NC, int EPI>
__global__ __launch_bounds__(256) void mfma_gemm(const ushort* __restrict__ Ah,
                                                 const ushort* __restrict__ Al,
                                                 const ushort* __restrict__ Bh,
                                                 const ushort* __restrict__ Bl,
                                                 const float* __restrict__ bias,
                                                 void* __restrict__ out0,
                                                 void* __restrict__ out1) {
    constexpr int CG = 64;           // cols per wave
    constexpr int NCT = 4;           // 16-col tiles per wave
    constexpr int GPR = NC / CG;     // col groups
    int wid = (blockIdx.x * blockDim.x + threadIdx.x) >> 6;
    int lane = threadIdx.x & 63;
    int rt = wid / GPR;
    int cg = wid % GPR;
    if (rt >= NN / 16) return;
    int row0 = rt * 16;
    int arow = row0 + (lane & 15);
    int koff = (lane >> 4) * 8;
    f32x4 acc[NCT] = {};
    const size_t aoff = (size_t)arow * K + koff;
    const size_t boff = (size_t)(cg * CG + (lane & 15)) * K + koff;
    for (int k0 = 0; k0 < K; k0 += 32) {
        short8 ah = *(const short8*)(Ah + aoff + k0);
        short8 al = *(const short8*)(Al + aoff + k0);
#pragma unroll
        for (int c = 0; c < NCT; ++c) {
            short8 bh = *(const short8*)(Bh + boff + (size_t)(c * 16) * K + k0);
            short8 bl = *(const short8*)(Bl + boff + (size_t)(c * 16) * K + k0);
            acc[c] = __builtin_amdgcn_mfma_f32_16x16x32_bf16(ah, bh, acc[c], 0, 0, 0);
            acc[c] = __builtin_amdgcn_mfma_f32_16x16x32_bf16(al, bh, acc[c], 0, 0, 0);
            acc[c] = __builtin_amdgcn_mfma_f32_16x16x32_bf16(ah, bl, acc[c], 0, 0, 0);
        }
    }
    // C/D: col=lane&15, row=(lane>>4)*4+reg
    int ccol = lane & 15;
    int crow = row0 + (lane >> 4) * 4;
    if constexpr (EPI == 0) {
        ushort* oh = (ushort*)out0;
        ushort* ol = (ushort*)out1;
#pragma unroll
        for (int c = 0; c < NCT; ++c) {
            int col = cg * CG + c * 16 + ccol;
            float bb = bias[col];
#pragma unroll
            for (int r = 0; r < 4; ++r) {
                float v = fmaxf(acc[c][r] + bb, 0.0f);
                ushort hi, lo; split_bf(v, hi, lo);
                oh[(size_t)(crow + r) * NC + col] = hi;
                ol[(size_t)(crow + r) * NC + col] = lo;
            }
        }
    } else {
        float* o = (cg == 0) ? (float*)out0 : (float*)out1;
#pragma unroll
        for (int c = 0; c < NCT; ++c) {
            int col = c * 16 + ccol;
#pragma unroll
            for (int r = 0; r < 4; ++r) {
                o[(size_t)(crow + r) * 64 + col] = acc[c][r];
            }
        }
    }
}

// ---------------- combine (in-place): out += agg*inv_deg + b ----------------
__global__ __launch_bounds__(256) void combine_kernel(float* __restrict__ out,
                                                      const float* __restrict__ agg,
                                                      const float* __restrict__ invd,
                                                      const float* __restrict__ bias) {
    int t = blockIdx.x * blockDim.x + threadIdx.x;
    if (t >= NN * DD) return;
    int n = t >> 6, d = t & 63;
    out[t] = out[t] + agg[t] * invd[n] + bias[d];
}

// ---------------- attention reduction, stage 1 ----------------
__global__ __launch_bounds__(256) void att_stage1(const float* __restrict__ pr,
                                                  const float* __restrict__ cc,
                                                  const float* __restrict__ ap,
                                                  const float* __restrict__ attW,
                                                  const float* __restrict__ attb,
                                                  float2* __restrict__ partial) {
    __shared__ float red[8];
    int lane = threadIdx.x & 63;
    int wv = threadIdx.x >> 6;
    int gw = blockIdx.x * 4 + wv;
    const int nwaves = ATT_BLOCKS * 4;
    float b = attb[lane];
    float c0 = 0.f, c1 = 0.f;
    for (int n = gw; n < NN; n += nwaves) {
        float p0 = 0.f, p1 = 0.f;
        for (int k = 0; k < DD; ++k) {
            float w = attW[k * DD + lane];
            p0 = fmaf(pr[n * DD + k], w, p0);
            p1 = fmaf(cc[n * DD + k], w, p1);
        }
        float a = ap[n * DD + lane];
        c0 += a * tanhf(p0 + b);
        c1 += a * tanhf(p1 + b);
    }
#pragma unroll
    for (int off = 32; off; off >>= 1) {
        c0 += __shfl_xor(c0, off);
        c1 += __shfl_xor(c1, off);
    }
    if (lane == 0) { red[wv * 2] = c0; red[wv * 2 + 1] = c1; }
    __syncthreads();
    if (threadIdx.x == 0) {
        partial[blockIdx.x] = make_float2(red[0] + red[2] + red[4] + red[6],
                                          red[1] + red[3] + red[5] + red[7]);
    }
}

__global__ __launch_bounds__(64) void att_stage2(const float2* __restrict__ partial,
                                                 float* __restrict__ w_acc) {
    int lane = threadIdx.x;
    float s0 = 0.f, s1 = 0.f;
    for (int i = lane; i < ATT_BLOCKS; i += 64) {
        float2 p = partial[i];
        s0 += p.x; s1 += p.y;
    }
#pragma unroll
    for (int off = 32; off; off >>= 1) {
        s0 += __shfl_xor(s0, off);
        s1 += __shfl_xor(s1, off);
    }
    if (lane == 0) { w_acc[0] = s0; w_acc[1] = s1; }
}

// ---------------- final ----------------
__global__ __launch_bounds__(256) void final_kernel(const float* __restrict__ pr,
                                                    const float* __restrict__ cc,
                                                    const float* __restrict__ w_acc,
                                                    float* __restrict__ out) {
    int t = blockIdx.x * blockDim.x + threadIdx.x;
    if (t >= NN * DD) return;
    float w0 = w_acc[0] * (1.0f / NN);
    float w1 = w_acc[1] * (1.0f / NN);
    float m = fmaxf(w0, w1);
    float e0 = __expf(w0 - m), e1 = __expf(w1 - m);
    float inv = 1.0f / (e0 + e1);
    out[t] = (e0 * pr[t] + e1 * cc[t]) * inv;
}

extern "C" void kernel_launch(void* const* d_in, const int* in_sizes, int n_in,
                              void* d_out, int out_size, void* d_ws, size_t ws_size,
                              hipStream_t stream) {
    const float* k_emb  = (const float*)d_in[0];
    const int*   pr_src = (const int*)d_in[1];
    const int*   pr_dst = (const int*)d_in[2];
    const float* pr_ew  = (const float*)d_in[3];
    const int*   cc_src = (const int*)d_in[4];
    const int*   cc_dst = (const int*)d_in[5];
    const float* cc_ew  = (const float*)d_in[6];
    const int*   sps_src = (const int*)d_in[7];
    const int*   sps_dst = (const int*)d_in[8];
    const float* pr_Ws0 = (const float*)d_in[9];
    const float* pr_Wn0 = (const float*)d_in[10];
    const float* pr_b0  = (const float*)d_in[11];
    const float* pr_Ws1 = (const float*)d_in[12];
    const float* pr_Wn1 = (const float*)d_in[13];
    const float* pr_b1  = (const float*)d_in[14];
    const float* cc_Ws0 = (const float*)d_in[15];
    const float* cc_Wn0 = (const float*)d_in[16];
    const float* cc_b0  = (const float*)d_in[17];
    const float* cc_Ws1 = (const float*)d_in[18];
    const float* cc_Wn1 = (const float*)d_in[19];
    const float* cc_b1  = (const float*)d_in[20];
    const float* ap_Ws0 = (const float*)d_in[21];
    const float* ap_Wn0 = (const float*)d_in[22];
    const float* ap_b0  = (const float*)d_in[23];
    const float* ap_Ws1 = (const float*)d_in[24];
    const float* ap_Wn1 = (const float*)d_in[25];
    const float* ap_b1  = (const float*)d_in[26];
    const float* att_W  = (const float*)d_in[27];
    const float* att_b  = (const float*)d_in[28];
    float* out = (float*)d_out;

    // ---- workspace layout (256B-aligned blocks) ----
    char* base = (char*)d_ws;
    size_t off = 0;
    auto alloc = [&](size_t bytes) -> void* {
        void* p = base + off;
        off = (off + bytes + 255) & ~(size_t)255;
        return p;
    };
    // deg: ONE contiguous block of 3*NN floats (inv_kernel and memset treat it
    // as contiguous — R3/R4's per-array alloc left deg_ap's tail unzeroed/uninverted).
    float*  deg    = (float*)alloc((size_t)3 * NN * 4);
    float*  deg_pr = deg;
    float*  deg_cc = deg + NN;
    float*  deg_ap = deg + 2 * NN;
    float*  w_acc  = (float*)alloc(64);
    float2* att_partial = (float2*)alloc(ATT_BLOCKS * 8);
    float*  xn     = (float*)alloc((size_t)NN * DD * 4);
    float*  out_pr = (float*)alloc((size_t)NN * DD * 4);
    float*  out_cc = (float*)alloc((size_t)NN * DD * 4);
    float*  out_ap = (float*)alloc((size_t)NN * DD * 4);
    ushort* xcat_h = (ushort*)alloc((size_t)NN * 128 * 2);
    ushort* xcat_l = (ushort*)alloc((size_t)NN * 128 * 2);
    ushort* h1_h   = (ushort*)alloc((size_t)NN * HH * 2);
    ushort* h1_l   = (ushort*)alloc((size_t)NN * HH * 2);
    ushort* W0h_pr = (ushort*)alloc(512 * 128 * 2);
    ushort* W0l_pr = (ushort*)alloc(512 * 128 * 2);
    ushort* W0h_cc = (ushort*)alloc(512 * 128 * 2);
    ushort* W0l_cc = (ushort*)alloc(512 * 128 * 2);
    ushort* W0h_ap = (ushort*)alloc(64 * 128 * 2);
    ushort* W0l_ap = (ushort*)alloc(64 * 128 * 2);
    ushort* W1h_pr = (ushort*)alloc(128 * 512 * 2);
    ushort* W1l_pr = (ushort*)alloc(128 * 512 * 2);
    ushort* W1h_cc = (ushort*)alloc(128 * 512 * 2);
    ushort* W1l_cc = (ushort*)alloc(128 * 512 * 2);
    ushort* W1h_ap = (ushort*)alloc(128 * 64 * 2);
    ushort* W1l_ap = (ushort*)alloc(128 * 64 * 2);
    // agg aliases the h1_h region: live ranges are disjoint within a branch
    // (h1: [layer0 write, layer1 read]; agg: [memset after layer1, combine]).
    float*  agg = (float*)h1_h;

    const int TB = 256;
    const int blocks_E  = EE / TB;          // 1250
    const int blocks_EL = (EE * 64) / TB;   // 80000
    const int blocks_ND = (NN * DD) / TB;   // 5000
    const int g_l0_big  = (NN / 16) * (512 / 64) / 4;      // 2500
    const int g_l1      = (NN / 16) * (128 / 64) / 4;      // 625
    const int g_l0_ap   = ((NN / 16) * (64 / 64) + 3) / 4; // 313

    // ---- prologue: weight packs + x cast + degrees ----
    pack_w0<128, 512><<<256, TB, 0, stream>>>(pr_Ws0, pr_Wn0, W0h_pr, W0l_pr);
    pack_w0<128, 512><<<256, TB, 0, stream>>>(cc_Ws0, cc_Wn0, W0h_cc, W0l_cc);
    pack_w0<128, 64><<<32, TB, 0, stream>>>(ap_Ws0, ap_Wn0, W0h_ap, W0l_ap);
    pack_w1<512><<<256, TB, 0, stream>>>(pr_Ws1, pr_Wn1, W1h_pr, W1l_pr);
    pack_w1<512><<<256, TB, 0, stream>>>(cc_Ws1, cc_Wn1, W1h_cc, W1l_cc);
    pack_w1<64><<<32, TB, 0, stream>>>(ap_Ws1, ap_Wn1, W1h_ap, W1l_ap);
    cast_x_kernel<<<blocks_ND, TB, 0, stream>>>(k_emb, xcat_h, xcat_l);

    hipMemsetAsync(deg, 0, (size_t)3 * NN * sizeof(float), stream);
    degree_kernel<<<blocks_E, TB, 0, stream>>>(pr_dst, deg_pr);
    degree_kernel<<<blocks_E, TB, 0, stream>>>(cc_dst, deg_cc);
    degree_kernel<<<blocks_E, TB, 0, stream>>>(sps_dst, deg_ap);
    inv_kernel<<<(3 * NN + TB - 1) / TB, TB, 0, stream>>>(deg, 3 * NN);

    // ---- pr branch ----
    hipMemsetAsync(agg, 0, (size_t)NN * DD * 4, stream);
    scatter_kernel<<<blocks_EL, TB, 0, stream>>>(k_emb, pr_src, pr_dst, pr_ew, agg);
    cast_agg_kernel<<<blocks_ND, TB, 0, stream>>>(agg, deg_pr, xcat_h, xcat_l);
    mfma_gemm<128, 512, 0><<<g_l0_big, TB, 0, stream>>>(xcat_h, xcat_l, W0h_pr, W0l_pr, pr_b0, h1_h, h1_l);
    mfma_gemm<512, 128, 1><<<g_l1, TB, 0, stream>>>(h1_h, h1_l, W1h_pr, W1l_pr, nullptr, out_pr, xn);
    hipMemsetAsync(agg, 0, (size_t)NN * DD * 4, stream);
    scatter_kernel<<<blocks_EL, TB, 0, stream>>>(xn, pr_src, pr_dst, pr_ew, agg);
    combine_kernel<<<blocks_ND, TB, 0, stream>>>(out_pr, agg, deg_pr, pr_b1);

    // ---- cc branch ----
    hipMemsetAsync(agg, 0, (size_t)NN * DD * 4, stream);
    scatter_kernel<<<blocks_EL, TB, 0, stream>>>(k_emb, cc_src, cc_dst, cc_ew, agg);
    cast_agg_kernel<<<blocks_ND, TB, 0, stream>>>(agg, deg_cc, xcat_h, xcat_l);
    mfma_gemm<128, 512, 0><<<g_l0_big, TB, 0, stream>>>(xcat_h, xcat_l, W0h_cc, W0l_cc, cc_b0, h1_h, h1_l);
    mfma_gemm<512, 128, 1><<<g_l1, TB, 0, stream>>>(h1_h, h1_l, W1h_cc, W1l_cc, nullptr, out_cc, xn);
    hipMemsetAsync(agg, 0, (size_t)NN * DD * 4, stream);
    scatter_kernel<<<blocks_EL, TB, 0, stream>>>(xn, cc_src, cc_dst, cc_ew, agg);
    combine_kernel<<<blocks_ND, TB, 0, stream>>>(out_cc, agg, deg_cc, cc_b1);

    // ---- ap branch ----
    hipMemsetAsync(agg, 0, (size_t)NN * DD * 4, stream);
    scatter_kernel<<<blocks_EL, TB, 0, stream>>>(k_emb, sps_src, sps_dst, nullptr, agg);
    cast_agg_kernel<<<blocks_ND, TB, 0, stream>>>(agg, deg_ap, xcat_h, xcat_l);
    mfma_gemm<128, 64, 0><<<g_l0_ap, TB, 0, stream>>>(xcat_h, xcat_l, W0h_ap, W0l_ap, ap_b0, h1_h, h1_l);
    mfma_gemm<64, 128, 1><<<g_l1, TB, 0, stream>>>(h1_h, h1_l, W1h_ap, W1l_ap, nullptr, out_ap, xn);
    hipMemsetAsync(agg, 0, (size_t)NN * DD * 4, stream);
    scatter_kernel<<<blocks_EL, TB, 0, stream>>>(xn, sps_src, sps_dst, nullptr, agg);
    combine_kernel<<<blocks_ND, TB, 0, stream>>>(out_ap, agg, deg_ap, ap_b1);

    // ---- attention fusion ----
    att_stage1<<<ATT_BLOCKS, TB, 0, stream>>>(out_pr, out_cc, out_ap, att_W, att_b, att_partial);
    att_stage2<<<1, 64, 0, stream>>>(att_partial, w_acc);
    final_kernel<<<blocks_ND, TB, 0, stream>>>(out_pr, out_cc, w_acc, out);
}

// Round 6
// 658.124 us; speedup vs baseline: 3.3211x; 1.2962x over previous
//
#include <hip/hip_runtime.h>

#define NN 20000   // nodes
#define DD 64      // emb dim
#define HH 512     // hidden
#define EE 320000  // edges per graph
#define ATT_BLOCKS 625

typedef __attribute__((ext_vector_type(8))) short short8;   // 8 bf16 = 4 VGPR
typedef __attribute__((ext_vector_type(4))) float f32x4;

__device__ __forceinline__ ushort f2bf(float f) {
    union { float f; unsigned u; } v; v.f = f;
    unsigned r = v.u + 0x7FFF + ((v.u >> 16) & 1);   // RNE
    return (ushort)(r >> 16);
}
__device__ __forceinline__ float bf2f(ushort h) {
    union { unsigned u; float f; } v; v.u = ((unsigned)h) << 16;
    return v.f;
}
__device__ __forceinline__ void split_bf(float f, ushort& hi, ushort& lo) {
    hi = f2bf(f);
    lo = f2bf(f - bf2f(hi));
}

// ---------------- CSR build ----------------
__global__ __launch_bounds__(256) void hist_kernel(const int* __restrict__ dst,
                                                   int* __restrict__ cnt) {
    int e = blockIdx.x * blockDim.x + threadIdx.x;
    if (e < EE) atomicAdd(&cnt[dst[e]], 1);
}

__global__ __launch_bounds__(256) void inv_kernel(const int* __restrict__ cnt,
                                                  float* __restrict__ invd, int n) {
    int i = blockIdx.x * blockDim.x + threadIdx.x;
    if (i < n) invd[i] = 1.0f / fmaxf((float)cnt[i], 1.0f);
}

// one block per graph: exclusive prefix-sum cnt[g*NN..] -> rowptr[g*(NN+1)..]
__global__ __launch_bounds__(1024) void scan_kernel(const int* __restrict__ cnt,
                                                    int* __restrict__ rowptr) {
    __shared__ int part[1024];
    int g = blockIdx.x;
    const int* c = cnt + g * NN;
    int* rp = rowptr + g * (NN + 1);
    int tid = threadIdx.x;
    const int CH = (NN + 1023) / 1024;   // 20
    int i0 = tid * CH;
    int s = 0;
    for (int i = 0; i < CH; ++i) { int idx = i0 + i; if (idx < NN) s += c[idx]; }
    part[tid] = s;
    __syncthreads();
    for (int off = 1; off < 1024; off <<= 1) {
        int v = (tid >= off) ? part[tid - off] : 0;
        __syncthreads();
        part[tid] += v;
        __syncthreads();
    }
    int run = (tid > 0) ? part[tid - 1] : 0;
    for (int i = 0; i < CH; ++i) {
        int idx = i0 + i;
        if (idx < NN) { rp[idx] = run; run += c[idx]; }
    }
    if (tid == 1023) rp[NN] = part[1023];
}

__global__ __launch_bounds__(256) void bucket_kernel(const int* __restrict__ src,
                                                     const int* __restrict__ dst,
                                                     const float* __restrict__ ew,
                                                     const int* __restrict__ rp,
                                                     int* __restrict__ cursor,
                                                     int* __restrict__ src_s,
                                                     float* __restrict__ ew_s) {
    int e = blockIdx.x * blockDim.x + threadIdx.x;
    if (e >= EE) return;
    int d = dst[e];
    int pos = rp[d] + atomicAdd(&cursor[d], 1);
    src_s[pos] = src[e];
    ew_s[pos] = ew ? ew[e] : 1.0f;
}

// ---------------- pull aggregation (wave per node, lane = feature) ----------------
// writes bf16 hi/lo agg half of xcat: xcat[n][64:128] = split(acc*invd[n])
__global__ __launch_bounds__(256) void pull_cast(const float* __restrict__ x,
                                                 const int* __restrict__ rp,
                                                 const int* __restrict__ src_s,
                                                 const float* __restrict__ ew_s,
                                                 const float* __restrict__ invd,
                                                 ushort* __restrict__ xh,
                                                 ushort* __restrict__ xl) {
    int wid = (blockIdx.x * blockDim.x + threadIdx.x) >> 6;
    int lane = threadIdx.x & 63;
    if (wid >= NN) return;
    int beg = rp[wid], end = rp[wid + 1];
    float acc = 0.f;
    for (int i = beg; i < end; ++i) {
        int s = src_s[i];
        float w = ew_s[i];
        acc = fmaf(x[s * DD + lane], w, acc);
    }
    ushort hi, lo; split_bf(acc * invd[wid], hi, lo);
    xh[wid * 128 + 64 + lane] = hi;
    xl[wid * 128 + 64 + lane] = lo;
}

// out[n] += acc*invd[n] + bias   (fused layer-1 aggregation + combine)
__global__ __launch_bounds__(256) void pull_combine(const float* __restrict__ x,
                                                    const int* __restrict__ rp,
                                                    const int* __restrict__ src_s,
                                                    const float* __restrict__ ew_s,
                                                    const float* __restrict__ invd,
                                                    const float* __restrict__ bias,
                                                    float* __restrict__ out) {
    int wid = (blockIdx.x * blockDim.x + threadIdx.x) >> 6;
    int lane = threadIdx.x & 63;
    if (wid >= NN) return;
    int beg = rp[wid], end = rp[wid + 1];
    float acc = 0.f;
    for (int i = beg; i < end; ++i) {
        int s = src_s[i];
        float w = ew_s[i];
        acc = fmaf(x[s * DD + lane], w, acc);
    }
    out[wid * DD + lane] += acc * invd[wid] + bias[lane];
}

// ---------------- bf16 hi/lo packing ----------------
__global__ __launch_bounds__(256) void cast_x_kernel(const float* __restrict__ x,
                                                     ushort* __restrict__ xh,
                                                     ushort* __restrict__ xl) {
    int t = blockIdx.x * blockDim.x + threadIdx.x;
    if (t >= NN * DD) return;
    int n = t >> 6, d = t & 63;
    ushort hi, lo; split_bf(x[t], hi, lo);
    xh[n * 128 + d] = hi;
    xl[n * 128 + d] = lo;
}

// Wt[c][k]: k<KT/2 -> Ws[k][c], else Wn[k-KT/2][c]   (stacked, transposed)
template <int KT, int NC>
__global__ __launch_bounds__(256) void pack_w0(const float* __restrict__ Ws,
                                               const float* __restrict__ Wn,
                                               ushort* __restrict__ Wh,
                                               ushort* __restrict__ Wl) {
    int t = blockIdx.x * blockDim.x + threadIdx.x;
    if (t >= NC * KT) return;
    int c = t / KT, k = t % KT;
    float v = (k < KT / 2) ? Ws[k * NC + c] : Wn[(k - KT / 2) * NC + c];
    ushort hi, lo; split_bf(v, hi, lo);
    Wh[t] = hi; Wl[t] = lo;
}

// Wt[c][k] (c<128): c<64 -> Ws[k][c], else Wn[k][c-64]   (side-by-side, transposed)
template <int KT>
__global__ __launch_bounds__(256) void pack_w1(const float* __restrict__ Ws,
                                               const float* __restrict__ Wn,
                                               ushort* __restrict__ Wh,
                                               ushort* __restrict__ Wl) {
    int t = blockIdx.x * blockDim.x + threadIdx.x;
    if (t >= 128 * KT) return;
    int c = t / KT, k = t % KT;
    float v = (c < 64) ? Ws[k * 64 + c] : Wn[k * 64 + (c - 64)];
    ushort hi, lo; split_bf(v, hi, lo);
    Wh[t] = hi; Wl[t] = lo;
}

// ---------------- MFMA GEMM with hi/lo fp32 emulation ----------------
template <int K, int NC, int EPI>
__global__ __launch_bounds__(256) void mfma_gemm(const ushort* __restrict__ Ah,
                                                 const ushort* __restrict__ Al,
                                                 const ushort* __restrict__ Bh,
                                                 const ushort* __restrict__ Bl,
                                                 const float* __restrict__ bias,
                                                 void* __restrict__ out0,
                                                 void* __restrict__ out1) {
    constexpr int CG = 64;
    constexpr int NCT = 4;
    constexpr int GPR = NC / CG;
    int wid = (blockIdx.x * blockDim.x + threadIdx.x) >> 6;
    int lane = threadIdx.x & 63;
    int rt = wid / GPR;
    int cg = wid % GPR;
    if (rt >= NN / 16) return;
    int row0 = rt * 16;
    int arow = row0 + (lane & 15);
    int koff = (lane >> 4) * 8;
    f32x4 acc[NCT] = {};
    const size_t aoff = (size_t)arow * K + koff;
    const size_t boff = (size_t)(cg * CG + (lane & 15)) * K + koff;
    for (int k0 = 0; k0 < K; k0 += 32) {
        short8 ah = *(const short8*)(Ah + aoff + k0);
        short8 al = *(const short8*)(Al + aoff + k0);
#pragma unroll
        for (int c = 0; c < NCT; ++c) {
            short8 bh = *(const short8*)(Bh + boff + (size_t)(c * 16) * K + k0);
            short8 bl = *(const short8*)(Bl + boff + (size_t)(c * 16) * K + k0);
            acc[c] = __builtin_amdgcn_mfma_f32_16x16x32_bf16(ah, bh, acc[c], 0, 0, 0);
            acc[c] = __builtin_amdgcn_mfma_f32_16x16x32_bf16(al, bh, acc[c], 0, 0, 0);
            acc[c] = __builtin_amdgcn_mfma_f32_16x16x32_bf16(ah, bl, acc[c], 0, 0, 0);
        }
    }
    int ccol = lane & 15;
    int crow = row0 + (lane >> 4) * 4;
    if constexpr (EPI == 0) {
        ushort* oh = (ushort*)out0;
        ushort* ol = (ushort*)out1;
#pragma unroll
        for (int c = 0; c < NCT; ++c) {
            int col = cg * CG + c * 16 + ccol;
            float bb = bias[col];
#pragma unroll
            for (int r = 0; r < 4; ++r) {
                float v = fmaxf(acc[c][r] + bb, 0.0f);
                ushort hi, lo; split_bf(v, hi, lo);
                oh[(size_t)(crow + r) * NC + col] = hi;
                ol[(size_t)(crow + r) * NC + col] = lo;
            }
        }
    } else {
        float* o = (cg == 0) ? (float*)out0 : (float*)out1;
#pragma unroll
        for (int c = 0; c < NCT; ++c) {
            int col = c * 16 + ccol;
#pragma unroll
            for (int r = 0; r < 4; ++r) {
                o[(size_t)(crow + r) * 64 + col] = acc[c][r];
            }
        }
    }
}

// ---------------- attention reduction ----------------
__global__ __launch_bounds__(256) void att_stage1(const float* __restrict__ pr,
                                                  const float* __restrict__ cc,
                                                  const float* __restrict__ ap,
                                                  const float* __restrict__ attW,
                                                  const float* __restrict__ attb,
                                                  float2* __restrict__ partial) {
    __shared__ float red[8];
    int lane = threadIdx.x & 63;
    int wv = threadIdx.x >> 6;
    int gw = blockIdx.x * 4 + wv;
    const int nwaves = ATT_BLOCKS * 4;
    float b = attb[lane];
    float c0 = 0.f, c1 = 0.f;
    for (int n = gw; n < NN; n += nwaves) {
        float p0 = 0.f, p1 = 0.f;
        for (int k = 0; k < DD; ++k) {
            float w = attW[k * DD + lane];
            p0 = fmaf(pr[n * DD + k], w, p0);
            p1 = fmaf(cc[n * DD + k], w, p1);
        }
        float a = ap[n * DD + lane];
        c0 += a * tanhf(p0 + b);
        c1 += a * tanhf(p1 + b);
    }
#pragma unroll
    for (int off = 32; off; off >>= 1) {
        c0 += __shfl_xor(c0, off);
        c1 += __shfl_xor(c1, off);
    }
    if (lane == 0) { red[wv * 2] = c0; red[wv * 2 + 1] = c1; }
    __syncthreads();
    if (threadIdx.x == 0) {
        partial[blockIdx.x] = make_float2(red[0] + red[2] + red[4] + red[6],
                                          red[1] + red[3] + red[5] + red[7]);
    }
}

__global__ __launch_bounds__(64) void att_stage2(const float2* __restrict__ partial,
                                                 float* __restrict__ w_acc) {
    int lane = threadIdx.x;
    float s0 = 0.f, s1 = 0.f;
    for (int i = lane; i < ATT_BLOCKS; i += 64) {
        float2 p = partial[i];
        s0 += p.x; s1 += p.y;
    }
#pragma unroll
    for (int off = 32; off; off >>= 1) {
        s0 += __shfl_xor(s0, off);
        s1 += __shfl_xor(s1, off);
    }
    if (lane == 0) { w_acc[0] = s0; w_acc[1] = s1; }
}

// ---------------- final (in-place on pr=out) ----------------
__global__ __launch_bounds__(256) void final_kernel(float* __restrict__ pr_out,
                                                    const float* __restrict__ cc,
                                                    const float* __restrict__ w_acc) {
    int t = blockIdx.x * blockDim.x + threadIdx.x;
    if (t >= NN * DD) return;
    float w0 = w_acc[0] * (1.0f / NN);
    float w1 = w_acc[1] * (1.0f / NN);
    float m = fmaxf(w0, w1);
    float e0 = __expf(w0 - m), e1 = __expf(w1 - m);
    float inv = 1.0f / (e0 + e1);
    pr_out[t] = (e0 * pr_out[t] + e1 * cc[t]) * inv;
}

extern "C" void kernel_launch(void* const* d_in, const int* in_sizes, int n_in,
                              void* d_out, int out_size, void* d_ws, size_t ws_size,
                              hipStream_t stream) {
    const float* k_emb  = (const float*)d_in[0];
    const int*   pr_src = (const int*)d_in[1];
    const int*   pr_dst = (const int*)d_in[2];
    const float* pr_ew  = (const float*)d_in[3];
    const int*   cc_src = (const int*)d_in[4];
    const int*   cc_dst = (const int*)d_in[5];
    const float* cc_ew  = (const float*)d_in[6];
    const int*   sps_src = (const int*)d_in[7];
    const int*   sps_dst = (const int*)d_in[8];
    const float* pr_Ws0 = (const float*)d_in[9];
    const float* pr_Wn0 = (const float*)d_in[10];
    const float* pr_b0  = (const float*)d_in[11];
    const float* pr_Ws1 = (const float*)d_in[12];
    const float* pr_Wn1 = (const float*)d_in[13];
    const float* pr_b1  = (const float*)d_in[14];
    const float* cc_Ws0 = (const float*)d_in[15];
    const float* cc_Wn0 = (const float*)d_in[16];
    const float* cc_b0  = (const float*)d_in[17];
    const float* cc_Ws1 = (const float*)d_in[18];
    const float* cc_Wn1 = (const float*)d_in[19];
    const float* cc_b1  = (const float*)d_in[20];
    const float* ap_Ws0 = (const float*)d_in[21];
    const float* ap_Wn0 = (const float*)d_in[22];
    const float* ap_b0  = (const float*)d_in[23];
    const float* ap_Ws1 = (const float*)d_in[24];
    const float* ap_Wn1 = (const float*)d_in[25];
    const float* ap_b1  = (const float*)d_in[26];
    const float* att_W  = (const float*)d_in[27];
    const float* att_b  = (const float*)d_in[28];
    float* out = (float*)d_out;

    // ---- workspace layout (256B-aligned; ~76 MB <= proven 77 MB) ----
    char* base = (char*)d_ws;
    size_t off = 0;
    auto alloc = [&](size_t bytes) -> void* {
        void* p = base + off;
        off = (off + bytes + 255) & ~(size_t)255;
        return p;
    };
    float*  invd   = (float*)alloc((size_t)3 * NN * 4);   // [3N], per graph
    int*    cnt    = (int*)alloc((size_t)3 * NN * 4);     // histogram, reused as cursor
    int*    rowptr = (int*)alloc((size_t)3 * (NN + 1) * 4);
    int*    src_s  = (int*)alloc((size_t)3 * EE * 4);     // dst-sorted src ids
    float*  ew_s   = (float*)alloc((size_t)3 * EE * 4);   // dst-sorted edge weights
    float*  w_acc  = (float*)alloc(64);
    float2* att_partial = (float2*)alloc(ATT_BLOCKS * 8);
    float*  xn     = (float*)alloc((size_t)NN * DD * 4);
    float*  out_cc = (float*)alloc((size_t)NN * DD * 4);
    float*  out_ap = (float*)alloc((size_t)NN * DD * 4);
    ushort* xcat_h = (ushort*)alloc((size_t)NN * 128 * 2);
    ushort* xcat_l = (ushort*)alloc((size_t)NN * 128 * 2);
    ushort* h1_h   = (ushort*)alloc((size_t)NN * HH * 2);
    ushort* h1_l   = (ushort*)alloc((size_t)NN * HH * 2);
    ushort* W0h_pr = (ushort*)alloc(512 * 128 * 2);
    ushort* W0l_pr = (ushort*)alloc(512 * 128 * 2);
    ushort* W0h_cc = (ushort*)alloc(512 * 128 * 2);
    ushort* W0l_cc = (ushort*)alloc(512 * 128 * 2);
    ushort* W0h_ap = (ushort*)alloc(64 * 128 * 2);
    ushort* W0l_ap = (ushort*)alloc(64 * 128 * 2);
    ushort* W1h_pr = (ushort*)alloc(128 * 512 * 2);
    ushort* W1l_pr = (ushort*)alloc(128 * 512 * 2);
    ushort* W1h_cc = (ushort*)alloc(128 * 512 * 2);
    ushort* W1l_cc = (ushort*)alloc(128 * 512 * 2);
    ushort* W1h_ap = (ushort*)alloc(128 * 64 * 2);
    ushort* W1l_ap = (ushort*)alloc(128 * 64 * 2);
    float*  out_pr = out;   // pr result lives in d_out (fully rewritten each call)

    // per-graph CSR views (graph order: 0=pr, 1=cc, 2=sps)
    float* invd_pr = invd;            float* invd_cc = invd + NN;        float* invd_ap = invd + 2 * NN;
    int*   rp_pr   = rowptr;          int*   rp_cc   = rowptr + (NN+1);  int*   rp_ap   = rowptr + 2*(NN+1);
    int*   ss_pr   = src_s;           int*   ss_cc   = src_s + EE;       int*   ss_ap   = src_s + 2*EE;
    float* es_pr   = ew_s;            float* es_cc   = ew_s + EE;        float* es_ap   = ew_s + 2*EE;

    const int TB = 256;
    const int blocks_E  = EE / TB;          // 1250
    const int blocks_ND = (NN * DD) / TB;   // 5000
    const int blocks_pull = (NN * 64) / TB; // 5000 (wave per node, 4 waves/block)
    const int g_l0_big  = (NN / 16) * (512 / 64) / 4;      // 2500
    const int g_l1      = (NN / 16) * (128 / 64) / 4;      // 625
    const int g_l0_ap   = ((NN / 16) * (64 / 64) + 3) / 4; // 313

    // ---- prologue: weight packs + x cast + CSR build ----
    pack_w0<128, 512><<<256, TB, 0, stream>>>(pr_Ws0, pr_Wn0, W0h_pr, W0l_pr);
    pack_w0<128, 512><<<256, TB, 0, stream>>>(cc_Ws0, cc_Wn0, W0h_cc, W0l_cc);
    pack_w0<128, 64><<<32, TB, 0, stream>>>(ap_Ws0, ap_Wn0, W0h_ap, W0l_ap);
    pack_w1<512><<<256, TB, 0, stream>>>(pr_Ws1, pr_Wn1, W1h_pr, W1l_pr);
    pack_w1<512><<<256, TB, 0, stream>>>(cc_Ws1, cc_Wn1, W1h_cc, W1l_cc);
    pack_w1<64><<<32, TB, 0, stream>>>(ap_Ws1, ap_Wn1, W1h_ap, W1l_ap);
    cast_x_kernel<<<blocks_ND, TB, 0, stream>>>(k_emb, xcat_h, xcat_l);

    hipMemsetAsync(cnt, 0, (size_t)3 * NN * 4, stream);
    hist_kernel<<<blocks_E, TB, 0, stream>>>(pr_dst, cnt);
    hist_kernel<<<blocks_E, TB, 0, stream>>>(cc_dst, cnt + NN);
    hist_kernel<<<blocks_E, TB, 0, stream>>>(sps_dst, cnt + 2 * NN);
    inv_kernel<<<(3 * NN + TB - 1) / TB, TB, 0, stream>>>(cnt, invd, 3 * NN);
    scan_kernel<<<3, 1024, 0, stream>>>(cnt, rowptr);
    hipMemsetAsync(cnt, 0, (size_t)3 * NN * 4, stream);   // cnt becomes cursor
    bucket_kernel<<<blocks_E, TB, 0, stream>>>(pr_src, pr_dst, pr_ew, rp_pr, cnt, ss_pr, es_pr);
    bucket_kernel<<<blocks_E, TB, 0, stream>>>(cc_src, cc_dst, cc_ew, rp_cc, cnt + NN, ss_cc, es_cc);
    bucket_kernel<<<blocks_E, TB, 0, stream>>>(sps_src, sps_dst, nullptr, rp_ap, cnt + 2 * NN, ss_ap, es_ap);

    // ---- pr branch ----
    pull_cast<<<blocks_pull, TB, 0, stream>>>(k_emb, rp_pr, ss_pr, es_pr, invd_pr, xcat_h, xcat_l);
    mfma_gemm<128, 512, 0><<<g_l0_big, TB, 0, stream>>>(xcat_h, xcat_l, W0h_pr, W0l_pr, pr_b0, h1_h, h1_l);
    mfma_gemm<512, 128, 1><<<g_l1, TB, 0, stream>>>(h1_h, h1_l, W1h_pr, W1l_pr, nullptr, out_pr, xn);
    pull_combine<<<blocks_pull, TB, 0, stream>>>(xn, rp_pr, ss_pr, es_pr, invd_pr, pr_b1, out_pr);

    // ---- cc branch ----
    pull_cast<<<blocks_pull, TB, 0, stream>>>(k_emb, rp_cc, ss_cc, es_cc, invd_cc, xcat_h, xcat_l);
    mfma_gemm<128, 512, 0><<<g_l0_big, TB, 0, stream>>>(xcat_h, xcat_l, W0h_cc, W0l_cc, cc_b0, h1_h, h1_l);
    mfma_gemm<512, 128, 1><<<g_l1, TB, 0, stream>>>(h1_h, h1_l, W1h_cc, W1l_cc, nullptr, out_cc, xn);
    pull_combine<<<blocks_pull, TB, 0, stream>>>(xn, rp_cc, ss_cc, es_cc, invd_cc, cc_b1, out_cc);

    // ---- ap branch ----
    pull_cast<<<blocks_pull, TB, 0, stream>>>(k_emb, rp_ap, ss_ap, es_ap, invd_ap, xcat_h, xcat_l);
    mfma_gemm<128, 64, 0><<<g_l0_ap, TB, 0, stream>>>(xcat_h, xcat_l, W0h_ap, W0l_ap, ap_b0, h1_h, h1_l);
    mfma_gemm<64, 128, 1><<<g_l1, TB, 0, stream>>>(h1_h, h1_l, W1h_ap, W1l_ap, nullptr, out_ap, xn);
    pull_combine<<<blocks_pull, TB, 0, stream>>>(xn, rp_ap, ss_ap, es_ap, invd_ap, ap_b1, out_ap);

    // ---- attention fusion ----
    att_stage1<<<ATT_BLOCKS, TB, 0, stream>>>(out_pr, out_cc, out_ap, att_W, att_b, att_partial);
    att_stage2<<<1, 64, 0, stream>>>(att_partial, w_acc);
    final_kernel<<<blocks_ND, TB, 0, stream>>>(out_pr, out_cc, w_acc);
}

// Round 7
// 589.259 us; speedup vs baseline: 3.7092x; 1.1169x over previous
//
#include <hip/hip_runtime.h>

#define NN 20000   // nodes
#define DD 64      // emb dim
#define HH 512     // hidden
#define EE 320000  // edges per graph
#define ATT_BLOCKS 625

typedef __attribute__((ext_vector_type(8))) short short8;   // 8 bf16 = 4 VGPR
typedef __attribute__((ext_vector_type(4))) float f32x4;

__device__ __forceinline__ ushort f2bf(float f) {
    union { float f; unsigned u; } v; v.f = f;
    unsigned r = v.u + 0x7FFF + ((v.u >> 16) & 1);   // RNE
    return (ushort)(r >> 16);
}
__device__ __forceinline__ float bf2f(ushort h) {
    union { unsigned u; float f; } v; v.u = ((unsigned)h) << 16;
    return v.f;
}
__device__ __forceinline__ void split_bf(float f, ushort& hi, ushort& lo) {
    hi = f2bf(f);
    lo = f2bf(f - bf2f(hi));
}

// ---------------- CSR build ----------------
__global__ __launch_bounds__(256) void hist_kernel(const int* __restrict__ dst,
                                                   int* __restrict__ cnt) {
    int e = blockIdx.x * blockDim.x + threadIdx.x;
    if (e < EE) atomicAdd(&cnt[dst[e]], 1);
}

__global__ __launch_bounds__(256) void inv_kernel(const int* __restrict__ cnt,
                                                  float* __restrict__ invd, int n) {
    int i = blockIdx.x * blockDim.x + threadIdx.x;
    if (i < n) invd[i] = 1.0f / fmaxf((float)cnt[i], 1.0f);
}

// one block per graph: exclusive prefix-sum cnt[g*NN..] -> rowptr[g*(NN+1)..]
__global__ __launch_bounds__(1024) void scan_kernel(const int* __restrict__ cnt,
                                                    int* __restrict__ rowptr) {
    __shared__ int part[1024];
    int g = blockIdx.x;
    const int* c = cnt + g * NN;
    int* rp = rowptr + g * (NN + 1);
    int tid = threadIdx.x;
    const int CH = (NN + 1023) / 1024;   // 20
    int i0 = tid * CH;
    int s = 0;
    for (int i = 0; i < CH; ++i) { int idx = i0 + i; if (idx < NN) s += c[idx]; }
    part[tid] = s;
    __syncthreads();
    for (int off = 1; off < 1024; off <<= 1) {
        int v = (tid >= off) ? part[tid - off] : 0;
        __syncthreads();
        part[tid] += v;
        __syncthreads();
    }
    int run = (tid > 0) ? part[tid - 1] : 0;
    for (int i = 0; i < CH; ++i) {
        int idx = i0 + i;
        if (idx < NN) { rp[idx] = run; run += c[idx]; }
    }
    if (tid == 1023) rp[NN] = part[1023];
}

__global__ __launch_bounds__(256) void bucket_kernel(const int* __restrict__ src,
                                                     const int* __restrict__ dst,
                                                     const float* __restrict__ ew,
                                                     const int* __restrict__ rp,
                                                     int* __restrict__ cursor,
                                                     int* __restrict__ src_s,
                                                     float* __restrict__ ew_s) {
    int e = blockIdx.x * blockDim.x + threadIdx.x;
    if (e >= EE) return;
    int d = dst[e];
    int pos = rp[d] + atomicAdd(&cursor[d], 1);
    src_s[pos] = src[e];
    ew_s[pos] = ew ? ew[e] : 1.0f;
}

// ---------------- pull aggregation (wave per node, lane = feature) ----------------
__global__ __launch_bounds__(256) void pull_cast(const float* __restrict__ x,
                                                 const int* __restrict__ rp,
                                                 const int* __restrict__ src_s,
                                                 const float* __restrict__ ew_s,
                                                 const float* __restrict__ invd,
                                                 ushort* __restrict__ xh,
                                                 ushort* __restrict__ xl) {
    int wid = (blockIdx.x * blockDim.x + threadIdx.x) >> 6;
    int lane = threadIdx.x & 63;
    if (wid >= NN) return;
    int beg = rp[wid], end = rp[wid + 1];
    float acc = 0.f;
    for (int i = beg; i < end; ++i) {
        int s = src_s[i];
        float w = ew_s[i];
        acc = fmaf(x[s * DD + lane], w, acc);
    }
    ushort hi, lo; split_bf(acc * invd[wid], hi, lo);
    xh[wid * 128 + 64 + lane] = hi;
    xl[wid * 128 + 64 + lane] = lo;
}

// out[n] += acc*invd[n] + bias   (fused layer-1 aggregation + combine)
__global__ __launch_bounds__(256) void pull_combine(const float* __restrict__ x,
                                                    const int* __restrict__ rp,
                                                    const int* __restrict__ src_s,
                                                    const float* __restrict__ ew_s,
                                                    const float* __restrict__ invd,
                                                    const float* __restrict__ bias,
                                                    float* __restrict__ out) {
    int wid = (blockIdx.x * blockDim.x + threadIdx.x) >> 6;
    int lane = threadIdx.x & 63;
    if (wid >= NN) return;
    int beg = rp[wid], end = rp[wid + 1];
    float acc = 0.f;
    for (int i = beg; i < end; ++i) {
        int s = src_s[i];
        float w = ew_s[i];
        acc = fmaf(x[s * DD + lane], w, acc);
    }
    out[wid * DD + lane] += acc * invd[wid] + bias[lane];
}

// ---------------- bf16 hi/lo packing ----------------
__global__ __launch_bounds__(256) void cast_x_kernel(const float* __restrict__ x,
                                                     ushort* __restrict__ xh,
                                                     ushort* __restrict__ xl) {
    int t = blockIdx.x * blockDim.x + threadIdx.x;
    if (t >= NN * DD) return;
    int n = t >> 6, d = t & 63;
    ushort hi, lo; split_bf(x[t], hi, lo);
    xh[n * 128 + d] = hi;
    xl[n * 128 + d] = lo;
}

// Wt[c][k]: k<KT/2 -> Ws[k][c], else Wn[k-KT/2][c]   (stacked, transposed)
template <int KT, int NC>
__global__ __launch_bounds__(256) void pack_w0(const float* __restrict__ Ws,
                                               const float* __restrict__ Wn,
                                               ushort* __restrict__ Wh,
                                               ushort* __restrict__ Wl) {
    int t = blockIdx.x * blockDim.x + threadIdx.x;
    if (t >= NC * KT) return;
    int c = t / KT, k = t % KT;
    float v = (k < KT / 2) ? Ws[k * NC + c] : Wn[(k - KT / 2) * NC + c];
    ushort hi, lo; split_bf(v, hi, lo);
    Wh[t] = hi; Wl[t] = lo;
}

// Wt[c][k] (c<128): c<64 -> Ws[k][c], else Wn[k][c-64]   (side-by-side, transposed)
template <int KT>
__global__ __launch_bounds__(256) void pack_w1(const float* __restrict__ Ws,
                                               const float* __restrict__ Wn,
                                               ushort* __restrict__ Wh,
                                               ushort* __restrict__ Wl) {
    int t = blockIdx.x * blockDim.x + threadIdx.x;
    if (t >= 128 * KT) return;
    int c = t / KT, k = t % KT;
    float v = (c < 64) ? Ws[k * 64 + c] : Wn[k * 64 + (c - 64)];
    ushort hi, lo; split_bf(v, hi, lo);
    Wh[t] = hi; Wl[t] = lo;
}

// ---------------- FUSED layer0+layer1 (h1 stays in LDS) ----------------
// Block = 256 threads (4 waves), 16 node-rows.
// Stage 1: h1[16][H] = relu(xcat[16][128] @ W0 + b0); hi/lo split -> LDS (pad +8).
// Stage 2: C[16][128] = h1 @ W1; cols 0-63 -> outS (s_part), 64-127 -> outX (xn).
// Hi/lo fp32 emulation on all MFMA: ah*bh + al*bh + ah*bl.
template <int H>
__global__ __launch_bounds__(256) void fused_sage(const ushort* __restrict__ Ah,
                                                  const ushort* __restrict__ Al,
                                                  const ushort* __restrict__ W0h,
                                                  const ushort* __restrict__ W0l,
                                                  const ushort* __restrict__ W1h,
                                                  const ushort* __restrict__ W1l,
                                                  const float* __restrict__ b0,
                                                  float* __restrict__ outS,
                                                  float* __restrict__ outX) {
    constexpr int LROW = H + 8;          // ushort pitch; +8 => 16B stagger per row
    __shared__ ushort h1h[16 * LROW];
    __shared__ ushort h1l[16 * LROW];
    int wv = threadIdx.x >> 6;
    int lane = threadIdx.x & 63;
    int row0 = blockIdx.x * 16;
    int lrow = lane & 15;
    int koff = (lane >> 4) * 8;

    // ---- stage 1 ----
    {
        constexpr int NCT1 = H / 64;     // 16-col tiles per wave (512->8, 64->1)
        const size_t aoff = (size_t)(row0 + lrow) * 128 + koff;
        f32x4 acc[NCT1] = {};
        for (int k0 = 0; k0 < 128; k0 += 32) {
            short8 a_h = *(const short8*)(Ah + aoff + k0);
            short8 a_l = *(const short8*)(Al + aoff + k0);
#pragma unroll
            for (int c = 0; c < NCT1; ++c) {
                int bcol = wv * (H / 4) + c * 16 + lrow;
                const ushort* bh = W0h + (size_t)bcol * 128 + koff + k0;
                const ushort* bl = W0l + (size_t)bcol * 128 + koff + k0;
                short8 b_h = *(const short8*)bh;
                short8 b_l = *(const short8*)bl;
                acc[c] = __builtin_amdgcn_mfma_f32_16x16x32_bf16(a_h, b_h, acc[c], 0, 0, 0);
                acc[c] = __builtin_amdgcn_mfma_f32_16x16x32_bf16(a_l, b_h, acc[c], 0, 0, 0);
                acc[c] = __builtin_amdgcn_mfma_f32_16x16x32_bf16(a_h, b_l, acc[c], 0, 0, 0);
            }
        }
        int crow = (lane >> 4) * 4;      // C/D: col=lane&15, row=(lane>>4)*4+r
#pragma unroll
        for (int c = 0; c < NCT1; ++c) {
            int col = wv * (H / 4) + c * 16 + lrow;
            float bb = b0[col];
#pragma unroll
            for (int r = 0; r < 4; ++r) {
                float v = fmaxf(acc[c][r] + bb, 0.0f);
                ushort hi, lo; split_bf(v, hi, lo);
                h1h[(crow + r) * LROW + col] = hi;
                h1l[(crow + r) * LROW + col] = lo;
            }
        }
    }
    __syncthreads();

    // ---- stage 2 ----
    {
        f32x4 acc[2] = {};
        for (int k0 = 0; k0 < H; k0 += 32) {
            short8 a_h = *(const short8*)&h1h[lrow * LROW + koff + k0];
            short8 a_l = *(const short8*)&h1l[lrow * LROW + koff + k0];
#pragma unroll
            for (int c = 0; c < 2; ++c) {
                int bcol = wv * 32 + c * 16 + lrow;
                const ushort* bh = W1h + (size_t)bcol * H + koff + k0;
                const ushort* bl = W1l + (size_t)bcol * H + koff + k0;
                short8 b_h = *(const short8*)bh;
                short8 b_l = *(const short8*)bl;
                acc[c] = __builtin_amdgcn_mfma_f32_16x16x32_bf16(a_h, b_h, acc[c], 0, 0, 0);
                acc[c] = __builtin_amdgcn_mfma_f32_16x16x32_bf16(a_l, b_h, acc[c], 0, 0, 0);
                acc[c] = __builtin_amdgcn_mfma_f32_16x16x32_bf16(a_h, b_l, acc[c], 0, 0, 0);
            }
        }
        int crow = row0 + (lane >> 4) * 4;
#pragma unroll
        for (int c = 0; c < 2; ++c) {
            int col = wv * 32 + c * 16 + lrow;
            float* o = (col < 64) ? (outS + (size_t)crow * 64 + col)
                                  : (outX + (size_t)crow * 64 + (col - 64));
#pragma unroll
            for (int r = 0; r < 4; ++r) {
                o[(size_t)r * 64] = acc[c][r];
            }
        }
    }
}

// ---------------- attention reduction ----------------
__global__ __launch_bounds__(256) void att_stage1(const float* __restrict__ pr,
                                                  const float* __restrict__ cc,
                                                  const float* __restrict__ ap,
                                                  const float* __restrict__ attW,
                                                  const float* __restrict__ attb,
                                                  float2* __restrict__ partial) {
    __shared__ float red[8];
    int lane = threadIdx.x & 63;
    int wv = threadIdx.x >> 6;
    int gw = blockIdx.x * 4 + wv;
    const int nwaves = ATT_BLOCKS * 4;
    float b = attb[lane];
    float c0 = 0.f, c1 = 0.f;
    for (int n = gw; n < NN; n += nwaves) {
        float p0 = 0.f, p1 = 0.f;
        for (int k = 0; k < DD; ++k) {
            float w = attW[k * DD + lane];
            p0 = fmaf(pr[n * DD + k], w, p0);
            p1 = fmaf(cc[n * DD + k], w, p1);
        }
        float a = ap[n * DD + lane];
        c0 += a * tanhf(p0 + b);
        c1 += a * tanhf(p1 + b);
    }
#pragma unroll
    for (int off = 32; off; off >>= 1) {
        c0 += __shfl_xor(c0, off);
        c1 += __shfl_xor(c1, off);
    }
    if (lane == 0) { red[wv * 2] = c0; red[wv * 2 + 1] = c1; }
    __syncthreads();
    if (threadIdx.x == 0) {
        partial[blockIdx.x] = make_float2(red[0] + red[2] + red[4] + red[6],
                                          red[1] + red[3] + red[5] + red[7]);
    }
}

__global__ __launch_bounds__(64) void att_stage2(const float2* __restrict__ partial,
                                                 float* __restrict__ w_acc) {
    int lane = threadIdx.x;
    float s0 = 0.f, s1 = 0.f;
    for (int i = lane; i < ATT_BLOCKS; i += 64) {
        float2 p = partial[i];
        s0 += p.x; s1 += p.y;
    }
#pragma unroll
    for (int off = 32; off; off >>= 1) {
        s0 += __shfl_xor(s0, off);
        s1 += __shfl_xor(s1, off);
    }
    if (lane == 0) { w_acc[0] = s0; w_acc[1] = s1; }
}

// ---------------- final (in-place on pr=out) ----------------
__global__ __launch_bounds__(256) void final_kernel(float* __restrict__ pr_out,
                                                    const float* __restrict__ cc,
                                                    const float* __restrict__ w_acc) {
    int t = blockIdx.x * blockDim.x + threadIdx.x;
    if (t >= NN * DD) return;
    float w0 = w_acc[0] * (1.0f / NN);
    float w1 = w_acc[1] * (1.0f / NN);
    float m = fmaxf(w0, w1);
    float e0 = __expf(w0 - m), e1 = __expf(w1 - m);
    float inv = 1.0f / (e0 + e1);
    pr_out[t] = (e0 * pr_out[t] + e1 * cc[t]) * inv;
}

extern "C" void kernel_launch(void* const* d_in, const int* in_sizes, int n_in,
                              void* d_out, int out_size, void* d_ws, size_t ws_size,
                              hipStream_t stream) {
    const float* k_emb  = (const float*)d_in[0];
    const int*   pr_src = (const int*)d_in[1];
    const int*   pr_dst = (const int*)d_in[2];
    const float* pr_ew  = (const float*)d_in[3];
    const int*   cc_src = (const int*)d_in[4];
    const int*   cc_dst = (const int*)d_in[5];
    const float* cc_ew  = (const float*)d_in[6];
    const int*   sps_src = (const int*)d_in[7];
    const int*   sps_dst = (const int*)d_in[8];
    const float* pr_Ws0 = (const float*)d_in[9];
    const float* pr_Wn0 = (const float*)d_in[10];
    const float* pr_b0  = (const float*)d_in[11];
    const float* pr_Ws1 = (const float*)d_in[12];
    const float* pr_Wn1 = (const float*)d_in[13];
    const float* pr_b1  = (const float*)d_in[14];
    const float* cc_Ws0 = (const float*)d_in[15];
    const float* cc_Wn0 = (const float*)d_in[16];
    const float* cc_b0  = (const float*)d_in[17];
    const float* cc_Ws1 = (const float*)d_in[18];
    const float* cc_Wn1 = (const float*)d_in[19];
    const float* cc_b1  = (const float*)d_in[20];
    const float* ap_Ws0 = (const float*)d_in[21];
    const float* ap_Wn0 = (const float*)d_in[22];
    const float* ap_b0  = (const float*)d_in[23];
    const float* ap_Ws1 = (const float*)d_in[24];
    const float* ap_Wn1 = (const float*)d_in[25];
    const float* ap_b1  = (const float*)d_in[26];
    const float* att_W  = (const float*)d_in[27];
    const float* att_b  = (const float*)d_in[28];
    float* out = (float*)d_out;

    // ---- workspace layout (256B-aligned) ----
    char* base = (char*)d_ws;
    size_t off = 0;
    auto alloc = [&](size_t bytes) -> void* {
        void* p = base + off;
        off = (off + bytes + 255) & ~(size_t)255;
        return p;
    };
    float*  invd   = (float*)alloc((size_t)3 * NN * 4);
    int*    cnt    = (int*)alloc((size_t)3 * NN * 4);
    int*    rowptr = (int*)alloc((size_t)3 * (NN + 1) * 4);
    int*    src_s  = (int*)alloc((size_t)3 * EE * 4);
    float*  ew_s   = (float*)alloc((size_t)3 * EE * 4);
    float*  w_acc  = (float*)alloc(64);
    float2* att_partial = (float2*)alloc(ATT_BLOCKS * 8);
    float*  xn     = (float*)alloc((size_t)NN * DD * 4);
    float*  out_cc = (float*)alloc((size_t)NN * DD * 4);
    float*  out_ap = (float*)alloc((size_t)NN * DD * 4);
    ushort* xcat_h = (ushort*)alloc((size_t)NN * 128 * 2);
    ushort* xcat_l = (ushort*)alloc((size_t)NN * 128 * 2);
    ushort* W0h_pr = (ushort*)alloc(512 * 128 * 2);
    ushort* W0l_pr = (ushort*)alloc(512 * 128 * 2);
    ushort* W0h_cc = (ushort*)alloc(512 * 128 * 2);
    ushort* W0l_cc = (ushort*)alloc(512 * 128 * 2);
    ushort* W0h_ap = (ushort*)alloc(64 * 128 * 2);
    ushort* W0l_ap = (ushort*)alloc(64 * 128 * 2);
    ushort* W1h_pr = (ushort*)alloc(128 * 512 * 2);
    ushort* W1l_pr = (ushort*)alloc(128 * 512 * 2);
    ushort* W1h_cc = (ushort*)alloc(128 * 512 * 2);
    ushort* W1l_cc = (ushort*)alloc(128 * 512 * 2);
    ushort* W1h_ap = (ushort*)alloc(128 * 64 * 2);
    ushort* W1l_ap = (ushort*)alloc(128 * 64 * 2);
    float*  out_pr = out;   // pr result lives in d_out

    float* invd_pr = invd;            float* invd_cc = invd + NN;        float* invd_ap = invd + 2 * NN;
    int*   rp_pr   = rowptr;          int*   rp_cc   = rowptr + (NN+1);  int*   rp_ap   = rowptr + 2*(NN+1);
    int*   ss_pr   = src_s;           int*   ss_cc   = src_s + EE;       int*   ss_ap   = src_s + 2*EE;
    float* es_pr   = ew_s;            float* es_cc   = ew_s + EE;        float* es_ap   = ew_s + 2*EE;

    const int TB = 256;
    const int blocks_E  = EE / TB;          // 1250
    const int blocks_ND = (NN * DD) / TB;   // 5000
    const int blocks_pull = (NN * 64) / TB; // 5000
    const int blocks_fused = NN / 16;       // 1250

    // ---- prologue: weight packs + x cast + CSR build ----
    pack_w0<128, 512><<<256, TB, 0, stream>>>(pr_Ws0, pr_Wn0, W0h_pr, W0l_pr);
    pack_w0<128, 512><<<256, TB, 0, stream>>>(cc_Ws0, cc_Wn0, W0h_cc, W0l_cc);
    pack_w0<128, 64><<<32, TB, 0, stream>>>(ap_Ws0, ap_Wn0, W0h_ap, W0l_ap);
    pack_w1<512><<<256, TB, 0, stream>>>(pr_Ws1, pr_Wn1, W1h_pr, W1l_pr);
    pack_w1<512><<<256, TB, 0, stream>>>(cc_Ws1, cc_Wn1, W1h_cc, W1l_cc);
    pack_w1<64><<<32, TB, 0, stream>>>(ap_Ws1, ap_Wn1, W1h_ap, W1l_ap);
    cast_x_kernel<<<blocks_ND, TB, 0, stream>>>(k_emb, xcat_h, xcat_l);

    hipMemsetAsync(cnt, 0, (size_t)3 * NN * 4, stream);
    hist_kernel<<<blocks_E, TB, 0, stream>>>(pr_dst, cnt);
    hist_kernel<<<blocks_E, TB, 0, stream>>>(cc_dst, cnt + NN);
    hist_kernel<<<blocks_E, TB, 0, stream>>>(sps_dst, cnt + 2 * NN);
    inv_kernel<<<(3 * NN + TB - 1) / TB, TB, 0, stream>>>(cnt, invd, 3 * NN);
    scan_kernel<<<3, 1024, 0, stream>>>(cnt, rowptr);
    hipMemsetAsync(cnt, 0, (size_t)3 * NN * 4, stream);   // cnt becomes cursor
    bucket_kernel<<<blocks_E, TB, 0, stream>>>(pr_src, pr_dst, pr_ew, rp_pr, cnt, ss_pr, es_pr);
    bucket_kernel<<<blocks_E, TB, 0, stream>>>(cc_src, cc_dst, cc_ew, rp_cc, cnt + NN, ss_cc, es_cc);
    bucket_kernel<<<blocks_E, TB, 0, stream>>>(sps_src, sps_dst, nullptr, rp_ap, cnt + 2 * NN, ss_ap, es_ap);

    // ---- pr branch ----
    pull_cast<<<blocks_pull, TB, 0, stream>>>(k_emb, rp_pr, ss_pr, es_pr, invd_pr, xcat_h, xcat_l);
    fused_sage<512><<<blocks_fused, TB, 0, stream>>>(xcat_h, xcat_l, W0h_pr, W0l_pr,
                                                     W1h_pr, W1l_pr, pr_b0, out_pr, xn);
    pull_combine<<<blocks_pull, TB, 0, stream>>>(xn, rp_pr, ss_pr, es_pr, invd_pr, pr_b1, out_pr);

    // ---- cc branch ----
    pull_cast<<<blocks_pull, TB, 0, stream>>>(k_emb, rp_cc, ss_cc, es_cc, invd_cc, xcat_h, xcat_l);
    fused_sage<512><<<blocks_fused, TB, 0, stream>>>(xcat_h, xcat_l, W0h_cc, W0l_cc,
                                                     W1h_cc, W1l_cc, cc_b0, out_cc, xn);
    pull_combine<<<blocks_pull, TB, 0, stream>>>(xn, rp_cc, ss_cc, es_cc, invd_cc, cc_b1, out_cc);

    // ---- ap branch ----
    pull_cast<<<blocks_pull, TB, 0, stream>>>(k_emb, rp_ap, ss_ap, es_ap, invd_ap, xcat_h, xcat_l);
    fused_sage<64><<<blocks_fused, TB, 0, stream>>>(xcat_h, xcat_l, W0h_ap, W0l_ap,
                                                    W1h_ap, W1l_ap, ap_b0, out_ap, xn);
    pull_combine<<<blocks_pull, TB, 0, stream>>>(xn, rp_ap, ss_ap, es_ap, invd_ap, ap_b1, out_ap);

    // ---- attention fusion ----
    att_stage1<<<ATT_BLOCKS, TB, 0, stream>>>(out_pr, out_cc, out_ap, att_W, att_b, att_partial);
    att_stage2<<<1, 64, 0, stream>>>(att_partial, w_acc);
    final_kernel<<<blocks_ND, TB, 0, stream>>>(out_pr, out_cc, w_acc);
}

// Round 8
// 551.185 us; speedup vs baseline: 3.9654x; 1.0691x over previous
//
#include <hip/hip_runtime.h>

#define NN 20000   // nodes
#define DD 64      // emb dim
#define HH 512     // hidden
#define EE 320000  // edges per graph
#define ATT_BLOCKS 625
#define NBLK (NN / 16)      // 1250 row-tiles
#define BLOCKS_E (EE / 256) // 1250

typedef __attribute__((ext_vector_type(8))) short short8;   // 8 bf16 = 4 VGPR
typedef __attribute__((ext_vector_type(4))) float f32x4;

__device__ __forceinline__ ushort f2bf(float f) {
    union { float f; unsigned u; } v; v.f = f;
    unsigned r = v.u + 0x7FFF + ((v.u >> 16) & 1);   // RNE
    return (ushort)(r >> 16);
}
__device__ __forceinline__ float bf2f(ushort h) {
    union { unsigned u; float f; } v; v.u = ((unsigned)h) << 16;
    return v.f;
}
__device__ __forceinline__ void split_bf(float f, ushort& hi, ushort& lo) {
    hi = f2bf(f);
    lo = f2bf(f - bf2f(hi));
}

// ---------------- CSR build (3 graphs in one dispatch) ----------------
__global__ __launch_bounds__(256) void hist3(const int* __restrict__ d0,
                                             const int* __restrict__ d1,
                                             const int* __restrict__ d2,
                                             int* __restrict__ cnt) {
    int g = blockIdx.x / BLOCKS_E;
    int e = (blockIdx.x % BLOCKS_E) * 256 + threadIdx.x;
    const int* d = (g == 0) ? d0 : (g == 1) ? d1 : d2;
    if (e < EE) atomicAdd(&cnt[g * NN + d[e]], 1);
}

__global__ __launch_bounds__(256) void inv_kernel(const int* __restrict__ cnt,
                                                  float* __restrict__ invd, int n) {
    int i = blockIdx.x * blockDim.x + threadIdx.x;
    if (i < n) invd[i] = 1.0f / fmaxf((float)cnt[i], 1.0f);
}

// one block per graph: exclusive prefix-sum cnt[g*NN..] -> rowptr[g*(NN+1)..]
__global__ __launch_bounds__(1024) void scan_kernel(const int* __restrict__ cnt,
                                                    int* __restrict__ rowptr) {
    __shared__ int part[1024];
    int g = blockIdx.x;
    const int* c = cnt + g * NN;
    int* rp = rowptr + g * (NN + 1);
    int tid = threadIdx.x;
    const int CH = (NN + 1023) / 1024;
    int i0 = tid * CH;
    int s = 0;
    for (int i = 0; i < CH; ++i) { int idx = i0 + i; if (idx < NN) s += c[idx]; }
    part[tid] = s;
    __syncthreads();
    for (int off = 1; off < 1024; off <<= 1) {
        int v = (tid >= off) ? part[tid - off] : 0;
        __syncthreads();
        part[tid] += v;
        __syncthreads();
    }
    int run = (tid > 0) ? part[tid - 1] : 0;
    for (int i = 0; i < CH; ++i) {
        int idx = i0 + i;
        if (idx < NN) { rp[idx] = run; run += c[idx]; }
    }
    if (tid == 1023) rp[NN] = part[1023];
}

__global__ __launch_bounds__(256) void bucket3(const int* __restrict__ s0, const int* __restrict__ d0, const float* __restrict__ w0,
                                               const int* __restrict__ s1, const int* __restrict__ d1, const float* __restrict__ w1,
                                               const int* __restrict__ s2, const int* __restrict__ d2,
                                               const int* __restrict__ rowptr,
                                               int* __restrict__ cursor,
                                               int* __restrict__ src_s,
                                               float* __restrict__ ew_s) {
    int g = blockIdx.x / BLOCKS_E;
    int e = (blockIdx.x % BLOCKS_E) * 256 + threadIdx.x;
    if (e >= EE) return;
    const int* src = (g == 0) ? s0 : (g == 1) ? s1 : s2;
    const int* dst = (g == 0) ? d0 : (g == 1) ? d1 : d2;
    const float* ew = (g == 0) ? w0 : (g == 1) ? w1 : nullptr;
    int d = dst[e];
    int pos = rowptr[g * (NN + 1) + d] + atomicAdd(&cursor[g * NN + d], 1);
    src_s[g * EE + pos] = src[e];
    ew_s[g * EE + pos] = ew ? ew[e] : 1.0f;
}

// ---------------- pull aggregation, 3 graphs in one dispatch ----------------
// agg[g][n][64] = (sum_e w_e * x[src_e]) * invd  -> bf16 hi/lo
__global__ __launch_bounds__(256) void pull_cast3(const float* __restrict__ x,
                                                  const int* __restrict__ rowptr,
                                                  const int* __restrict__ src_s,
                                                  const float* __restrict__ ew_s,
                                                  const float* __restrict__ invd,
                                                  ushort* __restrict__ aggh,
                                                  ushort* __restrict__ aggl) {
    int wid = (blockIdx.x * blockDim.x + threadIdx.x) >> 6;
    int lane = threadIdx.x & 63;
    if (wid >= 3 * NN) return;
    int g = wid / NN, n = wid % NN;
    const int* rp = rowptr + g * (NN + 1);
    const int* ss = src_s + (size_t)g * EE;
    const float* es = ew_s + (size_t)g * EE;
    int beg = rp[n], end = rp[n + 1];
    float acc = 0.f;
    for (int i = beg; i < end; ++i) {
        int s = ss[i];
        float w = es[i];
        acc = fmaf(x[s * DD + lane], w, acc);
    }
    ushort hi, lo; split_bf(acc * invd[g * NN + n], hi, lo);
    aggh[(size_t)wid * 64 + lane] = hi;
    aggl[(size_t)wid * 64 + lane] = lo;
}

// out[g][n] += acc*invd + bias  (layer-1 aggregation + combine), 3 graphs
__global__ __launch_bounds__(256) void pull_combine3(const float* __restrict__ xn,  // [3][NN][64]
                                                     const int* __restrict__ rowptr,
                                                     const int* __restrict__ src_s,
                                                     const float* __restrict__ ew_s,
                                                     const float* __restrict__ invd,
                                                     const float* __restrict__ b_pr,
                                                     const float* __restrict__ b_cc,
                                                     const float* __restrict__ b_ap,
                                                     float* __restrict__ o_pr,
                                                     float* __restrict__ o_cc,
                                                     float* __restrict__ o_ap) {
    int wid = (blockIdx.x * blockDim.x + threadIdx.x) >> 6;
    int lane = threadIdx.x & 63;
    if (wid >= 3 * NN) return;
    int g = wid / NN, n = wid % NN;
    const int* rp = rowptr + g * (NN + 1);
    const int* ss = src_s + (size_t)g * EE;
    const float* es = ew_s + (size_t)g * EE;
    const float* x = xn + (size_t)g * NN * 64;
    const float* bias = (g == 0) ? b_pr : (g == 1) ? b_cc : b_ap;
    float* out = (g == 0) ? o_pr : (g == 1) ? o_cc : o_ap;
    int beg = rp[n], end = rp[n + 1];
    float acc = 0.f;
    for (int i = beg; i < end; ++i) {
        int s = ss[i];
        float w = es[i];
        acc = fmaf(x[s * DD + lane], w, acc);
    }
    out[n * DD + lane] += acc * invd[g * NN + n] + bias[lane];
}

// ---------------- bf16 hi/lo packing ----------------
__global__ __launch_bounds__(256) void cast_x_kernel(const float* __restrict__ x,
                                                     ushort* __restrict__ xh,
                                                     ushort* __restrict__ xl) {
    int t = blockIdx.x * blockDim.x + threadIdx.x;
    if (t >= NN * DD) return;
    ushort hi, lo; split_bf(x[t], hi, lo);
    xh[t] = hi;
    xl[t] = lo;
}

// Wt[c][k]: k<64 -> Ws[k][c], else Wn[k-64][c]   (stacked, transposed; KT=128)
template <int NC>
__global__ __launch_bounds__(256) void pack_w0(const float* __restrict__ Ws,
                                               const float* __restrict__ Wn,
                                               ushort* __restrict__ Wh,
                                               ushort* __restrict__ Wl) {
    int t = blockIdx.x * blockDim.x + threadIdx.x;
    if (t >= NC * 128) return;
    int c = t / 128, k = t % 128;
    float v = (k < 64) ? Ws[k * NC + c] : Wn[(k - 64) * NC + c];
    ushort hi, lo; split_bf(v, hi, lo);
    Wh[t] = hi; Wl[t] = lo;
}

// Wt[c][k] (c<128, k<KT): c<64 -> Ws[k][c], else Wn[k][c-64]
template <int KT>
__global__ __launch_bounds__(256) void pack_w1(const float* __restrict__ Ws,
                                               const float* __restrict__ Wn,
                                               ushort* __restrict__ Wh,
                                               ushort* __restrict__ Wl) {
    int t = blockIdx.x * blockDim.x + threadIdx.x;
    if (t >= 128 * KT) return;
    int c = t / KT, k = t % KT;
    float v = (c < 64) ? Ws[k * 64 + c] : Wn[k * 64 + (c - 64)];
    ushort hi, lo; split_bf(v, hi, lo);
    Wh[t] = hi; Wl[t] = lo;
}

// ---------------- FUSED layer0+layer1 v2 ----------------
// WAVES waves/block, 16 node-rows/block. Up to 2 branches in one dispatch
// (branch = blockIdx.x / nblk). A = [x | agg_branch] (two 64-wide halves).
// Dual accumulators break the hi/lo 3-MFMA serial chain into 2 chains.
template <int H, int WAVES>
__global__ __launch_bounds__(WAVES * 64, 4) void fused_sage2(
    const ushort* __restrict__ xh, const ushort* __restrict__ xl,       // [NN][64]
    const ushort* __restrict__ aggh, const ushort* __restrict__ aggl,   // [branches][NN][64]
    const ushort* __restrict__ W0h0, const ushort* __restrict__ W0l0,
    const ushort* __restrict__ W1h0, const ushort* __restrict__ W1l0,
    const ushort* __restrict__ W0h1, const ushort* __restrict__ W0l1,
    const ushort* __restrict__ W1h1, const ushort* __restrict__ W1l1,
    const float* __restrict__ b0_0, const float* __restrict__ b0_1,
    float* __restrict__ outS0, float* __restrict__ outS1,
    float* __restrict__ xn,                                             // [branches][NN][64]
    int nblk) {
    constexpr int LROW = H + 8;
    __shared__ ushort h1h[16 * LROW];
    __shared__ ushort h1l[16 * LROW];
    int br = blockIdx.x / nblk;
    int rb = blockIdx.x % nblk;
    const ushort* W0h = br ? W0h1 : W0h0;
    const ushort* W0l = br ? W0l1 : W0l0;
    const ushort* W1h = br ? W1h1 : W1h0;
    const ushort* W1l = br ? W1l1 : W1l0;
    const float* b0 = br ? b0_1 : b0_0;
    float* outS = br ? outS1 : outS0;
    float* outX = xn + (size_t)br * NN * 64;
    const ushort* agh = aggh + (size_t)br * NN * 64;
    const ushort* agl = aggl + (size_t)br * NN * 64;

    int wv = threadIdx.x >> 6;
    int lane = threadIdx.x & 63;
    int lrow = lane & 15;
    int koff = (lane >> 4) * 8;
    int row0 = rb * 16;

    // ---- stage 1: h1[16][H] = relu([x|agg] @ W0 + b0) -> LDS hi/lo ----
    {
        constexpr int COLS1 = H / WAVES;
        constexpr int NCT1 = COLS1 / 16;
        const size_t aoff = (size_t)(row0 + lrow) * 64 + koff;
        f32x4 aH[NCT1] = {};
        f32x4 aL[NCT1] = {};
#pragma unroll
        for (int half = 0; half < 2; ++half) {
            const ushort* Ah = half ? agh : xh;
            const ushort* Al = half ? agl : xl;
#pragma unroll
            for (int kk = 0; kk < 2; ++kk) {
                short8 a_h = *(const short8*)(Ah + aoff + kk * 32);
                short8 a_l = *(const short8*)(Al + aoff + kk * 32);
                int kglob = half * 64 + kk * 32;
#pragma unroll
                for (int c = 0; c < NCT1; ++c) {
                    int bcol = wv * COLS1 + c * 16 + lrow;
                    short8 b_h = *(const short8*)(W0h + (size_t)bcol * 128 + koff + kglob);
                    short8 b_l = *(const short8*)(W0l + (size_t)bcol * 128 + koff + kglob);
                    aH[c] = __builtin_amdgcn_mfma_f32_16x16x32_bf16(a_h, b_h, aH[c], 0, 0, 0);
                    aL[c] = __builtin_amdgcn_mfma_f32_16x16x32_bf16(a_l, b_h, aL[c], 0, 0, 0);
                    aL[c] = __builtin_amdgcn_mfma_f32_16x16x32_bf16(a_h, b_l, aL[c], 0, 0, 0);
                }
            }
        }
        int crow = (lane >> 4) * 4;
#pragma unroll
        for (int c = 0; c < NCT1; ++c) {
            int col = wv * COLS1 + c * 16 + lrow;
            float bb = b0[col];
#pragma unroll
            for (int r = 0; r < 4; ++r) {
                float v = fmaxf(aH[c][r] + aL[c][r] + bb, 0.0f);
                ushort hi, lo; split_bf(v, hi, lo);
                h1h[(crow + r) * LROW + col] = hi;
                h1l[(crow + r) * LROW + col] = lo;
            }
        }
    }
    __syncthreads();

    // ---- stage 2: C[16][128] = h1 @ W1; cols 0-63 -> outS, 64-127 -> xn ----
    {
        constexpr int COLS2 = 128 / WAVES;
        constexpr int NCT2 = COLS2 / 16;
        f32x4 cH[NCT2] = {};
        f32x4 cL[NCT2] = {};
        for (int k0 = 0; k0 < H; k0 += 32) {
            short8 a_h = *(const short8*)&h1h[lrow * LROW + koff + k0];
            short8 a_l = *(const short8*)&h1l[lrow * LROW + koff + k0];
#pragma unroll
            for (int c = 0; c < NCT2; ++c) {
                int bcol = wv * COLS2 + c * 16 + lrow;
                short8 b_h = *(const short8*)(W1h + (size_t)bcol * H + koff + k0);
                short8 b_l = *(const short8*)(W1l + (size_t)bcol * H + koff + k0);
                cH[c] = __builtin_amdgcn_mfma_f32_16x16x32_bf16(a_h, b_h, cH[c], 0, 0, 0);
                cL[c] = __builtin_amdgcn_mfma_f32_16x16x32_bf16(a_l, b_h, cL[c], 0, 0, 0);
                cL[c] = __builtin_amdgcn_mfma_f32_16x16x32_bf16(a_h, b_l, cL[c], 0, 0, 0);
            }
        }
        int crow = row0 + (lane >> 4) * 4;
#pragma unroll
        for (int c = 0; c < NCT2; ++c) {
            int col = wv * COLS2 + c * 16 + lrow;
            float* o = (col < 64) ? (outS + (size_t)crow * 64 + col)
                                  : (outX + (size_t)crow * 64 + (col - 64));
#pragma unroll
            for (int r = 0; r < 4; ++r) {
                o[(size_t)r * 64] = cH[c][r] + cL[c][r];
            }
        }
    }
}

// ---------------- attention reduction ----------------
__global__ __launch_bounds__(256) void att_stage1(const float* __restrict__ pr,
                                                  const float* __restrict__ cc,
                                                  const float* __restrict__ ap,
                                                  const float* __restrict__ attW,
                                                  const float* __restrict__ attb,
                                                  float2* __restrict__ partial) {
    __shared__ float red[8];
    int lane = threadIdx.x & 63;
    int wv = threadIdx.x >> 6;
    int gw = blockIdx.x * 4 + wv;
    const int nwaves = ATT_BLOCKS * 4;
    float b = attb[lane];
    float c0 = 0.f, c1 = 0.f;
    for (int n = gw; n < NN; n += nwaves) {
        float p0 = 0.f, p1 = 0.f;
        for (int k = 0; k < DD; ++k) {
            float w = attW[k * DD + lane];
            p0 = fmaf(pr[n * DD + k], w, p0);
            p1 = fmaf(cc[n * DD + k], w, p1);
        }
        float a = ap[n * DD + lane];
        c0 += a * tanhf(p0 + b);
        c1 += a * tanhf(p1 + b);
    }
#pragma unroll
    for (int off = 32; off; off >>= 1) {
        c0 += __shfl_xor(c0, off);
        c1 += __shfl_xor(c1, off);
    }
    if (lane == 0) { red[wv * 2] = c0; red[wv * 2 + 1] = c1; }
    __syncthreads();
    if (threadIdx.x == 0) {
        partial[blockIdx.x] = make_float2(red[0] + red[2] + red[4] + red[6],
                                          red[1] + red[3] + red[5] + red[7]);
    }
}

__global__ __launch_bounds__(64) void att_stage2(const float2* __restrict__ partial,
                                                 float* __restrict__ w_acc) {
    int lane = threadIdx.x;
    float s0 = 0.f, s1 = 0.f;
    for (int i = lane; i < ATT_BLOCKS; i += 64) {
        float2 p = partial[i];
        s0 += p.x; s1 += p.y;
    }
#pragma unroll
    for (int off = 32; off; off >>= 1) {
        s0 += __shfl_xor(s0, off);
        s1 += __shfl_xor(s1, off);
    }
    if (lane == 0) { w_acc[0] = s0; w_acc[1] = s1; }
}

// ---------------- final (in-place on pr=out) ----------------
__global__ __launch_bounds__(256) void final_kernel(float* __restrict__ pr_out,
                                                    const float* __restrict__ cc,
                                                    const float* __restrict__ w_acc) {
    int t = blockIdx.x * blockDim.x + threadIdx.x;
    if (t >= NN * DD) return;
    float w0 = w_acc[0] * (1.0f / NN);
    float w1 = w_acc[1] * (1.0f / NN);
    float m = fmaxf(w0, w1);
    float e0 = __expf(w0 - m), e1 = __expf(w1 - m);
    float inv = 1.0f / (e0 + e1);
    pr_out[t] = (e0 * pr_out[t] + e1 * cc[t]) * inv;
}

extern "C" void kernel_launch(void* const* d_in, const int* in_sizes, int n_in,
                              void* d_out, int out_size, void* d_ws, size_t ws_size,
                              hipStream_t stream) {
    const float* k_emb  = (const float*)d_in[0];
    const int*   pr_src = (const int*)d_in[1];
    const int*   pr_dst = (const int*)d_in[2];
    const float* pr_ew  = (const float*)d_in[3];
    const int*   cc_src = (const int*)d_in[4];
    const int*   cc_dst = (const int*)d_in[5];
    const float* cc_ew  = (const float*)d_in[6];
    const int*   sps_src = (const int*)d_in[7];
    const int*   sps_dst = (const int*)d_in[8];
    const float* pr_Ws0 = (const float*)d_in[9];
    const float* pr_Wn0 = (const float*)d_in[10];
    const float* pr_b0  = (const float*)d_in[11];
    const float* pr_Ws1 = (const float*)d_in[12];
    const float* pr_Wn1 = (const float*)d_in[13];
    const float* pr_b1  = (const float*)d_in[14];
    const float* cc_Ws0 = (const float*)d_in[15];
    const float* cc_Wn0 = (const float*)d_in[16];
    const float* cc_b0  = (const float*)d_in[17];
    const float* cc_Ws1 = (const float*)d_in[18];
    const float* cc_Wn1 = (const float*)d_in[19];
    const float* cc_b1  = (const float*)d_in[20];
    const float* ap_Ws0 = (const float*)d_in[21];
    const float* ap_Wn0 = (const float*)d_in[22];
    const float* ap_b0  = (const float*)d_in[23];
    const float* ap_Ws1 = (const float*)d_in[24];
    const float* ap_Wn1 = (const float*)d_in[25];
    const float* ap_b1  = (const float*)d_in[26];
    const float* att_W  = (const float*)d_in[27];
    const float* att_b  = (const float*)d_in[28];
    float* out = (float*)d_out;

    // ---- workspace layout (256B-aligned; ~56 MB) ----
    char* base = (char*)d_ws;
    size_t off = 0;
    auto alloc = [&](size_t bytes) -> void* {
        void* p = base + off;
        off = (off + bytes + 255) & ~(size_t)255;
        return p;
    };
    float*  invd   = (float*)alloc((size_t)3 * NN * 4);
    int*    cnt    = (int*)alloc((size_t)3 * NN * 4);
    int*    rowptr = (int*)alloc((size_t)3 * (NN + 1) * 4);
    int*    src_s  = (int*)alloc((size_t)3 * EE * 4);
    float*  ew_s   = (float*)alloc((size_t)3 * EE * 4);
    float*  w_acc  = (float*)alloc(64);
    float2* att_partial = (float2*)alloc(ATT_BLOCKS * 8);
    float*  xn     = (float*)alloc((size_t)3 * NN * DD * 4);   // [3][NN][64]
    float*  out_cc = (float*)alloc((size_t)NN * DD * 4);
    float*  out_ap = (float*)alloc((size_t)NN * DD * 4);
    ushort* xh     = (ushort*)alloc((size_t)NN * DD * 2);
    ushort* xl     = (ushort*)alloc((size_t)NN * DD * 2);
    ushort* aggh   = (ushort*)alloc((size_t)3 * NN * DD * 2);  // [3][NN][64]
    ushort* aggl   = (ushort*)alloc((size_t)3 * NN * DD * 2);
    ushort* W0h_pr = (ushort*)alloc(512 * 128 * 2);
    ushort* W0l_pr = (ushort*)alloc(512 * 128 * 2);
    ushort* W0h_cc = (ushort*)alloc(512 * 128 * 2);
    ushort* W0l_cc = (ushort*)alloc(512 * 128 * 2);
    ushort* W0h_ap = (ushort*)alloc(64 * 128 * 2);
    ushort* W0l_ap = (ushort*)alloc(64 * 128 * 2);
    ushort* W1h_pr = (ushort*)alloc(128 * 512 * 2);
    ushort* W1l_pr = (ushort*)alloc(128 * 512 * 2);
    ushort* W1h_cc = (ushort*)alloc(128 * 512 * 2);
    ushort* W1l_cc = (ushort*)alloc(128 * 512 * 2);
    ushort* W1h_ap = (ushort*)alloc(128 * 64 * 2);
    ushort* W1l_ap = (ushort*)alloc(128 * 64 * 2);
    float*  out_pr = out;   // pr result lives in d_out

    const int TB = 256;
    const int blocks_ND = (NN * DD) / TB;        // 5000
    const int blocks_pull3 = (3 * NN * 64) / TB; // 15000
    const int wpack_big = (512 * 128 + TB - 1) / TB;
    const int wpack_small = (64 * 128 + TB - 1) / TB;

    // ---- prologue: weight packs + x cast + CSR build ----
    pack_w0<512><<<wpack_big, TB, 0, stream>>>(pr_Ws0, pr_Wn0, W0h_pr, W0l_pr);
    pack_w0<512><<<wpack_big, TB, 0, stream>>>(cc_Ws0, cc_Wn0, W0h_cc, W0l_cc);
    pack_w0<64><<<wpack_small, TB, 0, stream>>>(ap_Ws0, ap_Wn0, W0h_ap, W0l_ap);
    pack_w1<512><<<wpack_big, TB, 0, stream>>>(pr_Ws1, pr_Wn1, W1h_pr, W1l_pr);
    pack_w1<512><<<wpack_big, TB, 0, stream>>>(cc_Ws1, cc_Wn1, W1h_cc, W1l_cc);
    pack_w1<64><<<wpack_small, TB, 0, stream>>>(ap_Ws1, ap_Wn1, W1h_ap, W1l_ap);
    cast_x_kernel<<<blocks_ND, TB, 0, stream>>>(k_emb, xh, xl);

    hipMemsetAsync(cnt, 0, (size_t)3 * NN * 4, stream);
    hist3<<<3 * BLOCKS_E, TB, 0, stream>>>(pr_dst, cc_dst, sps_dst, cnt);
    inv_kernel<<<(3 * NN + TB - 1) / TB, TB, 0, stream>>>(cnt, invd, 3 * NN);
    scan_kernel<<<3, 1024, 0, stream>>>(cnt, rowptr);
    hipMemsetAsync(cnt, 0, (size_t)3 * NN * 4, stream);   // cnt becomes cursor
    bucket3<<<3 * BLOCKS_E, TB, 0, stream>>>(pr_src, pr_dst, pr_ew,
                                             cc_src, cc_dst, cc_ew,
                                             sps_src, sps_dst,
                                             rowptr, cnt, src_s, ew_s);

    // ---- layer-0 aggregation for all 3 graphs (one dispatch) ----
    pull_cast3<<<blocks_pull3, TB, 0, stream>>>(k_emb, rowptr, src_s, ew_s, invd, aggh, aggl);

    // ---- fused layer0+layer1: pr+cc in one dispatch, ap separate ----
    fused_sage2<512, 8><<<2 * NBLK, 512, 0, stream>>>(
        xh, xl, aggh, aggl,
        W0h_pr, W0l_pr, W1h_pr, W1l_pr,
        W0h_cc, W0l_cc, W1h_cc, W1l_cc,
        pr_b0, cc_b0, out_pr, out_cc, xn, NBLK);
    fused_sage2<64, 4><<<NBLK, 256, 0, stream>>>(
        xh, xl, aggh + (size_t)2 * NN * 64, aggl + (size_t)2 * NN * 64,
        W0h_ap, W0l_ap, W1h_ap, W1l_ap,
        W0h_ap, W0l_ap, W1h_ap, W1l_ap,
        ap_b0, ap_b0, out_ap, out_ap, xn + (size_t)2 * NN * 64, NBLK);

    // ---- layer-1 aggregation + combine for all 3 graphs (one dispatch) ----
    pull_combine3<<<blocks_pull3, TB, 0, stream>>>(xn, rowptr, src_s, ew_s, invd,
                                                   pr_b1, cc_b1, ap_b1,
                                                   out_pr, out_cc, out_ap);

    // ---- attention fusion ----
    att_stage1<<<ATT_BLOCKS, TB, 0, stream>>>(out_pr, out_cc, out_ap, att_W, att_b, att_partial);
    att_stage2<<<1, 64, 0, stream>>>(att_partial, w_acc);
    final_kernel<<<blocks_ND, TB, 0, stream>>>(out_pr, out_cc, w_acc);
}

// Round 9
// 456.995 us; speedup vs baseline: 4.7827x; 1.2061x over previous
//
#include <hip/hip_runtime.h>

#define NN 20000   // nodes
#define DD 64      // emb dim
#define HH 512     // hidden
#define EE 320000  // edges per graph
#define ATT_BLOCKS 625
#define NBLK (NN / 16)      // 1250 row-tiles
#define BLOCKS_E (EE / 256) // 1250

typedef __attribute__((ext_vector_type(8))) short short8;   // 8 bf16 = 4 VGPR
typedef __attribute__((ext_vector_type(4))) float f32x4;

__device__ __forceinline__ ushort f2bf(float f) {
    union { float f; unsigned u; } v; v.f = f;
    unsigned r = v.u + 0x7FFF + ((v.u >> 16) & 1);   // RNE
    return (ushort)(r >> 16);
}
__device__ __forceinline__ float bf2f(ushort h) {
    union { unsigned u; float f; } v; v.u = ((unsigned)h) << 16;
    return v.f;
}
__device__ __forceinline__ void split_bf(float f, ushort& hi, ushort& lo) {
    hi = f2bf(f);
    lo = f2bf(f - bf2f(hi));
}

// ---------------- CSR build (3 graphs in one dispatch) ----------------
__global__ __launch_bounds__(256) void hist3(const int* __restrict__ d0,
                                             const int* __restrict__ d1,
                                             const int* __restrict__ d2,
                                             int* __restrict__ cnt) {
    int g = blockIdx.x / BLOCKS_E;
    int e = (blockIdx.x % BLOCKS_E) * 256 + threadIdx.x;
    const int* d = (g == 0) ? d0 : (g == 1) ? d1 : d2;
    if (e < EE) atomicAdd(&cnt[g * NN + d[e]], 1);
}

__global__ __launch_bounds__(256) void inv_kernel(const int* __restrict__ cnt,
                                                  float* __restrict__ invd, int n) {
    int i = blockIdx.x * blockDim.x + threadIdx.x;
    if (i < n) invd[i] = 1.0f / fmaxf((float)cnt[i], 1.0f);
}

// one block per graph: exclusive prefix-sum cnt[g*NN..] -> rowptr[g*(NN+1)..]
__global__ __launch_bounds__(1024) void scan_kernel(const int* __restrict__ cnt,
                                                    int* __restrict__ rowptr) {
    __shared__ int part[1024];
    int g = blockIdx.x;
    const int* c = cnt + g * NN;
    int* rp = rowptr + g * (NN + 1);
    int tid = threadIdx.x;
    const int CH = (NN + 1023) / 1024;
    int i0 = tid * CH;
    int s = 0;
    for (int i = 0; i < CH; ++i) { int idx = i0 + i; if (idx < NN) s += c[idx]; }
    part[tid] = s;
    __syncthreads();
    for (int off = 1; off < 1024; off <<= 1) {
        int v = (tid >= off) ? part[tid - off] : 0;
        __syncthreads();
        part[tid] += v;
        __syncthreads();
    }
    int run = (tid > 0) ? part[tid - 1] : 0;
    for (int i = 0; i < CH; ++i) {
        int idx = i0 + i;
        if (idx < NN) { rp[idx] = run; run += c[idx]; }
    }
    if (tid == 1023) rp[NN] = part[1023];
}

__global__ __launch_bounds__(256) void bucket3(const int* __restrict__ s0, const int* __restrict__ d0, const float* __restrict__ w0,
                                               const int* __restrict__ s1, const int* __restrict__ d1, const float* __restrict__ w1,
                                               const int* __restrict__ s2, const int* __restrict__ d2,
                                               const int* __restrict__ rowptr,
                                               int* __restrict__ cursor,
                                               int* __restrict__ src_s,
                                               float* __restrict__ ew_s) {
    int g = blockIdx.x / BLOCKS_E;
    int e = (blockIdx.x % BLOCKS_E) * 256 + threadIdx.x;
    if (e >= EE) return;
    const int* src = (g == 0) ? s0 : (g == 1) ? s1 : s2;
    const int* dst = (g == 0) ? d0 : (g == 1) ? d1 : d2;
    const float* ew = (g == 0) ? w0 : (g == 1) ? w1 : nullptr;
    int d = dst[e];
    int pos = rowptr[g * (NN + 1) + d] + atomicAdd(&cursor[g * NN + d], 1);
    src_s[g * EE + pos] = src[e];
    ew_s[g * EE + pos] = ew ? ew[e] : 1.0f;
}

// ---------------- pull aggregation, 3 graphs, 4-way ILP ----------------
__global__ __launch_bounds__(256) void pull_cast3(const float* __restrict__ x,
                                                  const int* __restrict__ rowptr,
                                                  const int* __restrict__ src_s,
                                                  const float* __restrict__ ew_s,
                                                  const float* __restrict__ invd,
                                                  ushort* __restrict__ aggh,
                                                  ushort* __restrict__ aggl) {
    int wid = (blockIdx.x * blockDim.x + threadIdx.x) >> 6;
    int lane = threadIdx.x & 63;
    if (wid >= 3 * NN) return;
    int g = wid / NN, n = wid % NN;
    const int* rp = rowptr + g * (NN + 1);
    const int* ss = src_s + (size_t)g * EE;
    const float* es = ew_s + (size_t)g * EE;
    int beg = rp[n], end = rp[n + 1];
    float a0 = 0.f, a1 = 0.f, a2 = 0.f, a3 = 0.f;
    int i = beg;
    for (; i + 4 <= end; i += 4) {
        int s0 = ss[i], s1 = ss[i + 1], s2 = ss[i + 2], s3 = ss[i + 3];
        float w0 = es[i], w1 = es[i + 1], w2 = es[i + 2], w3 = es[i + 3];
        a0 = fmaf(x[s0 * DD + lane], w0, a0);
        a1 = fmaf(x[s1 * DD + lane], w1, a1);
        a2 = fmaf(x[s2 * DD + lane], w2, a2);
        a3 = fmaf(x[s3 * DD + lane], w3, a3);
    }
    for (; i < end; ++i) a0 = fmaf(x[ss[i] * DD + lane], es[i], a0);
    float acc = (a0 + a1) + (a2 + a3);
    ushort hi, lo; split_bf(acc * invd[g * NN + n], hi, lo);
    aggh[(size_t)wid * 64 + lane] = hi;
    aggl[(size_t)wid * 64 + lane] = lo;
}

__global__ __launch_bounds__(256) void pull_combine3(const float* __restrict__ xn,  // [3][NN][64]
                                                     const int* __restrict__ rowptr,
                                                     const int* __restrict__ src_s,
                                                     const float* __restrict__ ew_s,
                                                     const float* __restrict__ invd,
                                                     const float* __restrict__ b_pr,
                                                     const float* __restrict__ b_cc,
                                                     const float* __restrict__ b_ap,
                                                     float* __restrict__ o_pr,
                                                     float* __restrict__ o_cc,
                                                     float* __restrict__ o_ap) {
    int wid = (blockIdx.x * blockDim.x + threadIdx.x) >> 6;
    int lane = threadIdx.x & 63;
    if (wid >= 3 * NN) return;
    int g = wid / NN, n = wid % NN;
    const int* rp = rowptr + g * (NN + 1);
    const int* ss = src_s + (size_t)g * EE;
    const float* es = ew_s + (size_t)g * EE;
    const float* x = xn + (size_t)g * NN * 64;
    const float* bias = (g == 0) ? b_pr : (g == 1) ? b_cc : b_ap;
    float* out = (g == 0) ? o_pr : (g == 1) ? o_cc : o_ap;
    int beg = rp[n], end = rp[n + 1];
    float a0 = 0.f, a1 = 0.f, a2 = 0.f, a3 = 0.f;
    int i = beg;
    for (; i + 4 <= end; i += 4) {
        int s0 = ss[i], s1 = ss[i + 1], s2 = ss[i + 2], s3 = ss[i + 3];
        float w0 = es[i], w1 = es[i + 1], w2 = es[i + 2], w3 = es[i + 3];
        a0 = fmaf(x[s0 * DD + lane], w0, a0);
        a1 = fmaf(x[s1 * DD + lane], w1, a1);
        a2 = fmaf(x[s2 * DD + lane], w2, a2);
        a3 = fmaf(x[s3 * DD + lane], w3, a3);
    }
    for (; i < end; ++i) a0 = fmaf(x[ss[i] * DD + lane], es[i], a0);
    float acc = (a0 + a1) + (a2 + a3);
    out[n * DD + lane] += acc * invd[g * NN + n] + bias[lane];
}

// ---------------- bf16 hi/lo packing ----------------
__global__ __launch_bounds__(256) void cast_x_kernel(const float* __restrict__ x,
                                                     ushort* __restrict__ xh,
                                                     ushort* __restrict__ xl) {
    int t = blockIdx.x * blockDim.x + threadIdx.x;
    if (t >= NN * DD) return;
    ushort hi, lo; split_bf(x[t], hi, lo);
    xh[t] = hi;
    xl[t] = lo;
}

// Wt[c][k]: k<64 -> Ws[k][c], else Wn[k-64][c]   (stacked, transposed; KT=128)
template <int NC>
__global__ __launch_bounds__(256) void pack_w0(const float* __restrict__ Ws,
                                               const float* __restrict__ Wn,
                                               ushort* __restrict__ Wh,
                                               ushort* __restrict__ Wl) {
    int t = blockIdx.x * blockDim.x + threadIdx.x;
    if (t >= NC * 128) return;
    int c = t / 128, k = t % 128;
    float v = (k < 64) ? Ws[k * NC + c] : Wn[(k - 64) * NC + c];
    ushort hi, lo; split_bf(v, hi, lo);
    Wh[t] = hi; Wl[t] = lo;
}

// Wt[c][k] (c<128, k<KT): c<64 -> Ws[k][c], else Wn[k][c-64]
template <int KT>
__global__ __launch_bounds__(256) void pack_w1(const float* __restrict__ Ws,
                                               const float* __restrict__ Wn,
                                               ushort* __restrict__ Wh,
                                               ushort* __restrict__ Wl) {
    int t = blockIdx.x * blockDim.x + threadIdx.x;
    if (t >= 128 * KT) return;
    int c = t / KT, k = t % KT;
    float v = (c < 64) ? Ws[k * 64 + c] : Wn[k * 64 + (c - 64)];
    ushort hi, lo; split_bf(v, hi, lo);
    Wh[t] = hi; Wl[t] = lo;
}

// ---------------- FUSED layer0+layer1 v3: high per-wave ILP ----------------
// 4 waves (256 thr), 16 rows/block. Stage 1: each wave covers H/4 cols (NCT1=H/64
// 16-col tiles); A-fragments for all K=128 hoisted to registers once; per-c
// epilogue keeps acc pressure low so the unrolled c-loop pipelines 8 loads deep.
// Stage 2: each wave covers 32 cols, K=H unrolled. Branch = blockIdx.x / nblk.
template <int H>
__global__ __launch_bounds__(256, 4) void fused_sage3(
    const ushort* __restrict__ xh, const ushort* __restrict__ xl,       // [NN][64]
    const ushort* __restrict__ aggh, const ushort* __restrict__ aggl,   // [branches][NN][64]
    const ushort* __restrict__ W0h0, const ushort* __restrict__ W0l0,
    const ushort* __restrict__ W1h0, const ushort* __restrict__ W1l0,
    const ushort* __restrict__ W0h1, const ushort* __restrict__ W0l1,
    const ushort* __restrict__ W1h1, const ushort* __restrict__ W1l1,
    const float* __restrict__ b0_0, const float* __restrict__ b0_1,
    float* __restrict__ outS0, float* __restrict__ outS1,
    float* __restrict__ xn,                                             // [branches][NN][64]
    int nblk) {
    constexpr int LROW = H + 8;
    __shared__ ushort h1h[16 * LROW];
    __shared__ ushort h1l[16 * LROW];
    int br = blockIdx.x / nblk;
    int rb = blockIdx.x % nblk;
    const ushort* W0h = br ? W0h1 : W0h0;
    const ushort* W0l = br ? W0l1 : W0l0;
    const ushort* W1h = br ? W1h1 : W1h0;
    const ushort* W1l = br ? W1l1 : W1l0;
    const float* b0 = br ? b0_1 : b0_0;
    float* outS = br ? outS1 : outS0;
    float* outX = xn + (size_t)br * NN * 64;
    const ushort* agh = aggh + (size_t)br * NN * 64;
    const ushort* agl = aggl + (size_t)br * NN * 64;

    int wv = threadIdx.x >> 6;
    int lane = threadIdx.x & 63;
    int lrow = lane & 15;
    int koff = (lane >> 4) * 8;
    int row0 = rb * 16;

    // ---- stage 1: h1[16][H] = relu([x|agg] @ W0 + b0) -> LDS hi/lo ----
    {
        constexpr int COLS1 = H / 4;
        constexpr int NCT1 = COLS1 / 16;
        const size_t aoff = (size_t)(row0 + lrow) * 64 + koff;
        // hoist A fragments for all 4 K-chunks (chunks 0,1 = x; 2,3 = agg)
        short8 aFh[4], aFl[4];
#pragma unroll
        for (int kk = 0; kk < 2; ++kk) {
            aFh[kk]     = *(const short8*)(xh + aoff + kk * 32);
            aFl[kk]     = *(const short8*)(xl + aoff + kk * 32);
            aFh[2 + kk] = *(const short8*)(agh + aoff + kk * 32);
            aFl[2 + kk] = *(const short8*)(agl + aoff + kk * 32);
        }
        int crow = (lane >> 4) * 4;
#pragma unroll
        for (int c = 0; c < NCT1; ++c) {
            int bcol = wv * COLS1 + c * 16 + lrow;
            const ushort* bh = W0h + (size_t)bcol * 128 + koff;
            const ushort* bl = W0l + (size_t)bcol * 128 + koff;
            f32x4 h = {}, l = {};
#pragma unroll
            for (int kk = 0; kk < 4; ++kk) {
                short8 b_h = *(const short8*)(bh + kk * 32);
                short8 b_l = *(const short8*)(bl + kk * 32);
                h = __builtin_amdgcn_mfma_f32_16x16x32_bf16(aFh[kk], b_h, h, 0, 0, 0);
                l = __builtin_amdgcn_mfma_f32_16x16x32_bf16(aFl[kk], b_h, l, 0, 0, 0);
                l = __builtin_amdgcn_mfma_f32_16x16x32_bf16(aFh[kk], b_l, l, 0, 0, 0);
            }
            int col = wv * COLS1 + c * 16 + lrow;
            float bb = b0[col];
#pragma unroll
            for (int r = 0; r < 4; ++r) {
                float v = fmaxf(h[r] + l[r] + bb, 0.0f);
                ushort hi, lo; split_bf(v, hi, lo);
                h1h[(crow + r) * LROW + col] = hi;
                h1l[(crow + r) * LROW + col] = lo;
            }
        }
    }
    __syncthreads();

    // ---- stage 2: C[16][128] = h1 @ W1; cols 0-63 -> outS, 64-127 -> xn ----
    {
        f32x4 cH[2] = {};
        f32x4 cL[2] = {};
#pragma unroll 4
        for (int k0 = 0; k0 < H; k0 += 32) {
            short8 a_h = *(const short8*)&h1h[lrow * LROW + koff + k0];
            short8 a_l = *(const short8*)&h1l[lrow * LROW + koff + k0];
#pragma unroll
            for (int c = 0; c < 2; ++c) {
                int bcol = wv * 32 + c * 16 + lrow;
                short8 b_h = *(const short8*)(W1h + (size_t)bcol * H + koff + k0);
                short8 b_l = *(const short8*)(W1l + (size_t)bcol * H + koff + k0);
                cH[c] = __builtin_amdgcn_mfma_f32_16x16x32_bf16(a_h, b_h, cH[c], 0, 0, 0);
                cL[c] = __builtin_amdgcn_mfma_f32_16x16x32_bf16(a_l, b_h, cL[c], 0, 0, 0);
                cL[c] = __builtin_amdgcn_mfma_f32_16x16x32_bf16(a_h, b_l, cL[c], 0, 0, 0);
            }
        }
        int crow = row0 + (lane >> 4) * 4;
#pragma unroll
        for (int c = 0; c < 2; ++c) {
            int col = wv * 32 + c * 16 + lrow;
            float* o = (col < 64) ? (outS + (size_t)crow * 64 + col)
                                  : (outX + (size_t)crow * 64 + (col - 64));
#pragma unroll
            for (int r = 0; r < 4; ++r) {
                o[(size_t)r * 64] = cH[c][r] + cL[c][r];
            }
        }
    }
}

// ---------------- attention reduction ----------------
__global__ __launch_bounds__(256) void att_stage1(const float* __restrict__ pr,
                                                  const float* __restrict__ cc,
                                                  const float* __restrict__ ap,
                                                  const float* __restrict__ attW,
                                                  const float* __restrict__ attb,
                                                  float2* __restrict__ partial) {
    __shared__ float red[8];
    int lane = threadIdx.x & 63;
    int wv = threadIdx.x >> 6;
    int gw = blockIdx.x * 4 + wv;
    const int nwaves = ATT_BLOCKS * 4;
    float b = attb[lane];
    float c0 = 0.f, c1 = 0.f;
    for (int n = gw; n < NN; n += nwaves) {
        float p0 = 0.f, p1 = 0.f;
        for (int k = 0; k < DD; ++k) {
            float w = attW[k * DD + lane];
            p0 = fmaf(pr[n * DD + k], w, p0);
            p1 = fmaf(cc[n * DD + k], w, p1);
        }
        float a = ap[n * DD + lane];
        c0 += a * tanhf(p0 + b);
        c1 += a * tanhf(p1 + b);
    }
#pragma unroll
    for (int off = 32; off; off >>= 1) {
        c0 += __shfl_xor(c0, off);
        c1 += __shfl_xor(c1, off);
    }
    if (lane == 0) { red[wv * 2] = c0; red[wv * 2 + 1] = c1; }
    __syncthreads();
    if (threadIdx.x == 0) {
        partial[blockIdx.x] = make_float2(red[0] + red[2] + red[4] + red[6],
                                          red[1] + red[3] + red[5] + red[7]);
    }
}

__global__ __launch_bounds__(64) void att_stage2(const float2* __restrict__ partial,
                                                 float* __restrict__ w_acc) {
    int lane = threadIdx.x;
    float s0 = 0.f, s1 = 0.f;
    for (int i = lane; i < ATT_BLOCKS; i += 64) {
        float2 p = partial[i];
        s0 += p.x; s1 += p.y;
    }
#pragma unroll
    for (int off = 32; off; off >>= 1) {
        s0 += __shfl_xor(s0, off);
        s1 += __shfl_xor(s1, off);
    }
    if (lane == 0) { w_acc[0] = s0; w_acc[1] = s1; }
}

// ---------------- final (in-place on pr=out) ----------------
__global__ __launch_bounds__(256) void final_kernel(float* __restrict__ pr_out,
                                                    const float* __restrict__ cc,
                                                    const float* __restrict__ w_acc) {
    int t = blockIdx.x * blockDim.x + threadIdx.x;
    if (t >= NN * DD) return;
    float w0 = w_acc[0] * (1.0f / NN);
    float w1 = w_acc[1] * (1.0f / NN);
    float m = fmaxf(w0, w1);
    float e0 = __expf(w0 - m), e1 = __expf(w1 - m);
    float inv = 1.0f / (e0 + e1);
    pr_out[t] = (e0 * pr_out[t] + e1 * cc[t]) * inv;
}

extern "C" void kernel_launch(void* const* d_in, const int* in_sizes, int n_in,
                              void* d_out, int out_size, void* d_ws, size_t ws_size,
                              hipStream_t stream) {
    const float* k_emb  = (const float*)d_in[0];
    const int*   pr_src = (const int*)d_in[1];
    const int*   pr_dst = (const int*)d_in[2];
    const float* pr_ew  = (const float*)d_in[3];
    const int*   cc_src = (const int*)d_in[4];
    const int*   cc_dst = (const int*)d_in[5];
    const float* cc_ew  = (const float*)d_in[6];
    const int*   sps_src = (const int*)d_in[7];
    const int*   sps_dst = (const int*)d_in[8];
    const float* pr_Ws0 = (const float*)d_in[9];
    const float* pr_Wn0 = (const float*)d_in[10];
    const float* pr_b0  = (const float*)d_in[11];
    const float* pr_Ws1 = (const float*)d_in[12];
    const float* pr_Wn1 = (const float*)d_in[13];
    const float* pr_b1  = (const float*)d_in[14];
    const float* cc_Ws0 = (const float*)d_in[15];
    const float* cc_Wn0 = (const float*)d_in[16];
    const float* cc_b0  = (const float*)d_in[17];
    const float* cc_Ws1 = (const float*)d_in[18];
    const float* cc_Wn1 = (const float*)d_in[19];
    const float* cc_b1  = (const float*)d_in[20];
    const float* ap_Ws0 = (const float*)d_in[21];
    const float* ap_Wn0 = (const float*)d_in[22];
    const float* ap_b0  = (const float*)d_in[23];
    const float* ap_Ws1 = (const float*)d_in[24];
    const float* ap_Wn1 = (const float*)d_in[25];
    const float* ap_b1  = (const float*)d_in[26];
    const float* att_W  = (const float*)d_in[27];
    const float* att_b  = (const float*)d_in[28];
    float* out = (float*)d_out;

    // ---- workspace layout (256B-aligned; ~56 MB) ----
    char* base = (char*)d_ws;
    size_t off = 0;
    auto alloc = [&](size_t bytes) -> void* {
        void* p = base + off;
        off = (off + bytes + 255) & ~(size_t)255;
        return p;
    };
    float*  invd   = (float*)alloc((size_t)3 * NN * 4);
    int*    cnt    = (int*)alloc((size_t)3 * NN * 4);
    int*    rowptr = (int*)alloc((size_t)3 * (NN + 1) * 4);
    int*    src_s  = (int*)alloc((size_t)3 * EE * 4);
    float*  ew_s   = (float*)alloc((size_t)3 * EE * 4);
    float*  w_acc  = (float*)alloc(64);
    float2* att_partial = (float2*)alloc(ATT_BLOCKS * 8);
    float*  xn     = (float*)alloc((size_t)3 * NN * DD * 4);   // [3][NN][64]
    float*  out_cc = (float*)alloc((size_t)NN * DD * 4);
    float*  out_ap = (float*)alloc((size_t)NN * DD * 4);
    ushort* xh     = (ushort*)alloc((size_t)NN * DD * 2);
    ushort* xl     = (ushort*)alloc((size_t)NN * DD * 2);
    ushort* aggh   = (ushort*)alloc((size_t)3 * NN * DD * 2);  // [3][NN][64]
    ushort* aggl   = (ushort*)alloc((size_t)3 * NN * DD * 2);
    ushort* W0h_pr = (ushort*)alloc(512 * 128 * 2);
    ushort* W0l_pr = (ushort*)alloc(512 * 128 * 2);
    ushort* W0h_cc = (ushort*)alloc(512 * 128 * 2);
    ushort* W0l_cc = (ushort*)alloc(512 * 128 * 2);
    ushort* W0h_ap = (ushort*)alloc(64 * 128 * 2);
    ushort* W0l_ap = (ushort*)alloc(64 * 128 * 2);
    ushort* W1h_pr = (ushort*)alloc(128 * 512 * 2);
    ushort* W1l_pr = (ushort*)alloc(128 * 512 * 2);
    ushort* W1h_cc = (ushort*)alloc(128 * 512 * 2);
    ushort* W1l_cc = (ushort*)alloc(128 * 512 * 2);
    ushort* W1h_ap = (ushort*)alloc(128 * 64 * 2);
    ushort* W1l_ap = (ushort*)alloc(128 * 64 * 2);
    float*  out_pr = out;   // pr result lives in d_out

    const int TB = 256;
    const int blocks_ND = (NN * DD) / TB;        // 5000
    const int blocks_pull3 = (3 * NN * 64) / TB; // 15000
    const int wpack_big = (512 * 128 + TB - 1) / TB;
    const int wpack_small = (64 * 128 + TB - 1) / TB;

    // ---- prologue: weight packs + x cast + CSR build ----
    pack_w0<512><<<wpack_big, TB, 0, stream>>>(pr_Ws0, pr_Wn0, W0h_pr, W0l_pr);
    pack_w0<512><<<wpack_big, TB, 0, stream>>>(cc_Ws0, cc_Wn0, W0h_cc, W0l_cc);
    pack_w0<64><<<wpack_small, TB, 0, stream>>>(ap_Ws0, ap_Wn0, W0h_ap, W0l_ap);
    pack_w1<512><<<wpack_big, TB, 0, stream>>>(pr_Ws1, pr_Wn1, W1h_pr, W1l_pr);
    pack_w1<512><<<wpack_big, TB, 0, stream>>>(cc_Ws1, cc_Wn1, W1h_cc, W1l_cc);
    pack_w1<64><<<wpack_small, TB, 0, stream>>>(ap_Ws1, ap_Wn1, W1h_ap, W1l_ap);
    cast_x_kernel<<<blocks_ND, TB, 0, stream>>>(k_emb, xh, xl);

    hipMemsetAsync(cnt, 0, (size_t)3 * NN * 4, stream);
    hist3<<<3 * BLOCKS_E, TB, 0, stream>>>(pr_dst, cc_dst, sps_dst, cnt);
    inv_kernel<<<(3 * NN + TB - 1) / TB, TB, 0, stream>>>(cnt, invd, 3 * NN);
    scan_kernel<<<3, 1024, 0, stream>>>(cnt, rowptr);
    hipMemsetAsync(cnt, 0, (size_t)3 * NN * 4, stream);   // cnt becomes cursor
    bucket3<<<3 * BLOCKS_E, TB, 0, stream>>>(pr_src, pr_dst, pr_ew,
                                             cc_src, cc_dst, cc_ew,
                                             sps_src, sps_dst,
                                             rowptr, cnt, src_s, ew_s);

    // ---- layer-0 aggregation for all 3 graphs (one dispatch) ----
    pull_cast3<<<blocks_pull3, TB, 0, stream>>>(k_emb, rowptr, src_s, ew_s, invd, aggh, aggl);

    // ---- fused layer0+layer1: pr+cc in one dispatch, ap separate ----
    fused_sage3<512><<<2 * NBLK, 256, 0, stream>>>(
        xh, xl, aggh, aggl,
        W0h_pr, W0l_pr, W1h_pr, W1l_pr,
        W0h_cc, W0l_cc, W1h_cc, W1l_cc,
        pr_b0, cc_b0, out_pr, out_cc, xn, NBLK);
    fused_sage3<64><<<NBLK, 256, 0, stream>>>(
        xh, xl, aggh + (size_t)2 * NN * 64, aggl + (size_t)2 * NN * 64,
        W0h_ap, W0l_ap, W1h_ap, W1l_ap,
        W0h_ap, W0l_ap, W1h_ap, W1l_ap,
        ap_b0, ap_b0, out_ap, out_ap, xn + (size_t)2 * NN * 64, NBLK);

    // ---- layer-1 aggregation + combine for all 3 graphs (one dispatch) ----
    pull_combine3<<<blocks_pull3, TB, 0, stream>>>(xn, rowptr, src_s, ew_s, invd,
                                                   pr_b1, cc_b1, ap_b1,
                                                   out_pr, out_cc, out_ap);

    // ---- attention fusion ----
    att_stage1<<<ATT_BLOCKS, TB, 0, stream>>>(out_pr, out_cc, out_ap, att_W, att_b, att_partial);
    att_stage2<<<1, 64, 0, stream>>>(att_partial, w_acc);
    final_kernel<<<blocks_ND, TB, 0, stream>>>(out_pr, out_cc, w_acc);
}

// Round 10
// 326.810 us; speedup vs baseline: 6.6879x; 1.3984x over previous
//
#include <hip/hip_runtime.h>

#define NN 20000   // nodes
#define NP 20032   // padded nodes (313*64)
#define DD 64      // emb dim
#define HH 512     // hidden
#define EE 320000  // edges per graph
#define ATT_BLOCKS 625
#define BLOCKS_E (EE / 256) // 1250

typedef __attribute__((ext_vector_type(8))) short short8;   // 8 bf16 = 4 VGPR
typedef __attribute__((ext_vector_type(4))) float f32x4;

__device__ __forceinline__ ushort f2bf(float f) {
    union { float f; unsigned u; } v; v.f = f;
    unsigned r = v.u + 0x7FFF + ((v.u >> 16) & 1);   // RNE
    return (ushort)(r >> 16);
}

// ---------------- CSR build (3 graphs in one dispatch) ----------------
__global__ __launch_bounds__(256) void hist3(const int* __restrict__ d0,
                                             const int* __restrict__ d1,
                                             const int* __restrict__ d2,
                                             int* __restrict__ cnt) {
    int g = blockIdx.x / BLOCKS_E;
    int e = (blockIdx.x % BLOCKS_E) * 256 + threadIdx.x;
    const int* d = (g == 0) ? d0 : (g == 1) ? d1 : d2;
    if (e < EE) atomicAdd(&cnt[g * NN + d[e]], 1);
}

__global__ __launch_bounds__(256) void inv_kernel(const int* __restrict__ cnt,
                                                  float* __restrict__ invd, int n) {
    int i = blockIdx.x * blockDim.x + threadIdx.x;
    if (i < n) invd[i] = 1.0f / fmaxf((float)cnt[i], 1.0f);
}

__global__ __launch_bounds__(1024) void scan_kernel(const int* __restrict__ cnt,
                                                    int* __restrict__ rowptr) {
    __shared__ int part[1024];
    int g = blockIdx.x;
    const int* c = cnt + g * NN;
    int* rp = rowptr + g * (NN + 1);
    int tid = threadIdx.x;
    const int CH = (NN + 1023) / 1024;
    int i0 = tid * CH;
    int s = 0;
    for (int i = 0; i < CH; ++i) { int idx = i0 + i; if (idx < NN) s += c[idx]; }
    part[tid] = s;
    __syncthreads();
    for (int off = 1; off < 1024; off <<= 1) {
        int v = (tid >= off) ? part[tid - off] : 0;
        __syncthreads();
        part[tid] += v;
        __syncthreads();
    }
    int run = (tid > 0) ? part[tid - 1] : 0;
    for (int i = 0; i < CH; ++i) {
        int idx = i0 + i;
        if (idx < NN) { rp[idx] = run; run += c[idx]; }
    }
    if (tid == 1023) rp[NN] = part[1023];
}

__global__ __launch_bounds__(256) void bucket3(const int* __restrict__ s0, const int* __restrict__ d0, const float* __restrict__ w0,
                                               const int* __restrict__ s1, const int* __restrict__ d1, const float* __restrict__ w1,
                                               const int* __restrict__ s2, const int* __restrict__ d2,
                                               const int* __restrict__ rowptr,
                                               int* __restrict__ cursor,
                                               int* __restrict__ src_s,
                                               float* __restrict__ ew_s) {
    int g = blockIdx.x / BLOCKS_E;
    int e = (blockIdx.x % BLOCKS_E) * 256 + threadIdx.x;
    if (e >= EE) return;
    const int* src = (g == 0) ? s0 : (g == 1) ? s1 : s2;
    const int* dst = (g == 0) ? d0 : (g == 1) ? d1 : d2;
    const float* ew = (g == 0) ? w0 : (g == 1) ? w1 : nullptr;
    int d = dst[e];
    int pos = rowptr[g * (NN + 1) + d] + atomicAdd(&cursor[g * NN + d], 1);
    src_s[g * EE + pos] = src[e];
    ew_s[g * EE + pos] = ew ? ew[e] : 1.0f;
}

// ---------------- pull aggregation, 3 graphs, 4-way ILP -> bf16 agg ----------------
__global__ __launch_bounds__(256) void pull_cast3(const float* __restrict__ x,
                                                  const int* __restrict__ rowptr,
                                                  const int* __restrict__ src_s,
                                                  const float* __restrict__ ew_s,
                                                  const float* __restrict__ invd,
                                                  ushort* __restrict__ aggh) {
    int wid = (blockIdx.x * blockDim.x + threadIdx.x) >> 6;
    int lane = threadIdx.x & 63;
    if (wid >= 3 * NN) return;
    int g = wid / NN, n = wid % NN;
    const int* rp = rowptr + g * (NN + 1);
    const int* ss = src_s + (size_t)g * EE;
    const float* es = ew_s + (size_t)g * EE;
    int beg = rp[n], end = rp[n + 1];
    float a0 = 0.f, a1 = 0.f, a2 = 0.f, a3 = 0.f;
    int i = beg;
    for (; i + 4 <= end; i += 4) {
        int s0 = ss[i], s1 = ss[i + 1], s2 = ss[i + 2], s3 = ss[i + 3];
        float w0 = es[i], w1 = es[i + 1], w2 = es[i + 2], w3 = es[i + 3];
        a0 = fmaf(x[s0 * DD + lane], w0, a0);
        a1 = fmaf(x[s1 * DD + lane], w1, a1);
        a2 = fmaf(x[s2 * DD + lane], w2, a2);
        a3 = fmaf(x[s3 * DD + lane], w3, a3);
    }
    for (; i < end; ++i) a0 = fmaf(x[ss[i] * DD + lane], es[i], a0);
    float acc = (a0 + a1) + (a2 + a3);
    aggh[((size_t)g * NP + n) * 64 + lane] = f2bf(acc * invd[g * NN + n]);
}

__global__ __launch_bounds__(256) void pull_combine3(const float* __restrict__ xn,  // [3][NN][64]
                                                     const int* __restrict__ rowptr,
                                                     const int* __restrict__ src_s,
                                                     const float* __restrict__ ew_s,
                                                     const float* __restrict__ invd,
                                                     const float* __restrict__ b_pr,
                                                     const float* __restrict__ b_cc,
                                                     const float* __restrict__ b_ap,
                                                     float* __restrict__ o_pr,
                                                     float* __restrict__ o_cc,
                                                     float* __restrict__ o_ap) {
    int wid = (blockIdx.x * blockDim.x + threadIdx.x) >> 6;
    int lane = threadIdx.x & 63;
    if (wid >= 3 * NN) return;
    int g = wid / NN, n = wid % NN;
    const int* rp = rowptr + g * (NN + 1);
    const int* ss = src_s + (size_t)g * EE;
    const float* es = ew_s + (size_t)g * EE;
    const float* x = xn + (size_t)g * NN * 64;
    const float* bias = (g == 0) ? b_pr : (g == 1) ? b_cc : b_ap;
    float* out = (g == 0) ? o_pr : (g == 1) ? o_cc : o_ap;
    int beg = rp[n], end = rp[n + 1];
    float a0 = 0.f, a1 = 0.f, a2 = 0.f, a3 = 0.f;
    int i = beg;
    for (; i + 4 <= end; i += 4) {
        int s0 = ss[i], s1 = ss[i + 1], s2 = ss[i + 2], s3 = ss[i + 3];
        float w0 = es[i], w1 = es[i + 1], w2 = es[i + 2], w3 = es[i + 3];
        a0 = fmaf(x[s0 * DD + lane], w0, a0);
        a1 = fmaf(x[s1 * DD + lane], w1, a1);
        a2 = fmaf(x[s2 * DD + lane], w2, a2);
        a3 = fmaf(x[s3 * DD + lane], w3, a3);
    }
    for (; i < end; ++i) a0 = fmaf(x[ss[i] * DD + lane], es[i], a0);
    float acc = (a0 + a1) + (a2 + a3);
    out[n * DD + lane] += acc * invd[g * NN + n] + bias[lane];
}

// ---------------- bf16 packing ----------------
__global__ __launch_bounds__(256) void cast_x_kernel(const float* __restrict__ x,
                                                     ushort* __restrict__ xh) {
    int t = blockIdx.x * blockDim.x + threadIdx.x;
    if (t >= NN * DD) return;
    xh[t] = f2bf(x[t]);
}

// Wt[c][k]: k<64 -> Ws[k][c], else Wn[k-64][c]   (stacked, transposed; K=128)
template <int NC>
__global__ __launch_bounds__(256) void pack_w0(const float* __restrict__ Ws,
                                               const float* __restrict__ Wn,
                                               ushort* __restrict__ Wh) {
    int t = blockIdx.x * blockDim.x + threadIdx.x;
    if (t >= NC * 128) return;
    int c = t / 128, k = t % 128;
    Wh[t] = f2bf((k < 64) ? Ws[k * NC + c] : Wn[(k - 64) * NC + c]);
}

// Wt[c][k] (c<128, k<KT): c<64 -> Ws[k][c], else Wn[k][c-64]
template <int KT>
__global__ __launch_bounds__(256) void pack_w1(const float* __restrict__ Ws,
                                               const float* __restrict__ Wn,
                                               ushort* __restrict__ Wh) {
    int t = blockIdx.x * blockDim.x + threadIdx.x;
    if (t >= 128 * KT) return;
    int c = t / KT, k = t % KT;
    Wh[t] = f2bf((c < 64) ? Ws[k * 64 + c] : Wn[k * 64 + (c - 64)]);
}

// ---------------- FUSED layer0+layer1 v4: 64 rows, 8 waves, 4 col-phases ----------------
// A-tile [64][128] = [x|agg] staged in LDS once. Per phase p: stage1 computes
// h1[:, p*128..+128] -> LDS (each wave 16 cols); stage2 accumulates
// C[64][128] += h1_phase @ W1[p*128..,:] (each wave 16 out-cols). C cols 0-63 -> outS,
// 64-127 -> xn. Weight traffic amortized over 64 rows. bf16 single precision.
__global__ __launch_bounds__(512, 4) void fused_sage4(
    const ushort* __restrict__ xh,    // [NP][64]
    const ushort* __restrict__ aggA,  // [branches][NP][64] base
    const ushort* __restrict__ W0a, const ushort* __restrict__ W1a,
    const ushort* __restrict__ W0b, const ushort* __restrict__ W1b,
    const float* __restrict__ b0a, const float* __restrict__ b0b,
    float* __restrict__ outS0, float* __restrict__ outS1,
    float* __restrict__ xn, int nblk) {
    constexpr int LROW = 136;            // ushort pitch (128+8)
    __shared__ ushort Ahs[64 * LROW];
    __shared__ ushort h1s[64 * LROW];
    int br = blockIdx.x / nblk;
    int rb = blockIdx.x % nblk;
    const ushort* W0 = br ? W0b : W0a;
    const ushort* W1 = br ? W1b : W1a;
    const float* b0 = br ? b0b : b0a;
    float* outS = br ? outS1 : outS0;
    float* outX = xn + (size_t)br * NN * 64;
    const ushort* agg = aggA + (size_t)br * NP * 64;
    int row0 = rb * 64;

    int wv = threadIdx.x >> 6;
    int lane = threadIdx.x & 63;
    int lrow = lane & 15;
    int koff = (lane >> 4) * 8;
    int crow = (lane >> 4) * 4;

    // ---- stage A-tile: Ahs[r][0:64]=x, [64:128]=agg ----
    {
        int r = threadIdx.x >> 3;        // 0..63
        int seg = threadIdx.x & 7;       // 0..7, 16 ushorts each
        const ushort* src = (seg < 4) ? (xh + (size_t)(row0 + r) * 64 + seg * 16)
                                      : (agg + (size_t)(row0 + r) * 64 + (seg - 4) * 16);
        *(short8*)&Ahs[r * LROW + seg * 16] = *(const short8*)src;
        *(short8*)&Ahs[r * LROW + seg * 16 + 8] = *(const short8*)(src + 8);
    }
    __syncthreads();

    f32x4 C[4] = {};                     // persistent out acc: 4 rowgroups x 16 cols
#pragma unroll
    for (int p = 0; p < 4; ++p) {
        // ---- stage 1: h1[:, p*128 + wv*16 ..+16] ----
        {
            short8 B[4];
#pragma unroll
            for (int kk = 0; kk < 4; ++kk)
                B[kk] = *(const short8*)(W0 + (size_t)(p * 128 + wv * 16 + lrow) * 128 + kk * 32 + koff);
            f32x4 acc[4] = {};
#pragma unroll
            for (int rg = 0; rg < 4; ++rg) {
#pragma unroll
                for (int kk = 0; kk < 4; ++kk) {
                    short8 a = *(const short8*)&Ahs[(rg * 16 + lrow) * LROW + kk * 32 + koff];
                    acc[rg] = __builtin_amdgcn_mfma_f32_16x16x32_bf16(a, B[kk], acc[rg], 0, 0, 0);
                }
            }
            float bb = b0[p * 128 + wv * 16 + lrow];
#pragma unroll
            for (int rg = 0; rg < 4; ++rg) {
#pragma unroll
                for (int r = 0; r < 4; ++r) {
                    float v = fmaxf(acc[rg][r] + bb, 0.0f);
                    h1s[(rg * 16 + crow + r) * LROW + wv * 16 + lrow] = f2bf(v);
                }
            }
        }
        __syncthreads();
        // ---- stage 2: C += h1_phase @ W1[p*128.., wv*16..+16] ----
        {
            short8 B[4];
#pragma unroll
            for (int kc = 0; kc < 4; ++kc)
                B[kc] = *(const short8*)(W1 + (size_t)(wv * 16 + lrow) * HH + p * 128 + kc * 32 + koff);
#pragma unroll
            for (int rg = 0; rg < 4; ++rg) {
#pragma unroll
                for (int kc = 0; kc < 4; ++kc) {
                    short8 a = *(const short8*)&h1s[(rg * 16 + lrow) * LROW + kc * 32 + koff];
                    C[rg] = __builtin_amdgcn_mfma_f32_16x16x32_bf16(a, B[kc], C[rg], 0, 0, 0);
                }
            }
        }
        __syncthreads();
    }
    // ---- epilogue: C cols 0-63 -> outS, 64-127 -> xn ----
    int col = wv * 16 + lrow;
    float* o = (col < 64) ? (outS + col) : (outX + (col - 64));
#pragma unroll
    for (int rg = 0; rg < 4; ++rg) {
#pragma unroll
        for (int r = 0; r < 4; ++r) {
            int row = row0 + rg * 16 + crow + r;
            if (row < NN) o[(size_t)row * 64] = C[rg][r];
        }
    }
}

// ---------------- FUSED ap branch (64->64->64), bf16, 16 rows, 4 waves ----------------
__global__ __launch_bounds__(256, 4) void fused_sage_ap(
    const ushort* __restrict__ xh,    // [NP][64]
    const ushort* __restrict__ agg,   // [NP][64]
    const ushort* __restrict__ W0,    // [64][128]
    const ushort* __restrict__ W1,    // [128][64]
    const float* __restrict__ b0,
    float* __restrict__ outS,
    float* __restrict__ outX) {
    constexpr int LROW = 72;
    __shared__ ushort h1s[16 * LROW];
    int wv = threadIdx.x >> 6;
    int lane = threadIdx.x & 63;
    int lrow = lane & 15;
    int koff = (lane >> 4) * 8;
    int crow = (lane >> 4) * 4;
    int row0 = blockIdx.x * 16;

    // stage 1: h1[16][64] = relu([x|agg] @ W0 + b0); each wave 16 cols
    {
        const size_t aoff = (size_t)(row0 + lrow) * 64 + koff;
        short8 aF[4];
#pragma unroll
        for (int kk = 0; kk < 2; ++kk) {
            aF[kk]     = *(const short8*)(xh + aoff + kk * 32);
            aF[2 + kk] = *(const short8*)(agg + aoff + kk * 32);
        }
        f32x4 acc = {};
#pragma unroll
        for (int kk = 0; kk < 4; ++kk) {
            short8 b = *(const short8*)(W0 + (size_t)(wv * 16 + lrow) * 128 + kk * 32 + koff);
            acc = __builtin_amdgcn_mfma_f32_16x16x32_bf16(aF[kk], b, acc, 0, 0, 0);
        }
        float bb = b0[wv * 16 + lrow];
#pragma unroll
        for (int r = 0; r < 4; ++r) {
            h1s[(crow + r) * LROW + wv * 16 + lrow] = f2bf(fmaxf(acc[r] + bb, 0.0f));
        }
    }
    __syncthreads();
    // stage 2: C[16][128] = h1 @ W1; each wave 32 cols; K=64
    {
        f32x4 C2[2] = {};
#pragma unroll
        for (int kc = 0; kc < 2; ++kc) {
            short8 a = *(const short8*)&h1s[lrow * LROW + kc * 32 + koff];
#pragma unroll
            for (int c = 0; c < 2; ++c) {
                short8 b = *(const short8*)(W1 + (size_t)(wv * 32 + c * 16 + lrow) * 64 + kc * 32 + koff);
                C2[c] = __builtin_amdgcn_mfma_f32_16x16x32_bf16(a, b, C2[c], 0, 0, 0);
            }
        }
#pragma unroll
        for (int c = 0; c < 2; ++c) {
            int col = wv * 32 + c * 16 + lrow;
            float* o = (col < 64) ? (outS + col) : (outX + (col - 64));
#pragma unroll
            for (int r = 0; r < 4; ++r) {
                int row = row0 + crow + r;
                if (row < NN) o[(size_t)row * 64] = C2[c][r];
            }
        }
    }
}

// ---------------- attention reduction ----------------
__global__ __launch_bounds__(256) void att_stage1(const float* __restrict__ pr,
                                                  const float* __restrict__ cc,
                                                  const float* __restrict__ ap,
                                                  const float* __restrict__ attW,
                                                  const float* __restrict__ attb,
                                                  float2* __restrict__ partial) {
    __shared__ float red[8];
    int lane = threadIdx.x & 63;
    int wv = threadIdx.x >> 6;
    int gw = blockIdx.x * 4 + wv;
    const int nwaves = ATT_BLOCKS * 4;
    float b = attb[lane];
    float c0 = 0.f, c1 = 0.f;
    for (int n = gw; n < NN; n += nwaves) {
        float p0 = 0.f, p1 = 0.f;
        for (int k = 0; k < DD; ++k) {
            float w = attW[k * DD + lane];
            p0 = fmaf(pr[n * DD + k], w, p0);
            p1 = fmaf(cc[n * DD + k], w, p1);
        }
        float a = ap[n * DD + lane];
        c0 += a * tanhf(p0 + b);
        c1 += a * tanhf(p1 + b);
    }
#pragma unroll
    for (int off = 32; off; off >>= 1) {
        c0 += __shfl_xor(c0, off);
        c1 += __shfl_xor(c1, off);
    }
    if (lane == 0) { red[wv * 2] = c0; red[wv * 2 + 1] = c1; }
    __syncthreads();
    if (threadIdx.x == 0) {
        partial[blockIdx.x] = make_float2(red[0] + red[2] + red[4] + red[6],
                                          red[1] + red[3] + red[5] + red[7]);
    }
}

__global__ __launch_bounds__(64) void att_stage2(const float2* __restrict__ partial,
                                                 float* __restrict__ w_acc) {
    int lane = threadIdx.x;
    float s0 = 0.f, s1 = 0.f;
    for (int i = lane; i < ATT_BLOCKS; i += 64) {
        float2 p = partial[i];
        s0 += p.x; s1 += p.y;
    }
#pragma unroll
    for (int off = 32; off; off >>= 1) {
        s0 += __shfl_xor(s0, off);
        s1 += __shfl_xor(s1, off);
    }
    if (lane == 0) { w_acc[0] = s0; w_acc[1] = s1; }
}

// ---------------- final (in-place on pr=out) ----------------
__global__ __launch_bounds__(256) void final_kernel(float* __restrict__ pr_out,
                                                    const float* __restrict__ cc,
                                                    const float* __restrict__ w_acc) {
    int t = blockIdx.x * blockDim.x + threadIdx.x;
    if (t >= NN * DD) return;
    float w0 = w_acc[0] * (1.0f / NN);
    float w1 = w_acc[1] * (1.0f / NN);
    float m = fmaxf(w0, w1);
    float e0 = __expf(w0 - m), e1 = __expf(w1 - m);
    float inv = 1.0f / (e0 + e1);
    pr_out[t] = (e0 * pr_out[t] + e1 * cc[t]) * inv;
}

extern "C" void kernel_launch(void* const* d_in, const int* in_sizes, int n_in,
                              void* d_out, int out_size, void* d_ws, size_t ws_size,
                              hipStream_t stream) {
    const float* k_emb  = (const float*)d_in[0];
    const int*   pr_src = (const int*)d_in[1];
    const int*   pr_dst = (const int*)d_in[2];
    const float* pr_ew  = (const float*)d_in[3];
    const int*   cc_src = (const int*)d_in[4];
    const int*   cc_dst = (const int*)d_in[5];
    const float* cc_ew  = (const float*)d_in[6];
    const int*   sps_src = (const int*)d_in[7];
    const int*   sps_dst = (const int*)d_in[8];
    const float* pr_Ws0 = (const float*)d_in[9];
    const float* pr_Wn0 = (const float*)d_in[10];
    const float* pr_b0  = (const float*)d_in[11];
    const float* pr_Ws1 = (const float*)d_in[12];
    const float* pr_Wn1 = (const float*)d_in[13];
    const float* pr_b1  = (const float*)d_in[14];
    const float* cc_Ws0 = (const float*)d_in[15];
    const float* cc_Wn0 = (const float*)d_in[16];
    const float* cc_b0  = (const float*)d_in[17];
    const float* cc_Ws1 = (const float*)d_in[18];
    const float* cc_Wn1 = (const float*)d_in[19];
    const float* cc_b1  = (const float*)d_in[20];
    const float* ap_Ws0 = (const float*)d_in[21];
    const float* ap_Wn0 = (const float*)d_in[22];
    const float* ap_b0  = (const float*)d_in[23];
    const float* ap_Ws1 = (const float*)d_in[24];
    const float* ap_Wn1 = (const float*)d_in[25];
    const float* ap_b1  = (const float*)d_in[26];
    const float* att_W  = (const float*)d_in[27];
    const float* att_b  = (const float*)d_in[28];
    float* out = (float*)d_out;

    // ---- workspace layout (256B-aligned) ----
    char* base = (char*)d_ws;
    size_t off = 0;
    auto alloc = [&](size_t bytes) -> void* {
        void* p = base + off;
        off = (off + bytes + 255) & ~(size_t)255;
        return p;
    };
    float*  invd   = (float*)alloc((size_t)3 * NN * 4);
    int*    cnt    = (int*)alloc((size_t)3 * NN * 4);
    int*    rowptr = (int*)alloc((size_t)3 * (NN + 1) * 4);
    int*    src_s  = (int*)alloc((size_t)3 * EE * 4);
    float*  ew_s   = (float*)alloc((size_t)3 * EE * 4);
    float*  w_acc  = (float*)alloc(64);
    float2* att_partial = (float2*)alloc(ATT_BLOCKS * 8);
    float*  xn     = (float*)alloc((size_t)3 * NN * DD * 4);   // [3][NN][64]
    float*  out_cc = (float*)alloc((size_t)NN * DD * 4);
    float*  out_ap = (float*)alloc((size_t)NN * DD * 4);
    ushort* xh     = (ushort*)alloc((size_t)NP * DD * 2);      // padded
    ushort* aggh   = (ushort*)alloc((size_t)3 * NP * DD * 2);  // [3][NP][64] padded
    ushort* W0h_pr = (ushort*)alloc(512 * 128 * 2);
    ushort* W0h_cc = (ushort*)alloc(512 * 128 * 2);
    ushort* W0h_ap = (ushort*)alloc(64 * 128 * 2);
    ushort* W1h_pr = (ushort*)alloc(128 * 512 * 2);
    ushort* W1h_cc = (ushort*)alloc(128 * 512 * 2);
    ushort* W1h_ap = (ushort*)alloc(128 * 64 * 2);
    float*  out_pr = out;   // pr result lives in d_out

    const int TB = 256;
    const int blocks_ND = (NN * DD) / TB;        // 5000
    const int blocks_pull3 = (3 * NN * 64) / TB; // 15000
    const int wpack_big = (512 * 128 + TB - 1) / TB;
    const int wpack_small = (64 * 128 + TB - 1) / TB;
    const int NBLK64 = NP / 64;                  // 313 row-tiles of 64

    // ---- prologue: weight packs + x cast + CSR build ----
    pack_w0<512><<<wpack_big, TB, 0, stream>>>(pr_Ws0, pr_Wn0, W0h_pr);
    pack_w0<512><<<wpack_big, TB, 0, stream>>>(cc_Ws0, cc_Wn0, W0h_cc);
    pack_w0<64><<<wpack_small, TB, 0, stream>>>(ap_Ws0, ap_Wn0, W0h_ap);
    pack_w1<512><<<wpack_big, TB, 0, stream>>>(pr_Ws1, pr_Wn1, W1h_pr);
    pack_w1<512><<<wpack_big, TB, 0, stream>>>(cc_Ws1, cc_Wn1, W1h_cc);
    pack_w1<64><<<wpack_small, TB, 0, stream>>>(ap_Ws1, ap_Wn1, W1h_ap);
    cast_x_kernel<<<blocks_ND, TB, 0, stream>>>(k_emb, xh);

    hipMemsetAsync(cnt, 0, (size_t)3 * NN * 4, stream);
    hist3<<<3 * BLOCKS_E, TB, 0, stream>>>(pr_dst, cc_dst, sps_dst, cnt);
    inv_kernel<<<(3 * NN + TB - 1) / TB, TB, 0, stream>>>(cnt, invd, 3 * NN);
    scan_kernel<<<3, 1024, 0, stream>>>(cnt, rowptr);
    hipMemsetAsync(cnt, 0, (size_t)3 * NN * 4, stream);   // cnt becomes cursor
    bucket3<<<3 * BLOCKS_E, TB, 0, stream>>>(pr_src, pr_dst, pr_ew,
                                             cc_src, cc_dst, cc_ew,
                                             sps_src, sps_dst,
                                             rowptr, cnt, src_s, ew_s);

    // ---- layer-0 aggregation for all 3 graphs (one dispatch) ----
    pull_cast3<<<blocks_pull3, TB, 0, stream>>>(k_emb, rowptr, src_s, ew_s, invd, aggh);

    // ---- fused layer0+layer1: pr+cc (64-row phased), ap separate ----
    fused_sage4<<<2 * NBLK64, 512, 0, stream>>>(
        xh, aggh,
        W0h_pr, W1h_pr, W0h_cc, W1h_cc,
        pr_b0, cc_b0, out_pr, out_cc, xn, NBLK64);
    fused_sage_ap<<<NP / 16, 256, 0, stream>>>(
        xh, aggh + (size_t)2 * NP * 64,
        W0h_ap, W1h_ap, ap_b0, out_ap, xn + (size_t)2 * NN * 64);

    // ---- layer-1 aggregation + combine for all 3 graphs (one dispatch) ----
    pull_combine3<<<blocks_pull3, TB, 0, stream>>>(xn, rowptr, src_s, ew_s, invd,
                                                   pr_b1, cc_b1, ap_b1,
                                                   out_pr, out_cc, out_ap);

    // ---- attention fusion ----
    att_stage1<<<ATT_BLOCKS, TB, 0, stream>>>(out_pr, out_cc, out_ap, att_W, att_b, att_partial);
    att_stage2<<<1, 64, 0, stream>>>(att_partial, w_acc);
    final_kernel<<<blocks_ND, TB, 0, stream>>>(out_pr, out_cc, w_acc);
}

// Round 11
// 303.647 us; speedup vs baseline: 7.1981x; 1.0763x over previous
//
#include <hip/hip_runtime.h>

#define NN 20000   // nodes
#define NP 20032   // padded nodes (313*64)
#define DD 64      // emb dim
#define HH 512     // hidden
#define EE 320000  // edges per graph
#define ATT_BLOCKS 625
#define BLOCKS_E (EE / 256) // 1250

typedef __attribute__((ext_vector_type(8))) short short8;   // 8 bf16 = 4 VGPR
typedef __attribute__((ext_vector_type(4))) float f32x4;

__device__ __forceinline__ ushort f2bf(float f) {
    union { float f; unsigned u; } v; v.f = f;
    unsigned r = v.u + 0x7FFF + ((v.u >> 16) & 1);   // RNE
    return (ushort)(r >> 16);
}

// ---------------- CSR build ----------------
__global__ __launch_bounds__(256) void hist3(const int* __restrict__ d0,
                                             const int* __restrict__ d1,
                                             const int* __restrict__ d2,
                                             int* __restrict__ cnt) {
    int g = blockIdx.x / BLOCKS_E;
    int e = (blockIdx.x % BLOCKS_E) * 256 + threadIdx.x;
    const int* d = (g == 0) ? d0 : (g == 1) ? d1 : d2;
    if (e < EE) atomicAdd(&cnt[g * NN + d[e]], 1);
}

__global__ __launch_bounds__(256) void inv_kernel(const int* __restrict__ cnt,
                                                  float* __restrict__ invd, int n) {
    int i = blockIdx.x * blockDim.x + threadIdx.x;
    if (i < n) invd[i] = 1.0f / fmaxf((float)cnt[i], 1.0f);
}

__global__ __launch_bounds__(1024) void scan_kernel(const int* __restrict__ cnt,
                                                    int* __restrict__ rowptr) {
    __shared__ int part[1024];
    int g = blockIdx.x;
    const int* c = cnt + g * NN;
    int* rp = rowptr + g * (NN + 1);
    int tid = threadIdx.x;
    const int CH = (NN + 1023) / 1024;
    int i0 = tid * CH;
    int s = 0;
    for (int i = 0; i < CH; ++i) { int idx = i0 + i; if (idx < NN) s += c[idx]; }
    part[tid] = s;
    __syncthreads();
    for (int off = 1; off < 1024; off <<= 1) {
        int v = (tid >= off) ? part[tid - off] : 0;
        __syncthreads();
        part[tid] += v;
        __syncthreads();
    }
    int run = (tid > 0) ? part[tid - 1] : 0;
    for (int i = 0; i < CH; ++i) {
        int idx = i0 + i;
        if (idx < NN) { rp[idx] = run; run += c[idx]; }
    }
    if (tid == 1023) rp[NN] = part[1023];
}

// packed scatter: pr/cc -> int2{src, bits(ew)}; sps -> int src only
__global__ __launch_bounds__(256) void bucket3(const int* __restrict__ s0, const int* __restrict__ d0, const float* __restrict__ w0,
                                               const int* __restrict__ s1, const int* __restrict__ d1, const float* __restrict__ w1,
                                               const int* __restrict__ s2, const int* __restrict__ d2,
                                               const int* __restrict__ rowptr,
                                               int* __restrict__ cursor,
                                               int2* __restrict__ edge_s,   // [2*EE]
                                               int* __restrict__ src_s2) {  // [EE]
    int g = blockIdx.x / BLOCKS_E;
    int e = (blockIdx.x % BLOCKS_E) * 256 + threadIdx.x;
    if (e >= EE) return;
    const int* src = (g == 0) ? s0 : (g == 1) ? s1 : s2;
    const int* dst = (g == 0) ? d0 : (g == 1) ? d1 : d2;
    int d = dst[e];
    int pos = rowptr[g * (NN + 1) + d] + atomicAdd(&cursor[g * NN + d], 1);
    if (g < 2) {
        float w = (g == 0) ? w0[e] : w1[e];
        edge_s[(size_t)g * EE + pos] = make_int2(src[e], __float_as_int(w));
    } else {
        src_s2[pos] = src[e];
    }
}

// ---------------- pull aggregation, 3 graphs, 4-way ILP -> bf16 agg ----------------
__global__ __launch_bounds__(256) void pull_cast3(const float* __restrict__ x,
                                                  const int* __restrict__ rowptr,
                                                  const int2* __restrict__ edge_s,
                                                  const int* __restrict__ src_s2,
                                                  const float* __restrict__ invd,
                                                  ushort* __restrict__ aggh) {
    int wid = (blockIdx.x * blockDim.x + threadIdx.x) >> 6;
    int lane = threadIdx.x & 63;
    if (wid >= 3 * NN) return;
    int g = wid / NN, n = wid % NN;
    const int* rp = rowptr + g * (NN + 1);
    int beg = rp[n], end = rp[n + 1];
    float a0 = 0.f, a1 = 0.f, a2 = 0.f, a3 = 0.f;
    int i = beg;
    if (g < 2) {
        const int2* es = edge_s + (size_t)g * EE;
        for (; i + 4 <= end; i += 4) {
            int2 e0 = es[i], e1 = es[i + 1], e2 = es[i + 2], e3 = es[i + 3];
            a0 = fmaf(x[e0.x * DD + lane], __int_as_float(e0.y), a0);
            a1 = fmaf(x[e1.x * DD + lane], __int_as_float(e1.y), a1);
            a2 = fmaf(x[e2.x * DD + lane], __int_as_float(e2.y), a2);
            a3 = fmaf(x[e3.x * DD + lane], __int_as_float(e3.y), a3);
        }
        for (; i < end; ++i) { int2 e0 = es[i]; a0 = fmaf(x[e0.x * DD + lane], __int_as_float(e0.y), a0); }
    } else {
        for (; i + 4 <= end; i += 4) {
            int s0 = src_s2[i], s1 = src_s2[i + 1], s2 = src_s2[i + 2], s3 = src_s2[i + 3];
            a0 += x[s0 * DD + lane];
            a1 += x[s1 * DD + lane];
            a2 += x[s2 * DD + lane];
            a3 += x[s3 * DD + lane];
        }
        for (; i < end; ++i) a0 += x[src_s2[i] * DD + lane];
    }
    float acc = (a0 + a1) + (a2 + a3);
    aggh[((size_t)g * NP + n) * 64 + lane] = f2bf(acc * invd[g * NN + n]);
}

__global__ __launch_bounds__(256) void pull_combine3(const float* __restrict__ xn,  // [3][NN][64]
                                                     const int* __restrict__ rowptr,
                                                     const int2* __restrict__ edge_s,
                                                     const int* __restrict__ src_s2,
                                                     const float* __restrict__ invd,
                                                     const float* __restrict__ b_pr,
                                                     const float* __restrict__ b_cc,
                                                     const float* __restrict__ b_ap,
                                                     float* __restrict__ o_pr,
                                                     float* __restrict__ o_cc,
                                                     float* __restrict__ o_ap) {
    int wid = (blockIdx.x * blockDim.x + threadIdx.x) >> 6;
    int lane = threadIdx.x & 63;
    if (wid >= 3 * NN) return;
    int g = wid / NN, n = wid % NN;
    const int* rp = rowptr + g * (NN + 1);
    const float* x = xn + (size_t)g * NN * 64;
    const float* bias = (g == 0) ? b_pr : (g == 1) ? b_cc : b_ap;
    float* out = (g == 0) ? o_pr : (g == 1) ? o_cc : o_ap;
    int beg = rp[n], end = rp[n + 1];
    float a0 = 0.f, a1 = 0.f, a2 = 0.f, a3 = 0.f;
    int i = beg;
    if (g < 2) {
        const int2* es = edge_s + (size_t)g * EE;
        for (; i + 4 <= end; i += 4) {
            int2 e0 = es[i], e1 = es[i + 1], e2 = es[i + 2], e3 = es[i + 3];
            a0 = fmaf(x[e0.x * DD + lane], __int_as_float(e0.y), a0);
            a1 = fmaf(x[e1.x * DD + lane], __int_as_float(e1.y), a1);
            a2 = fmaf(x[e2.x * DD + lane], __int_as_float(e2.y), a2);
            a3 = fmaf(x[e3.x * DD + lane], __int_as_float(e3.y), a3);
        }
        for (; i < end; ++i) { int2 e0 = es[i]; a0 = fmaf(x[e0.x * DD + lane], __int_as_float(e0.y), a0); }
    } else {
        for (; i + 4 <= end; i += 4) {
            int s0 = src_s2[i], s1 = src_s2[i + 1], s2 = src_s2[i + 2], s3 = src_s2[i + 3];
            a0 += x[s0 * DD + lane];
            a1 += x[s1 * DD + lane];
            a2 += x[s2 * DD + lane];
            a3 += x[s3 * DD + lane];
        }
        for (; i < end; ++i) a0 += x[src_s2[i] * DD + lane];
    }
    float acc = (a0 + a1) + (a2 + a3);
    out[n * DD + lane] += acc * invd[g * NN + n] + bias[lane];
}

// ---------------- consolidated prologue pack: 6 weight packs + x cast ----------------
// blocks [0,256) W0_pr | [256,512) W0_cc | [512,768) W1_pr | [768,1024) W1_cc |
// [1024,1056) W0_ap | [1056,1088) W1_ap | [1088,6088) cast x
__global__ __launch_bounds__(256) void pack_all(
    const float* __restrict__ pr_Ws0, const float* __restrict__ pr_Wn0,
    const float* __restrict__ cc_Ws0, const float* __restrict__ cc_Wn0,
    const float* __restrict__ pr_Ws1, const float* __restrict__ pr_Wn1,
    const float* __restrict__ cc_Ws1, const float* __restrict__ cc_Wn1,
    const float* __restrict__ ap_Ws0, const float* __restrict__ ap_Wn0,
    const float* __restrict__ ap_Ws1, const float* __restrict__ ap_Wn1,
    const float* __restrict__ k_emb,
    ushort* __restrict__ W0h_pr, ushort* __restrict__ W0h_cc,
    ushort* __restrict__ W1h_pr, ushort* __restrict__ W1h_cc,
    ushort* __restrict__ W0h_ap, ushort* __restrict__ W1h_ap,
    ushort* __restrict__ xh) {
    int b = blockIdx.x;
    int tid = threadIdx.x;
    if (b < 512) {                       // W0 big: Wt[c][k], c<512, k<128
        int t = (b & 255) * 256 + tid;
        const float* Ws = (b < 256) ? pr_Ws0 : cc_Ws0;
        const float* Wn = (b < 256) ? pr_Wn0 : cc_Wn0;
        ushort* o = (b < 256) ? W0h_pr : W0h_cc;
        int c = t >> 7, k = t & 127;
        o[t] = f2bf((k < 64) ? Ws[k * 512 + c] : Wn[(k - 64) * 512 + c]);
    } else if (b < 1024) {               // W1 big: Wt[c][k], c<128, k<512
        int t = ((b - 512) & 255) * 256 + tid;
        const float* Ws = (b < 768) ? pr_Ws1 : cc_Ws1;
        const float* Wn = (b < 768) ? pr_Wn1 : cc_Wn1;
        ushort* o = (b < 768) ? W1h_pr : W1h_cc;
        int c = t >> 9, k = t & 511;
        o[t] = f2bf((c < 64) ? Ws[k * 64 + c] : Wn[k * 64 + (c - 64)]);
    } else if (b < 1056) {               // W0 ap: c<64, k<128
        int t = (b - 1024) * 256 + tid;
        int c = t >> 7, k = t & 127;
        W0h_ap[t] = f2bf((k < 64) ? ap_Ws0[k * 64 + c] : ap_Wn0[(k - 64) * 64 + c]);
    } else if (b < 1088) {               // W1 ap: c<128, k<64
        int t = (b - 1056) * 256 + tid;
        int c = t >> 6, k = t & 63;
        W1h_ap[t] = f2bf((c < 64) ? ap_Ws1[k * 64 + c] : ap_Wn1[k * 64 + (c - 64)]);
    } else {                             // cast x
        int t = (b - 1088) * 256 + tid;
        if (t < NN * DD) xh[t] = f2bf(k_emb[t]);
    }
}

// ---------------- FUSED layer0+layer1 v4 (unchanged from R10) ----------------
__global__ __launch_bounds__(512, 4) void fused_sage4(
    const ushort* __restrict__ xh,    // [NP][64]
    const ushort* __restrict__ aggA,  // [branches][NP][64] base
    const ushort* __restrict__ W0a, const ushort* __restrict__ W1a,
    const ushort* __restrict__ W0b, const ushort* __restrict__ W1b,
    const float* __restrict__ b0a, const float* __restrict__ b0b,
    float* __restrict__ outS0, float* __restrict__ outS1,
    float* __restrict__ xn, int nblk) {
    constexpr int LROW = 136;
    __shared__ ushort Ahs[64 * LROW];
    __shared__ ushort h1s[64 * LROW];
    int br = blockIdx.x / nblk;
    int rb = blockIdx.x % nblk;
    const ushort* W0 = br ? W0b : W0a;
    const ushort* W1 = br ? W1b : W1a;
    const float* b0 = br ? b0b : b0a;
    float* outS = br ? outS1 : outS0;
    float* outX = xn + (size_t)br * NN * 64;
    const ushort* agg = aggA + (size_t)br * NP * 64;
    int row0 = rb * 64;

    int wv = threadIdx.x >> 6;
    int lane = threadIdx.x & 63;
    int lrow = lane & 15;
    int koff = (lane >> 4) * 8;
    int crow = (lane >> 4) * 4;

    {
        int r = threadIdx.x >> 3;
        int seg = threadIdx.x & 7;
        const ushort* src = (seg < 4) ? (xh + (size_t)(row0 + r) * 64 + seg * 16)
                                      : (agg + (size_t)(row0 + r) * 64 + (seg - 4) * 16);
        *(short8*)&Ahs[r * LROW + seg * 16] = *(const short8*)src;
        *(short8*)&Ahs[r * LROW + seg * 16 + 8] = *(const short8*)(src + 8);
    }
    __syncthreads();

    f32x4 C[4] = {};
#pragma unroll
    for (int p = 0; p < 4; ++p) {
        {
            short8 B[4];
#pragma unroll
            for (int kk = 0; kk < 4; ++kk)
                B[kk] = *(const short8*)(W0 + (size_t)(p * 128 + wv * 16 + lrow) * 128 + kk * 32 + koff);
            f32x4 acc[4] = {};
#pragma unroll
            for (int rg = 0; rg < 4; ++rg) {
#pragma unroll
                for (int kk = 0; kk < 4; ++kk) {
                    short8 a = *(const short8*)&Ahs[(rg * 16 + lrow) * LROW + kk * 32 + koff];
                    acc[rg] = __builtin_amdgcn_mfma_f32_16x16x32_bf16(a, B[kk], acc[rg], 0, 0, 0);
                }
            }
            float bb = b0[p * 128 + wv * 16 + lrow];
#pragma unroll
            for (int rg = 0; rg < 4; ++rg) {
#pragma unroll
                for (int r = 0; r < 4; ++r) {
                    float v = fmaxf(acc[rg][r] + bb, 0.0f);
                    h1s[(rg * 16 + crow + r) * LROW + wv * 16 + lrow] = f2bf(v);
                }
            }
        }
        __syncthreads();
        {
            short8 B[4];
#pragma unroll
            for (int kc = 0; kc < 4; ++kc)
                B[kc] = *(const short8*)(W1 + (size_t)(wv * 16 + lrow) * HH + p * 128 + kc * 32 + koff);
#pragma unroll
            for (int rg = 0; rg < 4; ++rg) {
#pragma unroll
                for (int kc = 0; kc < 4; ++kc) {
                    short8 a = *(const short8*)&h1s[(rg * 16 + lrow) * LROW + kc * 32 + koff];
                    C[rg] = __builtin_amdgcn_mfma_f32_16x16x32_bf16(a, B[kc], C[rg], 0, 0, 0);
                }
            }
        }
        __syncthreads();
    }
    int col = wv * 16 + lrow;
    float* o = (col < 64) ? (outS + col) : (outX + (col - 64));
#pragma unroll
    for (int rg = 0; rg < 4; ++rg) {
#pragma unroll
        for (int r = 0; r < 4; ++r) {
            int row = row0 + rg * 16 + crow + r;
            if (row < NN) o[(size_t)row * 64] = C[rg][r];
        }
    }
}

// ---------------- FUSED ap branch (unchanged from R10) ----------------
__global__ __launch_bounds__(256, 4) void fused_sage_ap(
    const ushort* __restrict__ xh,
    const ushort* __restrict__ agg,
    const ushort* __restrict__ W0,
    const ushort* __restrict__ W1,
    const float* __restrict__ b0,
    float* __restrict__ outS,
    float* __restrict__ outX) {
    constexpr int LROW = 72;
    __shared__ ushort h1s[16 * LROW];
    int wv = threadIdx.x >> 6;
    int lane = threadIdx.x & 63;
    int lrow = lane & 15;
    int koff = (lane >> 4) * 8;
    int crow = (lane >> 4) * 4;
    int row0 = blockIdx.x * 16;

    {
        const size_t aoff = (size_t)(row0 + lrow) * 64 + koff;
        short8 aF[4];
#pragma unroll
        for (int kk = 0; kk < 2; ++kk) {
            aF[kk]     = *(const short8*)(xh + aoff + kk * 32);
            aF[2 + kk] = *(const short8*)(agg + aoff + kk * 32);
        }
        f32x4 acc = {};
#pragma unroll
        for (int kk = 0; kk < 4; ++kk) {
            short8 b = *(const short8*)(W0 + (size_t)(wv * 16 + lrow) * 128 + kk * 32 + koff);
            acc = __builtin_amdgcn_mfma_f32_16x16x32_bf16(aF[kk], b, acc, 0, 0, 0);
        }
        float bb = b0[wv * 16 + lrow];
#pragma unroll
        for (int r = 0; r < 4; ++r) {
            h1s[(crow + r) * LROW + wv * 16 + lrow] = f2bf(fmaxf(acc[r] + bb, 0.0f));
        }
    }
    __syncthreads();
    {
        f32x4 C2[2] = {};
#pragma unroll
        for (int kc = 0; kc < 2; ++kc) {
            short8 a = *(const short8*)&h1s[lrow * LROW + kc * 32 + koff];
#pragma unroll
            for (int c = 0; c < 2; ++c) {
                short8 b = *(const short8*)(W1 + (size_t)(wv * 32 + c * 16 + lrow) * 64 + kc * 32 + koff);
                C2[c] = __builtin_amdgcn_mfma_f32_16x16x32_bf16(a, b, C2[c], 0, 0, 0);
            }
        }
#pragma unroll
        for (int c = 0; c < 2; ++c) {
            int col = wv * 32 + c * 16 + lrow;
            float* o = (col < 64) ? (outS + col) : (outX + (col - 64));
#pragma unroll
            for (int r = 0; r < 4; ++r) {
                int row = row0 + crow + r;
                if (row < NN) o[(size_t)row * 64] = C2[c][r];
            }
        }
    }
}

// ---------------- attention reduction ----------------
__global__ __launch_bounds__(256) void att_stage1(const float* __restrict__ pr,
                                                  const float* __restrict__ cc,
                                                  const float* __restrict__ ap,
                                                  const float* __restrict__ attW,
                                                  const float* __restrict__ attb,
                                                  float2* __restrict__ partial) {
    __shared__ float red[8];
    int lane = threadIdx.x & 63;
    int wv = threadIdx.x >> 6;
    int gw = blockIdx.x * 4 + wv;
    const int nwaves = ATT_BLOCKS * 4;
    float b = attb[lane];
    float c0 = 0.f, c1 = 0.f;
    for (int n = gw; n < NN; n += nwaves) {
        float p0 = 0.f, p1 = 0.f;
        for (int k = 0; k < DD; ++k) {
            float w = attW[k * DD + lane];
            p0 = fmaf(pr[n * DD + k], w, p0);
            p1 = fmaf(cc[n * DD + k], w, p1);
        }
        float a = ap[n * DD + lane];
        c0 += a * tanhf(p0 + b);
        c1 += a * tanhf(p1 + b);
    }
#pragma unroll
    for (int off = 32; off; off >>= 1) {
        c0 += __shfl_xor(c0, off);
        c1 += __shfl_xor(c1, off);
    }
    if (lane == 0) { red[wv * 2] = c0; red[wv * 2 + 1] = c1; }
    __syncthreads();
    if (threadIdx.x == 0) {
        partial[blockIdx.x] = make_float2(red[0] + red[2] + red[4] + red[6],
                                          red[1] + red[3] + red[5] + red[7]);
    }
}

__global__ __launch_bounds__(64) void att_stage2(const float2* __restrict__ partial,
                                                 float* __restrict__ w_acc) {
    int lane = threadIdx.x;
    float s0 = 0.f, s1 = 0.f;
    for (int i = lane; i < ATT_BLOCKS; i += 64) {
        float2 p = partial[i];
        s0 += p.x; s1 += p.y;
    }
#pragma unroll
    for (int off = 32; off; off >>= 1) {
        s0 += __shfl_xor(s0, off);
        s1 += __shfl_xor(s1, off);
    }
    if (lane == 0) { w_acc[0] = s0; w_acc[1] = s1; }
}

// ---------------- final (in-place on pr=out) ----------------
__global__ __launch_bounds__(256) void final_kernel(float* __restrict__ pr_out,
                                                    const float* __restrict__ cc,
                                                    const float* __restrict__ w_acc) {
    int t = blockIdx.x * blockDim.x + threadIdx.x;
    if (t >= NN * DD) return;
    float w0 = w_acc[0] * (1.0f / NN);
    float w1 = w_acc[1] * (1.0f / NN);
    float m = fmaxf(w0, w1);
    float e0 = __expf(w0 - m), e1 = __expf(w1 - m);
    float inv = 1.0f / (e0 + e1);
    pr_out[t] = (e0 * pr_out[t] + e1 * cc[t]) * inv;
}

extern "C" void kernel_launch(void* const* d_in, const int* in_sizes, int n_in,
                              void* d_out, int out_size, void* d_ws, size_t ws_size,
                              hipStream_t stream) {
    const float* k_emb  = (const float*)d_in[0];
    const int*   pr_src = (const int*)d_in[1];
    const int*   pr_dst = (const int*)d_in[2];
    const float* pr_ew  = (const float*)d_in[3];
    const int*   cc_src = (const int*)d_in[4];
    const int*   cc_dst = (const int*)d_in[5];
    const float* cc_ew  = (const float*)d_in[6];
    const int*   sps_src = (const int*)d_in[7];
    const int*   sps_dst = (const int*)d_in[8];
    const float* pr_Ws0 = (const float*)d_in[9];
    const float* pr_Wn0 = (const float*)d_in[10];
    const float* pr_b0  = (const float*)d_in[11];
    const float* pr_Ws1 = (const float*)d_in[12];
    const float* pr_Wn1 = (const float*)d_in[13];
    const float* pr_b1  = (const float*)d_in[14];
    const float* cc_Ws0 = (const float*)d_in[15];
    const float* cc_Wn0 = (const float*)d_in[16];
    const float* cc_b0  = (const float*)d_in[17];
    const float* cc_Ws1 = (const float*)d_in[18];
    const float* cc_Wn1 = (const float*)d_in[19];
    const float* cc_b1  = (const float*)d_in[20];
    const float* ap_Ws0 = (const float*)d_in[21];
    const float* ap_Wn0 = (const float*)d_in[22];
    const float* ap_b0  = (const float*)d_in[23];
    const float* ap_Ws1 = (const float*)d_in[24];
    const float* ap_Wn1 = (const float*)d_in[25];
    const float* ap_b1  = (const float*)d_in[26];
    const float* att_W  = (const float*)d_in[27];
    const float* att_b  = (const float*)d_in[28];
    float* out = (float*)d_out;

    // ---- workspace layout (256B-aligned) ----
    char* base = (char*)d_ws;
    size_t off = 0;
    auto alloc = [&](size_t bytes) -> void* {
        void* p = base + off;
        off = (off + bytes + 255) & ~(size_t)255;
        return p;
    };
    float*  invd   = (float*)alloc((size_t)3 * NN * 4);
    int*    cnt    = (int*)alloc((size_t)3 * NN * 4);
    int*    rowptr = (int*)alloc((size_t)3 * (NN + 1) * 4);
    int2*   edge_s = (int2*)alloc((size_t)2 * EE * 8);   // pr,cc packed {src, ew}
    int*    src_s2 = (int*)alloc((size_t)EE * 4);        // sps src only
    float*  w_acc  = (float*)alloc(64);
    float2* att_partial = (float2*)alloc(ATT_BLOCKS * 8);
    float*  xn     = (float*)alloc((size_t)3 * NN * DD * 4);   // [3][NN][64]
    float*  out_cc = (float*)alloc((size_t)NN * DD * 4);
    float*  out_ap = (float*)alloc((size_t)NN * DD * 4);
    ushort* xh     = (ushort*)alloc((size_t)NP * DD * 2);
    ushort* aggh   = (ushort*)alloc((size_t)3 * NP * DD * 2);
    ushort* W0h_pr = (ushort*)alloc(512 * 128 * 2);
    ushort* W0h_cc = (ushort*)alloc(512 * 128 * 2);
    ushort* W0h_ap = (ushort*)alloc(64 * 128 * 2);
    ushort* W1h_pr = (ushort*)alloc(128 * 512 * 2);
    ushort* W1h_cc = (ushort*)alloc(128 * 512 * 2);
    ushort* W1h_ap = (ushort*)alloc(128 * 64 * 2);
    float*  out_pr = out;

    const int TB = 256;
    const int blocks_ND = (NN * DD) / TB;        // 5000
    const int blocks_pull3 = (3 * NN * 64) / TB; // 15000
    const int NBLK64 = NP / 64;                  // 313

    // ---- prologue: one pack dispatch + CSR build ----
    pack_all<<<1088 + blocks_ND, TB, 0, stream>>>(
        pr_Ws0, pr_Wn0, cc_Ws0, cc_Wn0, pr_Ws1, pr_Wn1, cc_Ws1, cc_Wn1,
        ap_Ws0, ap_Wn0, ap_Ws1, ap_Wn1, k_emb,
        W0h_pr, W0h_cc, W1h_pr, W1h_cc, W0h_ap, W1h_ap, xh);

    hipMemsetAsync(cnt, 0, (size_t)3 * NN * 4, stream);
    hist3<<<3 * BLOCKS_E, TB, 0, stream>>>(pr_dst, cc_dst, sps_dst, cnt);
    inv_kernel<<<(3 * NN + TB - 1) / TB, TB, 0, stream>>>(cnt, invd, 3 * NN);
    scan_kernel<<<3, 1024, 0, stream>>>(cnt, rowptr);
    hipMemsetAsync(cnt, 0, (size_t)3 * NN * 4, stream);   // cnt becomes cursor
    bucket3<<<3 * BLOCKS_E, TB, 0, stream>>>(pr_src, pr_dst, pr_ew,
                                             cc_src, cc_dst, cc_ew,
                                             sps_src, sps_dst,
                                             rowptr, cnt, edge_s, src_s2);

    // ---- layer-0 aggregation for all 3 graphs ----
    pull_cast3<<<blocks_pull3, TB, 0, stream>>>(k_emb, rowptr, edge_s, src_s2, invd, aggh);

    // ---- fused layer0+layer1 ----
    fused_sage4<<<2 * NBLK64, 512, 0, stream>>>(
        xh, aggh,
        W0h_pr, W1h_pr, W0h_cc, W1h_cc,
        pr_b0, cc_b0, out_pr, out_cc, xn, NBLK64);
    fused_sage_ap<<<NP / 16, 256, 0, stream>>>(
        xh, aggh + (size_t)2 * NP * 64,
        W0h_ap, W1h_ap, ap_b0, out_ap, xn + (size_t)2 * NN * 64);

    // ---- layer-1 aggregation + combine ----
    pull_combine3<<<blocks_pull3, TB, 0, stream>>>(xn, rowptr, edge_s, src_s2, invd,
                                                   pr_b1, cc_b1, ap_b1,
                                                   out_pr, out_cc, out_ap);

    // ---- attention fusion ----
    att_stage1<<<ATT_BLOCKS, TB, 0, stream>>>(out_pr, out_cc, out_ap, att_W, att_b, att_partial);
    att_stage2<<<1, 64, 0, stream>>>(att_partial, w_acc);
    final_kernel<<<blocks_ND, TB, 0, stream>>>(out_pr, out_cc, w_acc);
}

// Round 12
// 278.774 us; speedup vs baseline: 7.8403x; 1.0892x over previous
//
#include <hip/hip_runtime.h>

#define NN 20000   // nodes
#define NP 20032   // padded nodes (313*64)
#define DD 64      // emb dim
#define HH 512     // hidden
#define EE 320000  // edges per graph
#define ATT_BLOCKS 625
#define BLOCKS_E (EE / 256) // 1250
#define CB 157              // coarse buckets (dst>>7), 157*128 >= 20000
#define EPB 4096            // edges per bucket_coarse block
#define B1_BLOCKS ((EE + EPB - 1) / EPB)  // 79

typedef __attribute__((ext_vector_type(8))) short short8;   // 8 bf16 = 4 VGPR
typedef __attribute__((ext_vector_type(4))) float f32x4;

__device__ __forceinline__ ushort f2bf(float f) {
    union { float f; unsigned u; } v; v.f = f;
    unsigned r = v.u + 0x7FFF + ((v.u >> 16) & 1);   // RNE
    return (ushort)(r >> 16);
}
__device__ __forceinline__ float bf2f(ushort h) {
    union { unsigned u; float f; } v; v.u = ((unsigned)h) << 16;
    return v.f;
}

// ---------------- CSR build ----------------
__global__ __launch_bounds__(256) void hist3(const int* __restrict__ d0,
                                             const int* __restrict__ d1,
                                             const int* __restrict__ d2,
                                             int* __restrict__ cnt) {
    int g = blockIdx.x / BLOCKS_E;
    int e = (blockIdx.x % BLOCKS_E) * 256 + threadIdx.x;
    const int* d = (g == 0) ? d0 : (g == 1) ? d1 : d2;
    if (e < EE) atomicAdd(&cnt[g * NN + d[e]], 1);
}

__global__ __launch_bounds__(256) void inv_kernel(const int* __restrict__ cnt,
                                                  float* __restrict__ invd, int n) {
    int i = blockIdx.x * blockDim.x + threadIdx.x;
    if (i < n) invd[i] = 1.0f / fmaxf((float)cnt[i], 1.0f);
}

__global__ __launch_bounds__(1024) void scan_kernel(const int* __restrict__ cnt,
                                                    int* __restrict__ rowptr) {
    __shared__ int part[1024];
    int g = blockIdx.x;
    const int* c = cnt + g * NN;
    int* rp = rowptr + g * (NN + 1);
    int tid = threadIdx.x;
    const int CH = (NN + 1023) / 1024;
    int i0 = tid * CH;
    int s = 0;
    for (int i = 0; i < CH; ++i) { int idx = i0 + i; if (idx < NN) s += c[idx]; }
    part[tid] = s;
    __syncthreads();
    for (int off = 1; off < 1024; off <<= 1) {
        int v = (tid >= off) ? part[tid - off] : 0;
        __syncthreads();
        part[tid] += v;
        __syncthreads();
    }
    int run = (tid > 0) ? part[tid - 1] : 0;
    for (int i = 0; i < CH; ++i) {
        int idx = i0 + i;
        if (idx < NN) { rp[idx] = run; run += c[idx]; }
    }
    if (tid == 1023) rp[NN] = part[1023];
}

// ---------------- bucket pass 1: coarse partition with LDS staging ----------------
// Block sorts EPB edges by cb=dst>>7 in LDS, claims global per-cb chunks, copies
// out contiguous runs into coarse regions bounded by rowptr[cb*128].
__global__ __launch_bounds__(256) void bucket_coarse(
    const int* __restrict__ s0, const int* __restrict__ d0, const float* __restrict__ w0,
    const int* __restrict__ s1, const int* __restrict__ d1, const float* __restrict__ w1,
    const int* __restrict__ s2, const int* __restrict__ d2,
    const int* __restrict__ rowptr,
    int* __restrict__ ccur,          // [3*CB], zeroed
    int2* __restrict__ ce,           // [3*EE] coarse {src, ew_bits}
    ushort* __restrict__ cd) {       // [3*EE] coarse dst
    __shared__ int cnt_s[CB];
    __shared__ int off_s[CB];
    __shared__ int pos_s[CB];
    __shared__ int gbase[CB];
    __shared__ int lsrc[EPB];
    __shared__ int lew[EPB];
    __shared__ ushort ldst[EPB];
    int g = blockIdx.x / B1_BLOCKS;
    int blk = blockIdx.x % B1_BLOCKS;
    const int* S = (g == 0) ? s0 : (g == 1) ? s1 : s2;
    const int* D = (g == 0) ? d0 : (g == 1) ? d1 : d2;
    const float* W = (g == 0) ? w0 : (g == 1) ? w1 : nullptr;
    int e0 = blk * EPB;
    int n = min(EPB, EE - e0);
    for (int i = threadIdx.x; i < CB; i += 256) cnt_s[i] = 0;
    __syncthreads();
    for (int i = threadIdx.x; i < n; i += 256)
        atomicAdd(&cnt_s[D[e0 + i] >> 7], 1);
    __syncthreads();
    if (threadIdx.x == 0) {
        int run = 0;
        for (int i = 0; i < CB; ++i) { off_s[i] = run; run += cnt_s[i]; }
    }
    __syncthreads();
    if (threadIdx.x < CB) pos_s[threadIdx.x] = off_s[threadIdx.x];
    __syncthreads();
    for (int i = threadIdx.x; i < n; i += 256) {
        int e = e0 + i;
        int d = D[e];
        int p = atomicAdd(&pos_s[d >> 7], 1);
        lsrc[p] = S[e];
        lew[p] = (g < 2) ? __float_as_int(W[e]) : 0;
        ldst[p] = (ushort)d;
    }
    __syncthreads();
    if (threadIdx.x < CB)
        gbase[threadIdx.x] = atomicAdd(&ccur[g * CB + threadIdx.x], cnt_s[threadIdx.x]);
    __syncthreads();
    const int* rp = rowptr + g * (NN + 1);
    for (int j = threadIdx.x; j < n; j += 256) {
        ushort d = ldst[j];
        int cb = d >> 7;
        int gpos = rp[cb << 7] + gbase[cb] + (j - off_s[cb]);
        ce[(size_t)g * EE + gpos] = make_int2(lsrc[j], lew[j]);
        cd[(size_t)g * EE + gpos] = d;
    }
}

// ---------------- bucket pass 2: fine scatter within coarse window ----------------
// One block per (g, cb): LDS cursors, writes confined to a ~16KB window.
__global__ __launch_bounds__(256) void bucket_fine(
    const int* __restrict__ rowptr,
    const int2* __restrict__ ce, const ushort* __restrict__ cd,
    int2* __restrict__ edge_s,    // [2*EE] final pr/cc {src, ew}
    int* __restrict__ src_s2) {   // [EE] final sps src
    __shared__ int rp_s[129];
    __shared__ int cur_s[128];
    int g = blockIdx.x / CB;
    int cb = blockIdx.x % CB;
    const int* rp = rowptr + g * (NN + 1);
    int n0 = cb << 7;
    int n1 = min(n0 + 128, NN);
    int m = n1 - n0;
    if (threadIdx.x <= m) rp_s[threadIdx.x] = rp[n0 + threadIdx.x];
    if (threadIdx.x < m) cur_s[threadIdx.x] = 0;
    __syncthreads();
    int beg = rp_s[0], end = rp_s[m];
    for (int j = beg + threadIdx.x; j < end; j += 256) {
        int2 e = ce[(size_t)g * EE + j];
        int dl = (int)cd[(size_t)g * EE + j] - n0;
        int pos = rp_s[dl] + atomicAdd(&cur_s[dl], 1);
        if (g < 2) edge_s[(size_t)g * EE + pos] = e;
        else src_s2[pos] = e.x;
    }
}

// ---------------- pull aggregation (bf16 gathers), 3 graphs, 4-way ILP ----------------
__global__ __launch_bounds__(256) void pull_cast3(const ushort* __restrict__ xh,  // [NP][64] bf16
                                                  const int* __restrict__ rowptr,
                                                  const int2* __restrict__ edge_s,
                                                  const int* __restrict__ src_s2,
                                                  const float* __restrict__ invd,
                                                  ushort* __restrict__ aggh) {
    int wid = (blockIdx.x * blockDim.x + threadIdx.x) >> 6;
    int lane = threadIdx.x & 63;
    if (wid >= 3 * NN) return;
    int g = wid / NN, n = wid % NN;
    const int* rp = rowptr + g * (NN + 1);
    int beg = rp[n], end = rp[n + 1];
    float a0 = 0.f, a1 = 0.f, a2 = 0.f, a3 = 0.f;
    int i = beg;
    if (g < 2) {
        const int2* es = edge_s + (size_t)g * EE;
        for (; i + 4 <= end; i += 4) {
            int2 e0 = es[i], e1 = es[i + 1], e2 = es[i + 2], e3 = es[i + 3];
            a0 = fmaf(bf2f(xh[e0.x * DD + lane]), __int_as_float(e0.y), a0);
            a1 = fmaf(bf2f(xh[e1.x * DD + lane]), __int_as_float(e1.y), a1);
            a2 = fmaf(bf2f(xh[e2.x * DD + lane]), __int_as_float(e2.y), a2);
            a3 = fmaf(bf2f(xh[e3.x * DD + lane]), __int_as_float(e3.y), a3);
        }
        for (; i < end; ++i) { int2 e0 = es[i]; a0 = fmaf(bf2f(xh[e0.x * DD + lane]), __int_as_float(e0.y), a0); }
    } else {
        for (; i + 4 <= end; i += 4) {
            int s0 = src_s2[i], s1 = src_s2[i + 1], s2 = src_s2[i + 2], s3 = src_s2[i + 3];
            a0 += bf2f(xh[s0 * DD + lane]);
            a1 += bf2f(xh[s1 * DD + lane]);
            a2 += bf2f(xh[s2 * DD + lane]);
            a3 += bf2f(xh[s3 * DD + lane]);
        }
        for (; i < end; ++i) a0 += bf2f(xh[src_s2[i] * DD + lane]);
    }
    float acc = (a0 + a1) + (a2 + a3);
    aggh[((size_t)g * NP + n) * 64 + lane] = f2bf(acc * invd[g * NN + n]);
}

__global__ __launch_bounds__(256) void pull_combine3(const ushort* __restrict__ xnh, // [3][NP][64] bf16
                                                     const int* __restrict__ rowptr,
                                                     const int2* __restrict__ edge_s,
                                                     const int* __restrict__ src_s2,
                                                     const float* __restrict__ invd,
                                                     const float* __restrict__ b_pr,
                                                     const float* __restrict__ b_cc,
                                                     const float* __restrict__ b_ap,
                                                     float* __restrict__ o_pr,
                                                     float* __restrict__ o_cc,
                                                     float* __restrict__ o_ap) {
    int wid = (blockIdx.x * blockDim.x + threadIdx.x) >> 6;
    int lane = threadIdx.x & 63;
    if (wid >= 3 * NN) return;
    int g = wid / NN, n = wid % NN;
    const int* rp = rowptr + g * (NN + 1);
    const ushort* x = xnh + (size_t)g * NP * 64;
    const float* bias = (g == 0) ? b_pr : (g == 1) ? b_cc : b_ap;
    float* out = (g == 0) ? o_pr : (g == 1) ? o_cc : o_ap;
    int beg = rp[n], end = rp[n + 1];
    float a0 = 0.f, a1 = 0.f, a2 = 0.f, a3 = 0.f;
    int i = beg;
    if (g < 2) {
        const int2* es = edge_s + (size_t)g * EE;
        for (; i + 4 <= end; i += 4) {
            int2 e0 = es[i], e1 = es[i + 1], e2 = es[i + 2], e3 = es[i + 3];
            a0 = fmaf(bf2f(x[e0.x * DD + lane]), __int_as_float(e0.y), a0);
            a1 = fmaf(bf2f(x[e1.x * DD + lane]), __int_as_float(e1.y), a1);
            a2 = fmaf(bf2f(x[e2.x * DD + lane]), __int_as_float(e2.y), a2);
            a3 = fmaf(bf2f(x[e3.x * DD + lane]), __int_as_float(e3.y), a3);
        }
        for (; i < end; ++i) { int2 e0 = es[i]; a0 = fmaf(bf2f(x[e0.x * DD + lane]), __int_as_float(e0.y), a0); }
    } else {
        for (; i + 4 <= end; i += 4) {
            int s0 = src_s2[i], s1 = src_s2[i + 1], s2 = src_s2[i + 2], s3 = src_s2[i + 3];
            a0 += bf2f(x[s0 * DD + lane]);
            a1 += bf2f(x[s1 * DD + lane]);
            a2 += bf2f(x[s2 * DD + lane]);
            a3 += bf2f(x[s3 * DD + lane]);
        }
        for (; i < end; ++i) a0 += bf2f(x[src_s2[i] * DD + lane]);
    }
    float acc = (a0 + a1) + (a2 + a3);
    out[n * DD + lane] += acc * invd[g * NN + n] + bias[lane];
}

// ---------------- consolidated prologue pack ----------------
__global__ __launch_bounds__(256) void pack_all(
    const float* __restrict__ pr_Ws0, const float* __restrict__ pr_Wn0,
    const float* __restrict__ cc_Ws0, const float* __restrict__ cc_Wn0,
    const float* __restrict__ pr_Ws1, const float* __restrict__ pr_Wn1,
    const float* __restrict__ cc_Ws1, const float* __restrict__ cc_Wn1,
    const float* __restrict__ ap_Ws0, const float* __restrict__ ap_Wn0,
    const float* __restrict__ ap_Ws1, const float* __restrict__ ap_Wn1,
    const float* __restrict__ k_emb,
    ushort* __restrict__ W0h_pr, ushort* __restrict__ W0h_cc,
    ushort* __restrict__ W1h_pr, ushort* __restrict__ W1h_cc,
    ushort* __restrict__ W0h_ap, ushort* __restrict__ W1h_ap,
    ushort* __restrict__ xh) {
    int b = blockIdx.x;
    int tid = threadIdx.x;
    if (b < 512) {
        int t = (b & 255) * 256 + tid;
        const float* Ws = (b < 256) ? pr_Ws0 : cc_Ws0;
        const float* Wn = (b < 256) ? pr_Wn0 : cc_Wn0;
        ushort* o = (b < 256) ? W0h_pr : W0h_cc;
        int c = t >> 7, k = t & 127;
        o[t] = f2bf((k < 64) ? Ws[k * 512 + c] : Wn[(k - 64) * 512 + c]);
    } else if (b < 1024) {
        int t = ((b - 512) & 255) * 256 + tid;
        const float* Ws = (b < 768) ? pr_Ws1 : cc_Ws1;
        const float* Wn = (b < 768) ? pr_Wn1 : cc_Wn1;
        ushort* o = (b < 768) ? W1h_pr : W1h_cc;
        int c = t >> 9, k = t & 511;
        o[t] = f2bf((c < 64) ? Ws[k * 64 + c] : Wn[k * 64 + (c - 64)]);
    } else if (b < 1056) {
        int t = (b - 1024) * 256 + tid;
        int c = t >> 7, k = t & 127;
        W0h_ap[t] = f2bf((k < 64) ? ap_Ws0[k * 64 + c] : ap_Wn0[(k - 64) * 64 + c]);
    } else if (b < 1088) {
        int t = (b - 1056) * 256 + tid;
        int c = t >> 6, k = t & 63;
        W1h_ap[t] = f2bf((c < 64) ? ap_Ws1[k * 64 + c] : ap_Wn1[k * 64 + (c - 64)]);
    } else {
        int t = (b - 1088) * 256 + tid;
        if (t < NN * DD) xh[t] = f2bf(k_emb[t]);
    }
}

// ---------------- FUSED layer0+layer1 v4 (bf16 xn out) ----------------
__global__ __launch_bounds__(512, 4) void fused_sage4(
    const ushort* __restrict__ xh,    // [NP][64]
    const ushort* __restrict__ aggA,  // [branches][NP][64]
    const ushort* __restrict__ W0a, const ushort* __restrict__ W1a,
    const ushort* __restrict__ W0b, const ushort* __restrict__ W1b,
    const float* __restrict__ b0a, const float* __restrict__ b0b,
    float* __restrict__ outS0, float* __restrict__ outS1,
    ushort* __restrict__ xnh, int nblk) {   // [branches][NP][64] bf16
    constexpr int LROW = 136;
    __shared__ ushort Ahs[64 * LROW];
    __shared__ ushort h1s[64 * LROW];
    int br = blockIdx.x / nblk;
    int rb = blockIdx.x % nblk;
    const ushort* W0 = br ? W0b : W0a;
    const ushort* W1 = br ? W1b : W1a;
    const float* b0 = br ? b0b : b0a;
    float* outS = br ? outS1 : outS0;
    ushort* outX = xnh + (size_t)br * NP * 64;
    const ushort* agg = aggA + (size_t)br * NP * 64;
    int row0 = rb * 64;

    int wv = threadIdx.x >> 6;
    int lane = threadIdx.x & 63;
    int lrow = lane & 15;
    int koff = (lane >> 4) * 8;
    int crow = (lane >> 4) * 4;

    {
        int r = threadIdx.x >> 3;
        int seg = threadIdx.x & 7;
        const ushort* src = (seg < 4) ? (xh + (size_t)(row0 + r) * 64 + seg * 16)
                                      : (agg + (size_t)(row0 + r) * 64 + (seg - 4) * 16);
        *(short8*)&Ahs[r * LROW + seg * 16] = *(const short8*)src;
        *(short8*)&Ahs[r * LROW + seg * 16 + 8] = *(const short8*)(src + 8);
    }
    __syncthreads();

    f32x4 C[4] = {};
#pragma unroll
    for (int p = 0; p < 4; ++p) {
        {
            short8 B[4];
#pragma unroll
            for (int kk = 0; kk < 4; ++kk)
                B[kk] = *(const short8*)(W0 + (size_t)(p * 128 + wv * 16 + lrow) * 128 + kk * 32 + koff);
            f32x4 acc[4] = {};
#pragma unroll
            for (int rg = 0; rg < 4; ++rg) {
#pragma unroll
                for (int kk = 0; kk < 4; ++kk) {
                    short8 a = *(const short8*)&Ahs[(rg * 16 + lrow) * LROW + kk * 32 + koff];
                    acc[rg] = __builtin_amdgcn_mfma_f32_16x16x32_bf16(a, B[kk], acc[rg], 0, 0, 0);
                }
            }
            float bb = b0[p * 128 + wv * 16 + lrow];
#pragma unroll
            for (int rg = 0; rg < 4; ++rg) {
#pragma unroll
                for (int r = 0; r < 4; ++r) {
                    float v = fmaxf(acc[rg][r] + bb, 0.0f);
                    h1s[(rg * 16 + crow + r) * LROW + wv * 16 + lrow] = f2bf(v);
                }
            }
        }
        __syncthreads();
        {
            short8 B[4];
#pragma unroll
            for (int kc = 0; kc < 4; ++kc)
                B[kc] = *(const short8*)(W1 + (size_t)(wv * 16 + lrow) * HH + p * 128 + kc * 32 + koff);
#pragma unroll
            for (int rg = 0; rg < 4; ++rg) {
#pragma unroll
                for (int kc = 0; kc < 4; ++kc) {
                    short8 a = *(const short8*)&h1s[(rg * 16 + lrow) * LROW + kc * 32 + koff];
                    C[rg] = __builtin_amdgcn_mfma_f32_16x16x32_bf16(a, B[kc], C[rg], 0, 0, 0);
                }
            }
        }
        __syncthreads();
    }
    int col = wv * 16 + lrow;
    if (col < 64) {
        float* o = outS + col;
#pragma unroll
        for (int rg = 0; rg < 4; ++rg)
#pragma unroll
            for (int r = 0; r < 4; ++r) {
                int row = row0 + rg * 16 + crow + r;
                if (row < NN) o[(size_t)row * 64] = C[rg][r];
            }
    } else {
        ushort* o = outX + (col - 64);
#pragma unroll
        for (int rg = 0; rg < 4; ++rg)
#pragma unroll
            for (int r = 0; r < 4; ++r) {
                int row = row0 + rg * 16 + crow + r;
                if (row < NN) o[(size_t)row * 64] = f2bf(C[rg][r]);
            }
    }
}

// ---------------- FUSED ap branch (bf16 xn out) ----------------
__global__ __launch_bounds__(256, 4) void fused_sage_ap(
    const ushort* __restrict__ xh,
    const ushort* __restrict__ agg,
    const ushort* __restrict__ W0,
    const ushort* __restrict__ W1,
    const float* __restrict__ b0,
    float* __restrict__ outS,
    ushort* __restrict__ outX) {
    constexpr int LROW = 72;
    __shared__ ushort h1s[16 * LROW];
    int wv = threadIdx.x >> 6;
    int lane = threadIdx.x & 63;
    int lrow = lane & 15;
    int koff = (lane >> 4) * 8;
    int crow = (lane >> 4) * 4;
    int row0 = blockIdx.x * 16;

    {
        const size_t aoff = (size_t)(row0 + lrow) * 64 + koff;
        short8 aF[4];
#pragma unroll
        for (int kk = 0; kk < 2; ++kk) {
            aF[kk]     = *(const short8*)(xh + aoff + kk * 32);
            aF[2 + kk] = *(const short8*)(agg + aoff + kk * 32);
        }
        f32x4 acc = {};
#pragma unroll
        for (int kk = 0; kk < 4; ++kk) {
            short8 b = *(const short8*)(W0 + (size_t)(wv * 16 + lrow) * 128 + kk * 32 + koff);
            acc = __builtin_amdgcn_mfma_f32_16x16x32_bf16(aF[kk], b, acc, 0, 0, 0);
        }
        float bb = b0[wv * 16 + lrow];
#pragma unroll
        for (int r = 0; r < 4; ++r) {
            h1s[(crow + r) * LROW + wv * 16 + lrow] = f2bf(fmaxf(acc[r] + bb, 0.0f));
        }
    }
    __syncthreads();
    {
        f32x4 C2[2] = {};
#pragma unroll
        for (int kc = 0; kc < 2; ++kc) {
            short8 a = *(const short8*)&h1s[lrow * LROW + kc * 32 + koff];
#pragma unroll
            for (int c = 0; c < 2; ++c) {
                short8 b = *(const short8*)(W1 + (size_t)(wv * 32 + c * 16 + lrow) * 64 + kc * 32 + koff);
                C2[c] = __builtin_amdgcn_mfma_f32_16x16x32_bf16(a, b, C2[c], 0, 0, 0);
            }
        }
#pragma unroll
        for (int c = 0; c < 2; ++c) {
            int col = wv * 32 + c * 16 + lrow;
#pragma unroll
            for (int r = 0; r < 4; ++r) {
                int row = row0 + crow + r;
                if (row < NN) {
                    if (col < 64) outS[(size_t)row * 64 + col] = C2[c][r];
                    else outX[(size_t)row * 64 + (col - 64)] = f2bf(C2[c][r]);
                }
            }
        }
    }
}

// ---------------- attention reduction ----------------
__global__ __launch_bounds__(256) void att_stage1(const float* __restrict__ pr,
                                                  const float* __restrict__ cc,
                                                  const float* __restrict__ ap,
                                                  const float* __restrict__ attW,
                                                  const float* __restrict__ attb,
                                                  float2* __restrict__ partial) {
    __shared__ float red[8];
    int lane = threadIdx.x & 63;
    int wv = threadIdx.x >> 6;
    int gw = blockIdx.x * 4 + wv;
    const int nwaves = ATT_BLOCKS * 4;
    float b = attb[lane];
    float c0 = 0.f, c1 = 0.f;
    for (int n = gw; n < NN; n += nwaves) {
        float p0 = 0.f, p1 = 0.f;
        for (int k = 0; k < DD; ++k) {
            float w = attW[k * DD + lane];
            p0 = fmaf(pr[n * DD + k], w, p0);
            p1 = fmaf(cc[n * DD + k], w, p1);
        }
        float a = ap[n * DD + lane];
        c0 += a * tanhf(p0 + b);
        c1 += a * tanhf(p1 + b);
    }
#pragma unroll
    for (int off = 32; off; off >>= 1) {
        c0 += __shfl_xor(c0, off);
        c1 += __shfl_xor(c1, off);
    }
    if (lane == 0) { red[wv * 2] = c0; red[wv * 2 + 1] = c1; }
    __syncthreads();
    if (threadIdx.x == 0) {
        partial[blockIdx.x] = make_float2(red[0] + red[2] + red[4] + red[6],
                                          red[1] + red[3] + red[5] + red[7]);
    }
}

__global__ __launch_bounds__(64) void att_stage2(const float2* __restrict__ partial,
                                                 float* __restrict__ w_acc) {
    int lane = threadIdx.x;
    float s0 = 0.f, s1 = 0.f;
    for (int i = lane; i < ATT_BLOCKS; i += 64) {
        float2 p = partial[i];
        s0 += p.x; s1 += p.y;
    }
#pragma unroll
    for (int off = 32; off; off >>= 1) {
        s0 += __shfl_xor(s0, off);
        s1 += __shfl_xor(s1, off);
    }
    if (lane == 0) { w_acc[0] = s0; w_acc[1] = s1; }
}

// ---------------- final (in-place on pr=out) ----------------
__global__ __launch_bounds__(256) void final_kernel(float* __restrict__ pr_out,
                                                    const float* __restrict__ cc,
                                                    const float* __restrict__ w_acc) {
    int t = blockIdx.x * blockDim.x + threadIdx.x;
    if (t >= NN * DD) return;
    float w0 = w_acc[0] * (1.0f / NN);
    float w1 = w_acc[1] * (1.0f / NN);
    float m = fmaxf(w0, w1);
    float e0 = __expf(w0 - m), e1 = __expf(w1 - m);
    float inv = 1.0f / (e0 + e1);
    pr_out[t] = (e0 * pr_out[t] + e1 * cc[t]) * inv;
}

extern "C" void kernel_launch(void* const* d_in, const int* in_sizes, int n_in,
                              void* d_out, int out_size, void* d_ws, size_t ws_size,
                              hipStream_t stream) {
    const float* k_emb  = (const float*)d_in[0];
    const int*   pr_src = (const int*)d_in[1];
    const int*   pr_dst = (const int*)d_in[2];
    const float* pr_ew  = (const float*)d_in[3];
    const int*   cc_src = (const int*)d_in[4];
    const int*   cc_dst = (const int*)d_in[5];
    const float* cc_ew  = (const float*)d_in[6];
    const int*   sps_src = (const int*)d_in[7];
    const int*   sps_dst = (const int*)d_in[8];
    const float* pr_Ws0 = (const float*)d_in[9];
    const float* pr_Wn0 = (const float*)d_in[10];
    const float* pr_b0  = (const float*)d_in[11];
    const float* pr_Ws1 = (const float*)d_in[12];
    const float* pr_Wn1 = (const float*)d_in[13];
    const float* pr_b1  = (const float*)d_in[14];
    const float* cc_Ws0 = (const float*)d_in[15];
    const float* cc_Wn0 = (const float*)d_in[16];
    const float* cc_b0  = (const float*)d_in[17];
    const float* cc_Ws1 = (const float*)d_in[18];
    const float* cc_Wn1 = (const float*)d_in[19];
    const float* cc_b1  = (const float*)d_in[20];
    const float* ap_Ws0 = (const float*)d_in[21];
    const float* ap_Wn0 = (const float*)d_in[22];
    const float* ap_b0  = (const float*)d_in[23];
    const float* ap_Ws1 = (const float*)d_in[24];
    const float* ap_Wn1 = (const float*)d_in[25];
    const float* ap_b1  = (const float*)d_in[26];
    const float* att_W  = (const float*)d_in[27];
    const float* att_b  = (const float*)d_in[28];
    float* out = (float*)d_out;

    // ---- workspace layout (256B-aligned) ----
    char* base = (char*)d_ws;
    size_t off = 0;
    auto alloc = [&](size_t bytes) -> void* {
        void* p = base + off;
        off = (off + bytes + 255) & ~(size_t)255;
        return p;
    };
    float*  invd   = (float*)alloc((size_t)3 * NN * 4);
    int*    cnt    = (int*)alloc((size_t)(3 * NN + 3 * CB) * 4);  // cnt + coarse cursor (one memset)
    int*    ccur   = cnt + 3 * NN;
    int*    rowptr = (int*)alloc((size_t)3 * (NN + 1) * 4);
    int2*   edge_s = (int2*)alloc((size_t)2 * EE * 8);
    int*    src_s2 = (int*)alloc((size_t)EE * 4);
    int2*   ce     = (int2*)alloc((size_t)3 * EE * 8);
    ushort* cd     = (ushort*)alloc((size_t)3 * EE * 2);
    float*  w_acc  = (float*)alloc(64);
    float2* att_partial = (float2*)alloc(ATT_BLOCKS * 8);
    ushort* xnh    = (ushort*)alloc((size_t)3 * NP * DD * 2);   // bf16 xn
    float*  out_cc = (float*)alloc((size_t)NN * DD * 4);
    float*  out_ap = (float*)alloc((size_t)NN * DD * 4);
    ushort* xh     = (ushort*)alloc((size_t)NP * DD * 2);
    ushort* aggh   = (ushort*)alloc((size_t)3 * NP * DD * 2);
    ushort* W0h_pr = (ushort*)alloc(512 * 128 * 2);
    ushort* W0h_cc = (ushort*)alloc(512 * 128 * 2);
    ushort* W0h_ap = (ushort*)alloc(64 * 128 * 2);
    ushort* W1h_pr = (ushort*)alloc(128 * 512 * 2);
    ushort* W1h_cc = (ushort*)alloc(128 * 512 * 2);
    ushort* W1h_ap = (ushort*)alloc(128 * 64 * 2);
    float*  out_pr = out;

    const int TB = 256;
    const int blocks_ND = (NN * DD) / TB;        // 5000
    const int blocks_pull3 = (3 * NN * 64) / TB; // 15000
    const int NBLK64 = NP / 64;                  // 313

    // ---- prologue ----
    pack_all<<<1088 + blocks_ND, TB, 0, stream>>>(
        pr_Ws0, pr_Wn0, cc_Ws0, cc_Wn0, pr_Ws1, pr_Wn1, cc_Ws1, cc_Wn1,
        ap_Ws0, ap_Wn0, ap_Ws1, ap_Wn1, k_emb,
        W0h_pr, W0h_cc, W1h_pr, W1h_cc, W0h_ap, W1h_ap, xh);

    hipMemsetAsync(cnt, 0, (size_t)(3 * NN + 3 * CB) * 4, stream);
    hist3<<<3 * BLOCKS_E, TB, 0, stream>>>(pr_dst, cc_dst, sps_dst, cnt);
    inv_kernel<<<(3 * NN + TB - 1) / TB, TB, 0, stream>>>(cnt, invd, 3 * NN);
    scan_kernel<<<3, 1024, 0, stream>>>(cnt, rowptr);
    bucket_coarse<<<3 * B1_BLOCKS, TB, 0, stream>>>(pr_src, pr_dst, pr_ew,
                                                    cc_src, cc_dst, cc_ew,
                                                    sps_src, sps_dst,
                                                    rowptr, ccur, ce, cd);
    bucket_fine<<<3 * CB, TB, 0, stream>>>(rowptr, ce, cd, edge_s, src_s2);

    // ---- layer-0 aggregation (bf16 gather) ----
    pull_cast3<<<blocks_pull3, TB, 0, stream>>>(xh, rowptr, edge_s, src_s2, invd, aggh);

    // ---- fused layer0+layer1 ----
    fused_sage4<<<2 * NBLK64, 512, 0, stream>>>(
        xh, aggh,
        W0h_pr, W1h_pr, W0h_cc, W1h_cc,
        pr_b0, cc_b0, out_pr, out_cc, xnh, NBLK64);
    fused_sage_ap<<<NP / 16, 256, 0, stream>>>(
        xh, aggh + (size_t)2 * NP * 64,
        W0h_ap, W1h_ap, ap_b0, out_ap, xnh + (size_t)2 * NP * 64);

    // ---- layer-1 aggregation + combine (bf16 gather) ----
    pull_combine3<<<blocks_pull3, TB, 0, stream>>>(xnh, rowptr, edge_s, src_s2, invd,
                                                   pr_b1, cc_b1, ap_b1,
                                                   out_pr, out_cc, out_ap);

    // ---- attention fusion ----
    att_stage1<<<ATT_BLOCKS, TB, 0, stream>>>(out_pr, out_cc, out_ap, att_W, att_b, att_partial);
    att_stage2<<<1, 64, 0, stream>>>(att_partial, w_acc);
    final_kernel<<<blocks_ND, TB, 0, stream>>>(out_pr, out_cc, w_acc);
}